// Round 6
// baseline (375.469 us; speedup 1.0000x reference)
//
#include <hip/hip_runtime.h>
#include <math.h>

typedef unsigned short u16;
typedef __attribute__((ext_vector_type(8))) __bf16 bf16x8;
typedef __attribute__((ext_vector_type(4))) float floatx4;

#define T_TOK 4096
#define DD    512
#define FF    2048
#define EE    8
#define NSH   2

#define BM 128
#define BN 128
#define BK 32
#define LDK 40   // fallback kernels: padded LDS row stride
#define BT2 64   // fallback gemm2 N-tile
#define CAP 4096
#define PADF 0x80000000u
#define NSLOT (2 * T_TOK + EE * BM)   // 9216 compact rows max

__device__ __forceinline__ float bf2f(u16 v) {
  union { unsigned int u; float f; } c; c.u = ((unsigned int)v) << 16; return c.f;
}
__device__ __forceinline__ u16 f2bf(float f) {
  union { float ff; unsigned int u; } c; c.ff = f;
  unsigned int u = c.u;
  u += 0x7fffu + ((u >> 16) & 1u);   // RNE
  return (u16)(u >> 16);
}
__device__ __forceinline__ float decode(const void* p, size_t idx, int f) {
  return f ? ((const float*)p)[idx] : bf2f(((const u16*)p)[idx]);
}
__device__ __forceinline__ bf16x8 load8(const void* base, size_t idx, int f) {
  if (f) {
    const float* p = (const float*)base + idx;
    float4 a = *(const float4*)p;
    float4 b = *(const float4*)(p + 4);
    union { bf16x8 v; u16 s[8]; } u;
    u.s[0] = f2bf(a.x); u.s[1] = f2bf(a.y); u.s[2] = f2bf(a.z); u.s[3] = f2bf(a.w);
    u.s[4] = f2bf(b.x); u.s[5] = f2bf(b.y); u.s[6] = f2bf(b.z); u.s[7] = f2bf(b.w);
    return u.v;
  }
  return *(const bf16x8*)((const u16*)base + idx);
}
// full-precision 8-element load (fp32 stays fp32; bf16 widened) -- router path.
// Top-k selection is discontinuous in the logits: router must NOT quantize.
__device__ __forceinline__ void loadf8(const void* p, size_t idx, int f,
                                       float* o) {
  if (f) {
    const float* q = (const float*)p + idx;
    float4 a = *(const float4*)q;
    float4 b = *(const float4*)(q + 4);
    o[0] = a.x; o[1] = a.y; o[2] = a.z; o[3] = a.w;
    o[4] = b.x; o[5] = b.y; o[6] = b.z; o[7] = b.w;
  } else {
    union { bf16x8 v; u16 s[8]; } u;
    u.v = *(const bf16x8*)((const u16*)p + idx);
#pragma unroll
    for (int j = 0; j < 8; ++j) o[j] = bf2f(u.s[j]);
  }
}

// fast exact-GELU: erf via Abramowitz-Stegun 7.1.26 (|err| 1.5e-7), native rcp/exp
__device__ __forceinline__ float fast_gelu(float v) {
  float x  = v * 0.70710678118654752f;
  float ax = fabsf(x);
  float t  = __builtin_amdgcn_rcpf(fmaf(0.3275911f, ax, 1.0f));
  float p  = fmaf(t, 1.061405429f, -1.453152027f);
  p = fmaf(t, p, 1.421413741f);
  p = fmaf(t, p, -0.284496736f);
  p = fmaf(t, p, 0.254829592f);
  p = p * t;
  float e  = __expf(-ax * ax);
  float er = fmaf(-p, e, 1.0f);          // erf(|x|)
  er = (x < 0.f) ? -er : er;
  return 0.5f * v * (1.0f + er);
}

// async 16B global->LDS. LDS dest is wave-uniform base; HW writes base+lane*16.
__device__ __forceinline__ void gll16(const void* g, void* l) {
  __builtin_amdgcn_global_load_lds(
      (const __attribute__((address_space(1))) void*)g,
      (__attribute__((address_space(3))) void*)l, 16, 0, 0);
}

// ===== BK=64 swizzled 128x128 core (rule #21: linear LDS dest, inverse-swz
// GLOBAL source, same swz on ds_read). 128B rows: bank = (u^(row&7))*4 mod 32
// -> 16-lane fragment reads spread over 8 bank-starts = 2-way (free).
// 32 MFMA per 2-barrier step (2x the BK=32 amortization).
// Tile layout: row = idx>>3, u = idx&7 (16B units), LDS slot idx = c*256+tid.
// Global source pre-swizzled: lane loads unit (u ^ (row&7)) of its row.
#define BK2 64
__device__ __forceinline__ void core128swz(
    const u16* gA0, const u16* gA1, const u16* gA2, const u16* gA3,
    const u16* gB0, const u16* gB1, const u16* gB2, const u16* gB3,
    int K, u16* As, u16* Bs, floatx4 acc[4][4],
    int wave, int wm, int wn, int r, int q) {
  const int rs = r & 7;                 // fragment-row low bits (R&7 == r&7)
  for (int k0 = 0; k0 < K; k0 += BK2) {
    __syncthreads();
    gll16(gA0 + k0, As + wave * 512);
    gll16(gA1 + k0, As + 2048 + wave * 512);
    gll16(gA2 + k0, As + 4096 + wave * 512);
    gll16(gA3 + k0, As + 6144 + wave * 512);
    gll16(gB0 + k0, Bs + wave * 512);
    gll16(gB1 + k0, Bs + 2048 + wave * 512);
    gll16(gB2 + k0, Bs + 4096 + wave * 512);
    gll16(gB3 + k0, Bs + 6144 + wave * 512);
    __syncthreads();   // compiler drains vmcnt before barrier
#pragma unroll
    for (int s = 0; s < 2; ++s) {       // two k=32 slabs per 64-elem row
      bf16x8 af[4], bfr[4];
#pragma unroll
      for (int mi = 0; mi < 4; ++mi) {
        int R = wm + mi * 16 + r;
        int u = (s * 4 + q) ^ rs;
        af[mi] = *(const bf16x8*)(As + R * 64 + u * 8);
      }
#pragma unroll
      for (int ni = 0; ni < 4; ++ni) {
        int R = wn + ni * 16 + r;
        int u = (s * 4 + q) ^ rs;
        bfr[ni] = *(const bf16x8*)(Bs + R * 64 + u * 8);
      }
#pragma unroll
      for (int mi = 0; mi < 4; ++mi)
#pragma unroll
        for (int ni = 0; ni < 4; ++ni)
          acc[mi][ni] = __builtin_amdgcn_mfma_f32_16x16x32_bf16(
              af[mi], bfr[ni], acc[mi][ni], 0, 0, 0);
    }
  }
}

// Probe: classify tensors fp32(1)/bf16(0); zero meta (fast path).
__global__ __launch_bounds__(256) void detect_kernel(
    const void* x, const void* gw, const void* sw1, const void* sw2,
    const void* rw1, const void* rw2, int* flags, int* meta) {
  __shared__ int cnt;
  __shared__ int sflags[6];
  const void* ptrs[6] = {x, gw, sw1, sw2, rw1, rw2};
  for (int tnum = 0; tnum < 6; ++tnum) {
    if (threadIdx.x == 0) cnt = 0;
    __syncthreads();
    const u16* p = (const u16*)ptrs[tnum];
    int local = 0;
    for (int i = threadIdx.x; i < 4096; i += 256) {
      unsigned ef = (p[i] >> 7) & 0xFFu;
      if (ef >= 0xE0u) ++local;
    }
    if (local) atomicAdd(&cnt, local);
    __syncthreads();
    if (threadIdx.x == 0) sflags[tnum] = (cnt >= 16) ? 1 : 0;
    __syncthreads();
  }
  if (threadIdx.x == 0) {
#pragma unroll
    for (int i = 0; i < 6; ++i) flags[i] = sflags[i];
    flags[6] = sflags[0];  // output dtype follows x
    flags[7] = 0;          // ws bf16 buffers
  }
  if (meta && threadIdx.x < 24) meta[threadIdx.x] = 0;
}

// convert only if fp32; bf16 inputs are consumed raw by the GEMMs (skip-copy).
__global__ __launch_bounds__(256) void conv_kernel(
    const void* __restrict__ src, u16* __restrict__ dst,
    const int* __restrict__ flags, int idx, size_t n) {
  int f = flags[idx];
  if (!f) return;               // bf16: raw tensor used directly downstream
  size_t i = ((size_t)blockIdx.x * 256 + threadIdx.x) * 8;
  if (i >= n) return;
  *(bf16x8*)(dst + i) = load8(src, i, f);
}

// Router: FULL-precision logits (raw x, raw gw), vectorized 16B loads.
__global__ __launch_bounds__(256) void router_v(
    const void* __restrict__ x, const void* __restrict__ gw,
    const u16* __restrict__ gb, const int* __restrict__ flags,
    float* __restrict__ cw, int2* __restrict__ tix) {
  int wave = threadIdx.x >> 6, lane = threadIdx.x & 63;
  int t = blockIdx.x * 4 + wave;
  int fx = flags[0], fg = flags[1];
  float xf[8];
  loadf8(x, (size_t)t * DD + lane * 8, fx, xf);
  float acc[EE];
#pragma unroll
  for (int e = 0; e < EE; ++e) {
    float gf[8];
    loadf8(gw, (size_t)e * DD + lane * 8, fg, gf);
    float a = 0.f;
#pragma unroll
    for (int j = 0; j < 8; ++j) a = fmaf(xf[j], gf[j], a);
    acc[e] = a;
  }
#pragma unroll
  for (int e = 0; e < EE; ++e) {
    float v = acc[e];
#pragma unroll
    for (int off = 32; off > 0; off >>= 1) v += __shfl_xor(v, off, 64);
    acc[e] = v;
  }
  if (lane == 0) {
    float m = -1e30f;
#pragma unroll
    for (int e = 0; e < EE; ++e) {
      acc[e] += bf2f(gb[e]);   // all-zero: dtype-agnostic
      m = fmaxf(m, acc[e]);
    }
    float p[EE], s = 0.f;
#pragma unroll
    for (int e = 0; e < EE; ++e) { p[e] = expf(acc[e] - m); s += p[e]; }
    int i1 = 0;
#pragma unroll
    for (int e = 1; e < EE; ++e) if (p[e] > p[i1]) i1 = e;
    int i2 = (i1 == 0) ? 1 : 0;
#pragma unroll
    for (int e = 0; e < EE; ++e)
      if (e != i1 && p[e] > p[i2]) i2 = e;
    float inv = 1.0f / s;
#pragma unroll
    for (int e = 0; e < EE; ++e)
      cw[t * EE + e] = (e == i1 || e == i2) ? p[e] * inv : 0.0f;
    tix[t] = make_int2(i1, i2);
  }
}

// meta: [0..7]=cnt, [8..15]=pc (padded), [16..23]=row prefix
__global__ __launch_bounds__(256) void build_lists(
    const int2* __restrict__ tix, int* __restrict__ meta,
    unsigned* __restrict__ list, int4* __restrict__ srec) {
  int t = blockIdx.x * 256 + threadIdx.x;
  if (t >= T_TOK) return;
  int2 ii = tix[t];
  int p0 = atomicAdd(&meta[ii.x], 1);
  list[(size_t)ii.x * CAP + p0] = (unsigned)t;
  int p1 = atomicAdd(&meta[ii.y], 1);
  list[(size_t)ii.y * CAP + p1] = (unsigned)t;
  srec[t] = make_int4(ii.x, p0, ii.y, p1);
}
__global__ __launch_bounds__(256) void pad_lists(int* meta, unsigned* list) {
  if (threadIdx.x == 0) {
    int off = 0;
    for (int e = 0; e < EE; ++e) {
      int c = meta[e];
      int pc = (c + BM - 1) & ~(BM - 1);
      meta[8 + e] = pc;
      meta[16 + e] = off;
      off += pc;
    }
  }
  __syncthreads();
#pragma unroll
  for (int e = 0; e < EE; ++e) {
    int c = meta[e], pc = meta[8 + e];
    int i = c + threadIdx.x;
    if (i < pc) list[(size_t)e * CAP + i] = PADF;
  }
}

// ========== fast path: swizzled BK=64 128x128 GEMMs ==========

// FFN1 (shared + routed gather) in ONE dispatch.
// grid (16, T/BM, 2+EE)
__global__ __launch_bounds__(256) void g1_fused(
    const void* __restrict__ xr, const u16* __restrict__ xb,
    const void* __restrict__ s1r, const u16* __restrict__ s1b,
    const u16* __restrict__ sb1,
    const void* __restrict__ r1r, const u16* __restrict__ r1b,
    const u16* __restrict__ rb1, const unsigned* __restrict__ list,
    const int* __restrict__ meta, const int* __restrict__ flags,
    u16* __restrict__ Hsh, u16* __restrict__ Hrt) {
  // skip-copy: raw tensor when already bf16
  const u16* xp  = flags[0] ? xb  : (const u16*)xr;
  const u16* s1p = flags[2] ? s1b : (const u16*)s1r;
  const u16* r1p = flags[4] ? r1b : (const u16*)r1r;

  int z = blockIdx.z;
  int bm = blockIdx.y * BM;
  int tid = threadIdx.x, lane = tid & 63, wave = tid >> 6;
  int wm = (wave >> 1) * 64, wn = (wave & 1) * 64;
  int r = lane & 15, q = lane >> 4;
  const int K = DD;

  // staging geometry: idx = c*256+tid; row = c*32 + (tid>>3); unit = tid&7
  int rsub = tid >> 3;
  int us = (tid & 7) ^ (rsub & 7);   // pre-swizzled source unit

  __shared__ u16 As[BM * BK2];   // 16KB
  __shared__ u16 Bs[BN * BK2];   // 16KB

  const u16 *gA[4], *gB[4];
  int e = 0, ho = 0, bn;
  if (z < 2) {
    bn = (z * 16 + blockIdx.x) * BN;
#pragma unroll
    for (int c = 0; c < 4; ++c) {
      gA[c] = xp + (size_t)(bm + c * 32 + rsub) * K + us * 8;
      gB[c] = s1p + (size_t)(bn + c * 32 + rsub) * K + us * 8;
    }
  } else {
    e = z - 2;
    if (bm >= meta[8 + e]) return;
    ho = meta[16 + e];
    bn = blockIdx.x * BN;
#pragma unroll
    for (int c = 0; c < 4; ++c) {
      unsigned tk = list[(size_t)e * CAP + bm + c * 32 + rsub] & 0x7fffffffu;
      gA[c] = xp + (size_t)tk * K + us * 8;
      gB[c] = r1p + (size_t)e * FF * DD + (size_t)(bn + c * 32 + rsub) * K +
              us * 8;
    }
  }

  floatx4 acc[4][4];
  floatx4 zero = {0.f, 0.f, 0.f, 0.f};
#pragma unroll
  for (int i = 0; i < 4; ++i)
#pragma unroll
    for (int j = 0; j < 4; ++j) acc[i][j] = zero;

  core128swz(gA[0], gA[1], gA[2], gA[3], gB[0], gB[1], gB[2], gB[3],
             K, As, Bs, acc, wave, wm, wn, r, q);

  if (z < 2) {
#pragma unroll
    for (int mi = 0; mi < 4; ++mi)
#pragma unroll
      for (int ni = 0; ni < 4; ++ni) {
        int col = bn + wn + ni * 16 + r;
        float bv = bf2f(sb1[col]);
#pragma unroll
        for (int rr = 0; rr < 4; ++rr) {
          int row = bm + wm + mi * 16 + q * 4 + rr;
          float v = acc[mi][ni][rr] + bv;
          Hsh[(size_t)row * (NSH * FF) + col] = f2bf(fast_gelu(v));
        }
      }
  } else {
#pragma unroll
    for (int mi = 0; mi < 4; ++mi)
#pragma unroll
      for (int ni = 0; ni < 4; ++ni) {
        int col = bn + wn + ni * 16 + r;
        float bv = bf2f(rb1[(size_t)e * FF + col]);
#pragma unroll
        for (int rr = 0; rr < 4; ++rr) {
          int slot = bm + wm + mi * 16 + q * 4 + rr;
          float v = acc[mi][ni][rr] + bv;
          Hrt[(size_t)(ho + slot) * FF + col] = f2bf(fast_gelu(v));
        }
      }
  }
}

// FFN2 (shared planes + routed compact) in ONE dispatch.
// grid (DD/BN=4, CAP/BM=32, NSH+EE)
__global__ __launch_bounds__(256) void g2_fused(
    const u16* __restrict__ Hsh,
    const void* __restrict__ s2r, const u16* __restrict__ s2b,
    const u16* __restrict__ sb2, const u16* __restrict__ Hrt,
    const void* __restrict__ r2r, const u16* __restrict__ r2b,
    const u16* __restrict__ rb2,
    const unsigned* __restrict__ list, const int* __restrict__ meta,
    const int* __restrict__ flags, const float* __restrict__ cw,
    float* __restrict__ oacc, float* __restrict__ Ort) {
  const u16* s2p = flags[3] ? s2b : (const u16*)s2r;
  const u16* r2p = flags[5] ? r2b : (const u16*)r2r;

  int z = blockIdx.z;
  int bm = blockIdx.y * BM;
  int bn = blockIdx.x * BN;
  int tid = threadIdx.x, lane = tid & 63, wave = tid >> 6;
  int wm = (wave >> 1) * 64, wn = (wave & 1) * 64;
  int r = lane & 15, q = lane >> 4;
  const int K = FF;

  int rsub = tid >> 3;
  int us = (tid & 7) ^ (rsub & 7);

  __shared__ u16 As[BM * BK2];
  __shared__ u16 Bs[BN * BK2];

  const u16 *gA[4], *gB[4];
  int e = 0, ho = 0;
  if (z < NSH) {
    const int ldA = NSH * FF;
#pragma unroll
    for (int c = 0; c < 4; ++c) {
      gA[c] = Hsh + (size_t)(bm + c * 32 + rsub) * ldA + (size_t)z * FF +
              us * 8;
      gB[c] = s2p + (size_t)z * DD * FF + (size_t)(bn + c * 32 + rsub) * K +
              us * 8;
    }
  } else {
    e = z - NSH;
    if (bm >= meta[8 + e]) return;
    ho = meta[16 + e];
#pragma unroll
    for (int c = 0; c < 4; ++c) {
      gA[c] = Hrt + (size_t)(ho + bm + c * 32 + rsub) * K + us * 8;
      gB[c] = r2p + (size_t)e * DD * FF + (size_t)(bn + c * 32 + rsub) * K +
              us * 8;
    }
  }

  floatx4 acc[4][4];
  floatx4 zero = {0.f, 0.f, 0.f, 0.f};
#pragma unroll
  for (int i = 0; i < 4; ++i)
#pragma unroll
    for (int j = 0; j < 4; ++j) acc[i][j] = zero;

  core128swz(gA[0], gA[1], gA[2], gA[3], gB[0], gB[1], gB[2], gB[3],
             K, As, Bs, acc, wave, wm, wn, r, q);

  if (z < NSH) {
    float* op = oacc + (size_t)z * T_TOK * DD;
#pragma unroll
    for (int mi = 0; mi < 4; ++mi)
#pragma unroll
      for (int ni = 0; ni < 4; ++ni) {
        int col = bn + wn + ni * 16 + r;
        float bv = bf2f(sb2[(size_t)z * DD + col]);
#pragma unroll
        for (int rr = 0; rr < 4; ++rr) {
          int row = bm + wm + mi * 16 + q * 4 + rr;
          op[(size_t)row * DD + col] = acc[mi][ni][rr] + bv;
        }
      }
  } else {
#pragma unroll
    for (int mi = 0; mi < 4; ++mi)
#pragma unroll
      for (int rr = 0; rr < 4; ++rr) {
        int slot = bm + wm + mi * 16 + q * 4 + rr;
        unsigned raw = list[(size_t)e * CAP + slot];
        if (raw & PADF) continue;
        float s = cw[raw * EE + e];
#pragma unroll
        for (int ni = 0; ni < 4; ++ni) {
          int col = bn + wn + ni * 16 + r;
          float v = acc[mi][ni][rr] + bf2f(rb2[(size_t)e * DD + col]);
          Ort[(size_t)(ho + slot) * DD + col] = s * v;
        }
      }
  }
}

// final: out[t] = oacc0[t] + oacc1[t] + Ort[g0(t)] + Ort[g1(t)]
typedef struct { u16 a, b, c, d; } u16x4;
__global__ __launch_bounds__(256) void combine_out(
    const float* __restrict__ oacc, const float* __restrict__ Ort,
    const int4* __restrict__ srec, const int* __restrict__ meta,
    void* __restrict__ out, const int* __restrict__ flags) {
  int t  = blockIdx.x * 2 + (threadIdx.x >> 7);
  int c4 = (threadIdx.x & 127) * 4;
  int4 sr = srec[t];
  int g0 = meta[16 + sr.x] + sr.y;
  int g1 = meta[16 + sr.z] + sr.w;
  float4 a = *(const float4*)(oacc + (size_t)t * DD + c4);
  float4 b = *(const float4*)(oacc + (size_t)(T_TOK + t) * DD + c4);
  float4 u = *(const float4*)(Ort + (size_t)g0 * DD + c4);
  float4 v = *(const float4*)(Ort + (size_t)g1 * DD + c4);
  float o0 = a.x + b.x + u.x + v.x;
  float o1 = a.y + b.y + u.y + v.y;
  float o2 = a.z + b.z + u.z + v.z;
  float o3 = a.w + b.w + u.w + v.w;
  size_t idx = (size_t)t * DD + c4;
  if (flags[6]) {
    *(float4*)((float*)out + idx) = make_float4(o0, o1, o2, o3);
  } else {
    u16x4 h = {f2bf(o0), f2bf(o1), f2bf(o2), f2bf(o3)};
    *(u16x4*)((u16*)out + idx) = h;
  }
}

// ---------------- fallback-path kernels (dense, unconverted) ----------------
__device__ __forceinline__ void gemm_core(const void* A, size_t aoff, int fA,
                                          const void* B, size_t boff, int fB,
                                          int K, u16* As, u16* Bs,
                                          floatx4 acc[4][4]) {
  int tid  = threadIdx.x;
  int lane = tid & 63, wave = tid >> 6;
  int wm = (wave >> 1) * 64, wn = (wave & 1) * 64;
  int r = lane & 15, q = lane >> 4;
  int srow = tid >> 2;
  int sc8  = (tid & 3) * 8;
  size_t abase = aoff + (size_t)srow * K + sc8;
  size_t bbase = boff + (size_t)srow * K + sc8;
  const size_t half = (size_t)64 * K;

  for (int k0 = 0; k0 < K; k0 += BK) {
    bf16x8 av0 = load8(A, abase + k0, fA);
    bf16x8 av1 = load8(A, abase + half + k0, fA);
    bf16x8 bv0 = load8(B, bbase + k0, fB);
    bf16x8 bv1 = load8(B, bbase + half + k0, fB);
    __syncthreads();
    *(bf16x8*)(As + srow * LDK + sc8)        = av0;
    *(bf16x8*)(As + (srow + 64) * LDK + sc8) = av1;
    *(bf16x8*)(Bs + srow * LDK + sc8)        = bv0;
    *(bf16x8*)(Bs + (srow + 64) * LDK + sc8) = bv1;
    __syncthreads();

    bf16x8 af[4], bfr[4];
#pragma unroll
    for (int mi = 0; mi < 4; ++mi)
      af[mi] = *(const bf16x8*)(As + (wm + mi * 16 + r) * LDK + q * 8);
#pragma unroll
    for (int ni = 0; ni < 4; ++ni)
      bfr[ni] = *(const bf16x8*)(Bs + (wn + ni * 16 + r) * LDK + q * 8);
#pragma unroll
    for (int mi = 0; mi < 4; ++mi)
#pragma unroll
      for (int ni = 0; ni < 4; ++ni)
        acc[mi][ni] = __builtin_amdgcn_mfma_f32_16x16x32_bf16(
            af[mi], bfr[ni], acc[mi][ni], 0, 0, 0);
  }
}

__global__ __launch_bounds__(256) void gemm1_gelu(
    const void* __restrict__ A, size_t aoff, const void* __restrict__ B,
    size_t boff, const u16* __restrict__ bias, size_t bioff,
    u16* __restrict__ H, const int* __restrict__ flags, int iA, int iB,
    int N, int K) {
  __shared__ u16 As[BM * LDK];
  __shared__ u16 Bs[BN * LDK];
  int fA = flags[iA], fB = flags[iB];
  floatx4 acc[4][4];
  floatx4 zero = {0.f, 0.f, 0.f, 0.f};
#pragma unroll
  for (int i = 0; i < 4; ++i)
#pragma unroll
    for (int j = 0; j < 4; ++j) acc[i][j] = zero;

  int bm = blockIdx.y * BM, bn = blockIdx.x * BN;
  gemm_core(A, aoff + (size_t)bm * K, fA, B, boff + (size_t)bn * K, fB, K,
            As, Bs, acc);

  int tid = threadIdx.x, wave = tid >> 6, lane = tid & 63;
  int wm = (wave >> 1) * 64, wn = (wave & 1) * 64;
  int r = lane & 15, q = lane >> 4;
#pragma unroll
  for (int mi = 0; mi < 4; ++mi)
#pragma unroll
    for (int ni = 0; ni < 4; ++ni) {
      int col = bn + wn + ni * 16 + r;
      float bv = bf2f(bias[bioff + col]);
#pragma unroll
      for (int rr = 0; rr < 4; ++rr) {
        int row = bm + wm + mi * 16 + q * 4 + rr;
        float v = acc[mi][ni][rr] + bv;
        H[(size_t)row * N + col] = f2bf(fast_gelu(v));
      }
    }
}

__global__ __launch_bounds__(256) void gemm2_acc(
    const u16* __restrict__ A, const void* __restrict__ B, size_t boff,
    const u16* __restrict__ bias, size_t bioff, float* __restrict__ outf,
    void* __restrict__ outb, const float* __restrict__ cw,
    const int* __restrict__ flags, int iB, int expert, int accum,
    int row0, int N, int K) {
  __shared__ u16 As[BT2 * LDK];
  __shared__ u16 Bs[BT2 * LDK];
  int fB = flags[iB], fO = flags[6];
  floatx4 acc[2][2];
  floatx4 zero = {0.f, 0.f, 0.f, 0.f};
#pragma unroll
  for (int i = 0; i < 2; ++i)
#pragma unroll
    for (int j = 0; j < 2; ++j) acc[i][j] = zero;

  int bm = blockIdx.y * BT2, bn = blockIdx.x * BT2;
  int tid  = threadIdx.x;
  int lane = tid & 63, wave = tid >> 6;
  int wm = (wave >> 1) * 32, wn = (wave & 1) * 32;
  int r = lane & 15, q = lane >> 4;
  int srow = tid >> 2;
  int sc8  = (tid & 3) * 8;
  size_t abase = (size_t)(bm + srow) * K + sc8;
  size_t bbase = boff + (size_t)(bn + srow) * K + sc8;

  for (int k0 = 0; k0 < K; k0 += BK) {
    bf16x8 av = *(const bf16x8*)(A + abase + k0);
    bf16x8 bv = load8(B, bbase + k0, fB);
    __syncthreads();
    *(bf16x8*)(As + srow * LDK + sc8) = av;
    *(bf16x8*)(Bs + srow * LDK + sc8) = bv;
    __syncthreads();

    bf16x8 af[2], bfr[2];
#pragma unroll
    for (int mi = 0; mi < 2; ++mi)
      af[mi] = *(const bf16x8*)(As + (wm + mi * 16 + r) * LDK + q * 8);
#pragma unroll
    for (int ni = 0; ni < 2; ++ni)
      bfr[ni] = *(const bf16x8*)(Bs + (wn + ni * 16 + r) * LDK + q * 8);
#pragma unroll
    for (int mi = 0; mi < 2; ++mi)
#pragma unroll
      for (int ni = 0; ni < 2; ++ni)
        acc[mi][ni] = __builtin_amdgcn_mfma_f32_16x16x32_bf16(
            af[mi], bfr[ni], acc[mi][ni], 0, 0, 0);
  }

#pragma unroll
  for (int mi = 0; mi < 2; ++mi)
#pragma unroll
    for (int rr = 0; rr < 4; ++rr) {
      int grow = row0 + bm + wm + mi * 16 + q * 4 + rr;
      float s = cw ? cw[grow * EE + expert] : 1.0f;
#pragma unroll
      for (int ni = 0; ni < 2; ++ni) {
        int col = bn + wn + ni * 16 + r;
        float v = acc[mi][ni][rr] + bf2f(bias[bioff + col]);
        size_t idx = (size_t)grow * N + col;
        if (outf) {
          float prev = accum ? outf[idx] : 0.0f;
          outf[idx] = prev + s * v;
        } else if (fO) {
          float* ob = (float*)outb;
          float prev = accum ? ob[idx] : 0.0f;
          ob[idx] = prev + s * v;
        } else {
          u16* ob = (u16*)outb;
          float prev = accum ? bf2f(ob[idx]) : 0.0f;
          ob[idx] = f2bf(prev + s * v);
        }
      }
    }
}

__global__ __launch_bounds__(256) void convert_out(
    const float* __restrict__ acc, void* __restrict__ out,
    const int* __restrict__ flags, int n) {
  int i = blockIdx.x * blockDim.x + threadIdx.x;
  if (i >= n) return;
  if (flags[6]) ((float*)out)[i] = acc[i];
  else ((u16*)out)[i] = f2bf(acc[i]);
}

extern "C" void kernel_launch(void* const* d_in, const int* in_sizes, int n_in,
                              void* d_out, int out_size, void* d_ws, size_t ws_size,
                              hipStream_t stream) {
  (void)in_sizes; (void)n_in; (void)out_size;
  const void* x   = d_in[0];
  const void* gw  = d_in[1];
  const u16*  gb  = (const u16*)d_in[2];
  const void* sw1 = d_in[3];
  const u16*  sb1 = (const u16*)d_in[4];
  const void* sw2 = d_in[5];
  const u16*  sb2 = (const u16*)d_in[6];
  const void* rw1 = d_in[7];
  const u16*  rb1 = (const u16*)d_in[8];
  const void* rw2 = d_in[9];
  const u16*  rb2 = (const u16*)d_in[10];

  const size_t NX   = (size_t)T_TOK * DD;
  const size_t NW1S = (size_t)NSH * FF * DD;
  const size_t NW1R = (size_t)EE * FF * DD;
  const size_t NW2S = (size_t)NSH * DD * FF;
  const size_t NW2R = (size_t)EE * DD * FF;

  // fast-path layout
  size_t off = 0;
  const size_t flO   = off; off += 256;
  const size_t cwO   = off; off += (size_t)T_TOK * EE * 4;
  const size_t tixO  = off; off += (size_t)T_TOK * 8;
  const size_t metaO = off; off += 256;
  const size_t listO = off; off += (size_t)EE * CAP * 4;
  const size_t srecO = off; off += (size_t)T_TOK * 16;
  const size_t accO  = off; off += (size_t)NSH * T_TOK * DD * 4;
  const size_t hshO  = off; off += (size_t)T_TOK * NSH * FF * 2;
  const size_t hrtO  = off; off += (size_t)NSLOT * FF * 2;
  const size_t ortO  = off; off += (size_t)NSLOT * DD * 4;
  const size_t xbO   = off; off += NX * 2;
  const size_t s1O   = off; off += NW1S * 2;
  const size_t r1O   = off; off += NW1R * 2;
  const size_t s2O   = off; off += NW2S * 2;
  const size_t r2O   = off; off += NW2R * 2;
  const int fast = (off <= ws_size) ? 1 : 0;

  char* ws = (char*)d_ws;
  int*   flags = (int*)(ws + flO);
  float* cw    = (float*)(ws + cwO);
  dim3 blk(256);

  if (fast) {
    int2*     tix  = (int2*)(ws + tixO);
    int*      meta = (int*)(ws + metaO);
    unsigned* list = (unsigned*)(ws + listO);
    int4*     srec = (int4*)(ws + srecO);
    float*    oacc = (float*)(ws + accO);
    u16*      Hsh  = (u16*)(ws + hshO);
    u16*      Hrt  = (u16*)(ws + hrtO);
    float*    Ort  = (float*)(ws + ortO);
    u16*      xb   = (u16*)(ws + xbO);
    u16*      s1b  = (u16*)(ws + s1O);
    u16*      r1b  = (u16*)(ws + r1O);
    u16*      s2b  = (u16*)(ws + s2O);
    u16*      r2b  = (u16*)(ws + r2O);

    detect_kernel<<<1, 256, 0, stream>>>(x, gw, sw1, sw2, rw1, rw2, flags,
                                         meta);
    conv_kernel<<<NX   / 2048, 256, 0, stream>>>(x,   xb,  flags, 0, NX);
    conv_kernel<<<NW1S / 2048, 256, 0, stream>>>(sw1, s1b, flags, 2, NW1S);
    conv_kernel<<<NW1R / 2048, 256, 0, stream>>>(rw1, r1b, flags, 4, NW1R);
    conv_kernel<<<NW2S / 2048, 256, 0, stream>>>(sw2, s2b, flags, 3, NW2S);
    conv_kernel<<<NW2R / 2048, 256, 0, stream>>>(rw2, r2b, flags, 5, NW2R);
    router_v<<<T_TOK / 4, 256, 0, stream>>>(x, gw, gb, flags, cw, tix);
    build_lists<<<T_TOK / 256, 256, 0, stream>>>(tix, meta, list, srec);
    pad_lists<<<1, 256, 0, stream>>>(meta, list);

    // FFN1: shared (z<2) + routed gather (z>=2), one dispatch
    dim3 gf1(16, T_TOK / BM, 2 + EE);            // 16 x 32 x 10
    g1_fused<<<gf1, blk, 0, stream>>>(x, xb, sw1, s1b, sb1, rw1, r1b, rb1,
                                      list, meta, flags, Hsh, Hrt);
    // FFN2: shared planes (z<NSH) + routed compact (z>=NSH), one dispatch
    dim3 gf2(DD / BN, CAP / BM, NSH + EE);       // 4 x 32 x 10
    g2_fused<<<gf2, blk, 0, stream>>>(Hsh, sw2, s2b, sb2, Hrt, rw2, r2b, rb2,
                                      list, meta, flags, cw, oacc, Ort);
    combine_out<<<T_TOK / 2, 256, 0, stream>>>(oacc, Ort, srec, meta, d_out,
                                               flags);
    return;
  }

  // -------- fallback: dense all-FFN path (no conversion), ws-adaptive --------
  detect_kernel<<<1, 256, 0, stream>>>(x, gw, sw1, sw2, rw1, rw2, flags,
                                       nullptr);
  const size_t flB = 256, cwB = (size_t)T_TOK * EE * 4, tixB = (size_t)T_TOK * 8;
  const size_t accB = (size_t)T_TOK * DD * 4;
  static const int tcs[4] = {4096, 2048, 1024, 512};
  int TC = 0, use_f32 = 1;
  for (int i = 0; i < 4; ++i)
    if (flB + cwB + tixB + accB + (size_t)tcs[i] * FF * 2 <= ws_size) { TC = tcs[i]; break; }
  if (!TC) {
    use_f32 = 0;
    for (int i = 0; i < 4; ++i)
      if (flB + cwB + tixB + (size_t)tcs[i] * FF * 2 <= ws_size) { TC = tcs[i]; break; }
  }
  if (!TC) { TC = 512; use_f32 = 0; }

  int2*  tix     = (int2*)(ws + flB + cwB);
  float* out_acc = use_f32 ? (float*)(ws + flB + cwB + tixB) : nullptr;
  u16*   H       = (u16*)(ws + flB + cwB + tixB + (use_f32 ? accB : 0));

  router_v<<<T_TOK / 4, 256, 0, stream>>>(x, gw, gb, flags, cw, tix);
  dim3 g1(FF / BN, TC / BM);
  dim3 g2(DD / BT2, TC / BT2);
  const int nchunk = T_TOK / TC;
  for (int f = 0; f < NSH + EE; ++f) {
    const void *w1, *w2; const u16 *b1, *b2; const float* cwp;
    int expert, i1, i2v; size_t w1off, w2off, b1off, b2off;
    if (f < NSH) {
      w1 = sw1; w2 = sw2; b1 = sb1; b2 = sb2;
      w1off = (size_t)f * FF * DD; w2off = (size_t)f * DD * FF;
      b1off = (size_t)f * FF; b2off = (size_t)f * DD;
      cwp = nullptr; expert = 0; i1 = 2; i2v = 3;
    } else {
      int e = f - NSH;
      w1 = rw1; w2 = rw2; b1 = rb1; b2 = rb2;
      w1off = (size_t)e * FF * DD; w2off = (size_t)e * DD * FF;
      b1off = (size_t)e * FF; b2off = (size_t)e * DD;
      cwp = cw; expert = e; i1 = 4; i2v = 5;
    }
    int accum = (f > 0) ? 1 : 0;
    for (int c = 0; c < nchunk; ++c) {
      size_t t0 = (size_t)c * TC;
      gemm1_gelu<<<g1, blk, 0, stream>>>(x, t0 * DD, w1, w1off, b1, b1off, H,
                                         flags, 0, i1, FF, DD);
      gemm2_acc<<<g2, blk, 0, stream>>>(H, w2, w2off, b2, b2off, out_acc,
                                        d_out, cwp, flags, i2v, expert, accum,
                                        (int)t0, DD, FF);
    }
  }
  if (use_f32)
    convert_out<<<(T_TOK * DD) / 256, 256, 0, stream>>>(out_acc, d_out, flags,
                                                        T_TOK * DD);
}

// Round 7
// 374.747 us; speedup vs baseline: 1.0019x; 1.0019x over previous
//
#include <hip/hip_runtime.h>
#include <math.h>

typedef unsigned short u16;
typedef __attribute__((ext_vector_type(8))) __bf16 bf16x8;
typedef __attribute__((ext_vector_type(4))) float floatx4;

#define T_TOK 4096
#define DD    512
#define FF    2048
#define EE    8
#define NSH   2

#define BM 128
#define BN 128
#define BK 32
#define LDK 40   // fallback kernels: padded LDS row stride
#define BT2 64   // fallback gemm2 N-tile
#define CAP 4096
#define PADF 0x80000000u
#define NSLOT (2 * T_TOK + EE * BM)   // 9216 compact rows max

__device__ __forceinline__ float bf2f(u16 v) {
  union { unsigned int u; float f; } c; c.u = ((unsigned int)v) << 16; return c.f;
}
__device__ __forceinline__ u16 f2bf(float f) {
  union { float ff; unsigned int u; } c; c.ff = f;
  unsigned int u = c.u;
  u += 0x7fffu + ((u >> 16) & 1u);   // RNE
  return (u16)(u >> 16);
}
__device__ __forceinline__ float decode(const void* p, size_t idx, int f) {
  return f ? ((const float*)p)[idx] : bf2f(((const u16*)p)[idx]);
}
__device__ __forceinline__ bf16x8 load8(const void* base, size_t idx, int f) {
  if (f) {
    const float* p = (const float*)base + idx;
    float4 a = *(const float4*)p;
    float4 b = *(const float4*)(p + 4);
    union { bf16x8 v; u16 s[8]; } u;
    u.s[0] = f2bf(a.x); u.s[1] = f2bf(a.y); u.s[2] = f2bf(a.z); u.s[3] = f2bf(a.w);
    u.s[4] = f2bf(b.x); u.s[5] = f2bf(b.y); u.s[6] = f2bf(b.z); u.s[7] = f2bf(b.w);
    return u.v;
  }
  return *(const bf16x8*)((const u16*)base + idx);
}
// full-precision 8-element load (fp32 stays fp32; bf16 widened) -- router path.
// Top-k selection is discontinuous in the logits: router must NOT quantize.
__device__ __forceinline__ void loadf8(const void* p, size_t idx, int f,
                                       float* o) {
  if (f) {
    const float* q = (const float*)p + idx;
    float4 a = *(const float4*)q;
    float4 b = *(const float4*)(q + 4);
    o[0] = a.x; o[1] = a.y; o[2] = a.z; o[3] = a.w;
    o[4] = b.x; o[5] = b.y; o[6] = b.z; o[7] = b.w;
  } else {
    union { bf16x8 v; u16 s[8]; } u;
    u.v = *(const bf16x8*)((const u16*)p + idx);
#pragma unroll
    for (int j = 0; j < 8; ++j) o[j] = bf2f(u.s[j]);
  }
}

// fast exact-GELU: erf via Abramowitz-Stegun 7.1.26 (|err| 1.5e-7), native rcp/exp
__device__ __forceinline__ float fast_gelu(float v) {
  float x  = v * 0.70710678118654752f;
  float ax = fabsf(x);
  float t  = __builtin_amdgcn_rcpf(fmaf(0.3275911f, ax, 1.0f));
  float p  = fmaf(t, 1.061405429f, -1.453152027f);
  p = fmaf(t, p, 1.421413741f);
  p = fmaf(t, p, -0.284496736f);
  p = fmaf(t, p, 0.254829592f);
  p = p * t;
  float e  = __expf(-ax * ax);
  float er = fmaf(-p, e, 1.0f);          // erf(|x|)
  er = (x < 0.f) ? -er : er;
  return 0.5f * v * (1.0f + er);
}

// async 16B global->LDS. LDS dest is wave-uniform base; HW writes base+lane*16.
__device__ __forceinline__ void gll16(const void* g, void* l) {
  __builtin_amdgcn_global_load_lds(
      (const __attribute__((address_space(1))) void*)g,
      (__attribute__((address_space(3))) void*)l, 16, 0, 0);
}

// ===== BK=64 swizzled 128x128 core (rule #21: linear LDS dest, inverse-swz
// GLOBAL source, same swz on ds_read). Conflict-free verified (round 6:
// SQ_LDS_BANK_CONFLICT 4.29M -> 0). 32 MFMA per 2-barrier step.
#define BK2 64
__device__ __forceinline__ void core128swz(
    const u16* gA0, const u16* gA1, const u16* gA2, const u16* gA3,
    const u16* gB0, const u16* gB1, const u16* gB2, const u16* gB3,
    int K, u16* As, u16* Bs, floatx4 acc[4][4],
    int wave, int wm, int wn, int r, int q) {
  const int rs = r & 7;                 // fragment-row low bits (R&7 == r&7)
  for (int k0 = 0; k0 < K; k0 += BK2) {
    __syncthreads();
    gll16(gA0 + k0, As + wave * 512);
    gll16(gA1 + k0, As + 2048 + wave * 512);
    gll16(gA2 + k0, As + 4096 + wave * 512);
    gll16(gA3 + k0, As + 6144 + wave * 512);
    gll16(gB0 + k0, Bs + wave * 512);
    gll16(gB1 + k0, Bs + 2048 + wave * 512);
    gll16(gB2 + k0, Bs + 4096 + wave * 512);
    gll16(gB3 + k0, Bs + 6144 + wave * 512);
    __syncthreads();   // compiler drains vmcnt before barrier
#pragma unroll
    for (int s = 0; s < 2; ++s) {       // two k=32 slabs per 64-elem row
      bf16x8 af[4], bfr[4];
#pragma unroll
      for (int mi = 0; mi < 4; ++mi) {
        int R = wm + mi * 16 + r;
        int u = (s * 4 + q) ^ rs;
        af[mi] = *(const bf16x8*)(As + R * 64 + u * 8);
      }
#pragma unroll
      for (int ni = 0; ni < 4; ++ni) {
        int R = wn + ni * 16 + r;
        int u = (s * 4 + q) ^ rs;
        bfr[ni] = *(const bf16x8*)(Bs + R * 64 + u * 8);
      }
#pragma unroll
      for (int mi = 0; mi < 4; ++mi)
#pragma unroll
        for (int ni = 0; ni < 4; ++ni)
          acc[mi][ni] = __builtin_amdgcn_mfma_f32_16x16x32_bf16(
              af[mi], bfr[ni], acc[mi][ni], 0, 0, 0);
    }
  }
}

// Probe: classify tensors fp32(1)/bf16(0); zero meta (fast path).
__global__ __launch_bounds__(256) void detect_kernel(
    const void* x, const void* gw, const void* sw1, const void* sw2,
    const void* rw1, const void* rw2, int* flags, int* meta) {
  __shared__ int cnt;
  __shared__ int sflags[6];
  const void* ptrs[6] = {x, gw, sw1, sw2, rw1, rw2};
  for (int tnum = 0; tnum < 6; ++tnum) {
    if (threadIdx.x == 0) cnt = 0;
    __syncthreads();
    const u16* p = (const u16*)ptrs[tnum];
    int local = 0;
    for (int i = threadIdx.x; i < 4096; i += 256) {
      unsigned ef = (p[i] >> 7) & 0xFFu;
      if (ef >= 0xE0u) ++local;
    }
    if (local) atomicAdd(&cnt, local);
    __syncthreads();
    if (threadIdx.x == 0) sflags[tnum] = (cnt >= 16) ? 1 : 0;
    __syncthreads();
  }
  if (threadIdx.x == 0) {
#pragma unroll
    for (int i = 0; i < 6; ++i) flags[i] = sflags[i];
    flags[6] = sflags[0];  // output dtype follows x
    flags[7] = 0;          // ws bf16 buffers
  }
  if (meta && threadIdx.x < 24) meta[threadIdx.x] = 0;
}

// merged conversion over x + 4 weight tensors; per-segment flag early-exit
// (bf16 inputs are consumed raw downstream -- skip-copy).
#define U8_X  (T_TOK * DD / 8)
#define U8_S1 (NSH * FF * DD / 8)
#define U8_R1 (EE * FF * DD / 8)
#define U8_S2 (NSH * DD * FF / 8)
#define U8_R2 (EE * DD * FF / 8)
#define U8_C0 (U8_X)
#define U8_C1 (U8_C0 + U8_S1)
#define U8_C2 (U8_C1 + U8_R1)
#define U8_C3 (U8_C2 + U8_S2)
#define U8_C4 (U8_C3 + U8_R2)
__global__ __launch_bounds__(256) void conv_all(
    const void* __restrict__ x, const void* __restrict__ sw1,
    const void* __restrict__ rw1, const void* __restrict__ sw2,
    const void* __restrict__ rw2, u16* __restrict__ xb,
    u16* __restrict__ s1b, u16* __restrict__ r1b, u16* __restrict__ s2b,
    u16* __restrict__ r2b, const int* __restrict__ flags) {
  size_t u = (size_t)blockIdx.x * 256 + threadIdx.x;
  const void* src; u16* dst; int fi; size_t base;
  if (u < U8_C0)      { src = x;   dst = xb;  fi = 0; base = 0; }
  else if (u < U8_C1) { src = sw1; dst = s1b; fi = 2; base = U8_C0; }
  else if (u < U8_C2) { src = rw1; dst = r1b; fi = 4; base = U8_C1; }
  else if (u < U8_C3) { src = sw2; dst = s2b; fi = 3; base = U8_C2; }
  else                { src = rw2; dst = r2b; fi = 5; base = U8_C3; }
  int f = flags[fi];
  if (!f) return;               // bf16: raw tensor used directly downstream
  size_t i = (u - base) * 8;
  *(bf16x8*)(dst + i) = load8(src, i, f);
}

// Router: FULL-precision logits (raw x, raw gw), vectorized 16B loads.
__global__ __launch_bounds__(256) void router_v(
    const void* __restrict__ x, const void* __restrict__ gw,
    const u16* __restrict__ gb, const int* __restrict__ flags,
    float* __restrict__ cw, int2* __restrict__ tix) {
  int wave = threadIdx.x >> 6, lane = threadIdx.x & 63;
  int t = blockIdx.x * 4 + wave;
  int fx = flags[0], fg = flags[1];
  float xf[8];
  loadf8(x, (size_t)t * DD + lane * 8, fx, xf);
  float acc[EE];
#pragma unroll
  for (int e = 0; e < EE; ++e) {
    float gf[8];
    loadf8(gw, (size_t)e * DD + lane * 8, fg, gf);
    float a = 0.f;
#pragma unroll
    for (int j = 0; j < 8; ++j) a = fmaf(xf[j], gf[j], a);
    acc[e] = a;
  }
#pragma unroll
  for (int e = 0; e < EE; ++e) {
    float v = acc[e];
#pragma unroll
    for (int off = 32; off > 0; off >>= 1) v += __shfl_xor(v, off, 64);
    acc[e] = v;
  }
  if (lane == 0) {
    float m = -1e30f;
#pragma unroll
    for (int e = 0; e < EE; ++e) {
      acc[e] += bf2f(gb[e]);   // all-zero: dtype-agnostic
      m = fmaxf(m, acc[e]);
    }
    float p[EE], s = 0.f;
#pragma unroll
    for (int e = 0; e < EE; ++e) { p[e] = expf(acc[e] - m); s += p[e]; }
    int i1 = 0;
#pragma unroll
    for (int e = 1; e < EE; ++e) if (p[e] > p[i1]) i1 = e;
    int i2 = (i1 == 0) ? 1 : 0;
#pragma unroll
    for (int e = 0; e < EE; ++e)
      if (e != i1 && p[e] > p[i2]) i2 = e;
    float inv = 1.0f / s;
#pragma unroll
    for (int e = 0; e < EE; ++e)
      cw[t * EE + e] = (e == i1 || e == i2) ? p[e] * inv : 0.0f;
    tix[t] = make_int2(i1, i2);
  }
}

// build lists + pad, ONE single-block kernel (all-lane atomics: TA/L2
// combines same-address lanes -- NOT the round-2 single-lane mistake).
// meta: [0..7]=cnt, [8..15]=pc (padded), [16..23]=row prefix
__global__ __launch_bounds__(1024) void build_pad(
    const int2* __restrict__ tix, int* __restrict__ meta,
    unsigned* __restrict__ list, int4* __restrict__ srec) {
  for (int t = threadIdx.x; t < T_TOK; t += 1024) {
    int2 ii = tix[t];
    int p0 = atomicAdd(&meta[ii.x], 1);
    list[(size_t)ii.x * CAP + p0] = (unsigned)t;
    int p1 = atomicAdd(&meta[ii.y], 1);
    list[(size_t)ii.y * CAP + p1] = (unsigned)t;
    srec[t] = make_int4(ii.x, p0, ii.y, p1);
  }
  __syncthreads();
  if (threadIdx.x == 0) {
    int off = 0;
    for (int e = 0; e < EE; ++e) {
      int c = meta[e];
      int pc = (c + BM - 1) & ~(BM - 1);
      meta[8 + e] = pc;
      meta[16 + e] = off;
      off += pc;
    }
  }
  __syncthreads();
#pragma unroll
  for (int e = 0; e < EE; ++e) {
    int c = meta[e], pc = meta[8 + e];
    for (int i = c + threadIdx.x; i < pc; i += 1024)
      list[(size_t)e * CAP + i] = PADF;
  }
}

// ========== fast path: swizzled BK=64 128x128 GEMMs + XCD-aware remap =====
// T1: consecutive linear block ids round-robin across 8 XCDs (id mod 8).
// Remap so all bn-tiles sharing one A-panel carry the SAME id mod 8 ->
// co-located on one XCD's L2 -> A-panel fetched from HBM ~once, not 4-16x.

// FFN1 (shared + routed gather) in ONE dispatch. grid (16, 32, 10).
__global__ __launch_bounds__(256) void g1_fused(
    const void* __restrict__ xr, const u16* __restrict__ xb,
    const void* __restrict__ s1r, const u16* __restrict__ s1b,
    const u16* __restrict__ sb1,
    const void* __restrict__ r1r, const u16* __restrict__ r1b,
    const u16* __restrict__ rb1, const unsigned* __restrict__ list,
    const int* __restrict__ meta, const int* __restrict__ flags,
    u16* __restrict__ Hsh, u16* __restrict__ Hrt) {
  // skip-copy: raw tensor when already bf16
  const u16* xp  = flags[0] ? xb  : (const u16*)xr;
  const u16* s1p = flags[2] ? s1b : (const u16*)s1r;
  const u16* r1p = flags[4] ? r1b : (const u16*)r1r;

  // XCD remap: 16 x-sharers of an A-panel get ids == same (mod 8)
  int L  = blockIdx.x + 16 * (blockIdx.y + 32 * blockIdx.z);
  int xx = (L & 127) >> 3;                    // 0..15 (bn tile)
  int pp = ((L >> 7) << 3) | (L & 7);         // panel 0..319
  int z  = pp >> 5;                           // 0..9
  int bm = (pp & 31) * BM;

  int tid = threadIdx.x, lane = tid & 63, wave = tid >> 6;
  int wm = (wave >> 1) * 64, wn = (wave & 1) * 64;
  int r = lane & 15, q = lane >> 4;
  const int K = DD;

  // staging geometry: idx = c*256+tid; row = c*32 + (tid>>3); unit = tid&7
  int rsub = tid >> 3;
  int us = (tid & 7) ^ (rsub & 7);   // pre-swizzled source unit

  __shared__ u16 As[BM * BK2];   // 16KB
  __shared__ u16 Bs[BN * BK2];   // 16KB

  const u16 *gA[4], *gB[4];
  int e = 0, ho = 0, bn;
  if (z < 2) {
    bn = (z * 16 + xx) * BN;
#pragma unroll
    for (int c = 0; c < 4; ++c) {
      gA[c] = xp + (size_t)(bm + c * 32 + rsub) * K + us * 8;
      gB[c] = s1p + (size_t)(bn + c * 32 + rsub) * K + us * 8;
    }
  } else {
    e = z - 2;
    if (bm >= meta[8 + e]) return;
    ho = meta[16 + e];
    bn = xx * BN;
#pragma unroll
    for (int c = 0; c < 4; ++c) {
      unsigned tk = list[(size_t)e * CAP + bm + c * 32 + rsub] & 0x7fffffffu;
      gA[c] = xp + (size_t)tk * K + us * 8;
      gB[c] = r1p + (size_t)e * FF * DD + (size_t)(bn + c * 32 + rsub) * K +
              us * 8;
    }
  }

  floatx4 acc[4][4];
  floatx4 zero = {0.f, 0.f, 0.f, 0.f};
#pragma unroll
  for (int i = 0; i < 4; ++i)
#pragma unroll
    for (int j = 0; j < 4; ++j) acc[i][j] = zero;

  core128swz(gA[0], gA[1], gA[2], gA[3], gB[0], gB[1], gB[2], gB[3],
             K, As, Bs, acc, wave, wm, wn, r, q);

  if (z < 2) {
#pragma unroll
    for (int mi = 0; mi < 4; ++mi)
#pragma unroll
      for (int ni = 0; ni < 4; ++ni) {
        int col = bn + wn + ni * 16 + r;
        float bv = bf2f(sb1[col]);
#pragma unroll
        for (int rr = 0; rr < 4; ++rr) {
          int row = bm + wm + mi * 16 + q * 4 + rr;
          float v = acc[mi][ni][rr] + bv;
          Hsh[(size_t)row * (NSH * FF) + col] = f2bf(fast_gelu(v));
        }
      }
  } else {
#pragma unroll
    for (int mi = 0; mi < 4; ++mi)
#pragma unroll
      for (int ni = 0; ni < 4; ++ni) {
        int col = bn + wn + ni * 16 + r;
        float bv = bf2f(rb1[(size_t)e * FF + col]);
#pragma unroll
        for (int rr = 0; rr < 4; ++rr) {
          int slot = bm + wm + mi * 16 + q * 4 + rr;
          float v = acc[mi][ni][rr] + bv;
          Hrt[(size_t)(ho + slot) * FF + col] = f2bf(fast_gelu(v));
        }
      }
  }
}

// FFN2 (shared planes + routed compact) in ONE dispatch. grid (4, 32, 10).
__global__ __launch_bounds__(256) void g2_fused(
    const u16* __restrict__ Hsh,
    const void* __restrict__ s2r, const u16* __restrict__ s2b,
    const u16* __restrict__ sb2, const u16* __restrict__ Hrt,
    const void* __restrict__ r2r, const u16* __restrict__ r2b,
    const u16* __restrict__ rb2,
    const unsigned* __restrict__ list, const int* __restrict__ meta,
    const int* __restrict__ flags, const float* __restrict__ cw,
    float* __restrict__ oacc, float* __restrict__ Ort) {
  const u16* s2p = flags[3] ? s2b : (const u16*)s2r;
  const u16* r2p = flags[5] ? r2b : (const u16*)r2r;

  // XCD remap: 4 x-sharers of an A-panel get ids == same (mod 8)
  int L  = blockIdx.x + 4 * (blockIdx.y + 32 * blockIdx.z);
  int xx = (L & 31) >> 3;                     // 0..3 (bn tile)
  int pp = ((L >> 5) << 3) | (L & 7);         // panel 0..319
  int z  = pp >> 5;                           // 0..9
  int bm = (pp & 31) * BM;
  int bn = xx * BN;

  int tid = threadIdx.x, lane = tid & 63, wave = tid >> 6;
  int wm = (wave >> 1) * 64, wn = (wave & 1) * 64;
  int r = lane & 15, q = lane >> 4;
  const int K = FF;

  int rsub = tid >> 3;
  int us = (tid & 7) ^ (rsub & 7);

  __shared__ u16 As[BM * BK2];
  __shared__ u16 Bs[BN * BK2];

  const u16 *gA[4], *gB[4];
  int e = 0, ho = 0;
  if (z < NSH) {
    const int ldA = NSH * FF;
#pragma unroll
    for (int c = 0; c < 4; ++c) {
      gA[c] = Hsh + (size_t)(bm + c * 32 + rsub) * ldA + (size_t)z * FF +
              us * 8;
      gB[c] = s2p + (size_t)z * DD * FF + (size_t)(bn + c * 32 + rsub) * K +
              us * 8;
    }
  } else {
    e = z - NSH;
    if (bm >= meta[8 + e]) return;
    ho = meta[16 + e];
#pragma unroll
    for (int c = 0; c < 4; ++c) {
      gA[c] = Hrt + (size_t)(ho + bm + c * 32 + rsub) * K + us * 8;
      gB[c] = r2p + (size_t)e * DD * FF + (size_t)(bn + c * 32 + rsub) * K +
              us * 8;
    }
  }

  floatx4 acc[4][4];
  floatx4 zero = {0.f, 0.f, 0.f, 0.f};
#pragma unroll
  for (int i = 0; i < 4; ++i)
#pragma unroll
    for (int j = 0; j < 4; ++j) acc[i][j] = zero;

  core128swz(gA[0], gA[1], gA[2], gA[3], gB[0], gB[1], gB[2], gB[3],
             K, As, Bs, acc, wave, wm, wn, r, q);

  if (z < NSH) {
    float* op = oacc + (size_t)z * T_TOK * DD;
#pragma unroll
    for (int mi = 0; mi < 4; ++mi)
#pragma unroll
      for (int ni = 0; ni < 4; ++ni) {
        int col = bn + wn + ni * 16 + r;
        float bv = bf2f(sb2[(size_t)z * DD + col]);
#pragma unroll
        for (int rr = 0; rr < 4; ++rr) {
          int row = bm + wm + mi * 16 + q * 4 + rr;
          op[(size_t)row * DD + col] = acc[mi][ni][rr] + bv;
        }
      }
  } else {
#pragma unroll
    for (int mi = 0; mi < 4; ++mi)
#pragma unroll
      for (int rr = 0; rr < 4; ++rr) {
        int slot = bm + wm + mi * 16 + q * 4 + rr;
        unsigned raw = list[(size_t)e * CAP + slot];
        if (raw & PADF) continue;
        float s = cw[raw * EE + e];
#pragma unroll
        for (int ni = 0; ni < 4; ++ni) {
          int col = bn + wn + ni * 16 + r;
          float v = acc[mi][ni][rr] + bf2f(rb2[(size_t)e * DD + col]);
          Ort[(size_t)(ho + slot) * DD + col] = s * v;
        }
      }
  }
}

// final: out[t] = oacc0[t] + oacc1[t] + Ort[g0(t)] + Ort[g1(t)]
typedef struct { u16 a, b, c, d; } u16x4;
__global__ __launch_bounds__(256) void combine_out(
    const float* __restrict__ oacc, const float* __restrict__ Ort,
    const int4* __restrict__ srec, const int* __restrict__ meta,
    void* __restrict__ out, const int* __restrict__ flags) {
  int t  = blockIdx.x * 2 + (threadIdx.x >> 7);
  int c4 = (threadIdx.x & 127) * 4;
  int4 sr = srec[t];
  int g0 = meta[16 + sr.x] + sr.y;
  int g1 = meta[16 + sr.z] + sr.w;
  float4 a = *(const float4*)(oacc + (size_t)t * DD + c4);
  float4 b = *(const float4*)(oacc + (size_t)(T_TOK + t) * DD + c4);
  float4 u = *(const float4*)(Ort + (size_t)g0 * DD + c4);
  float4 v = *(const float4*)(Ort + (size_t)g1 * DD + c4);
  float o0 = a.x + b.x + u.x + v.x;
  float o1 = a.y + b.y + u.y + v.y;
  float o2 = a.z + b.z + u.z + v.z;
  float o3 = a.w + b.w + u.w + v.w;
  size_t idx = (size_t)t * DD + c4;
  if (flags[6]) {
    *(float4*)((float*)out + idx) = make_float4(o0, o1, o2, o3);
  } else {
    u16x4 h = {f2bf(o0), f2bf(o1), f2bf(o2), f2bf(o3)};
    *(u16x4*)((u16*)out + idx) = h;
  }
}

// ---------------- fallback-path kernels (dense, unconverted) ----------------
__device__ __forceinline__ void gemm_core(const void* A, size_t aoff, int fA,
                                          const void* B, size_t boff, int fB,
                                          int K, u16* As, u16* Bs,
                                          floatx4 acc[4][4]) {
  int tid  = threadIdx.x;
  int lane = tid & 63, wave = tid >> 6;
  int wm = (wave >> 1) * 64, wn = (wave & 1) * 64;
  int r = lane & 15, q = lane >> 4;
  int srow = tid >> 2;
  int sc8  = (tid & 3) * 8;
  size_t abase = aoff + (size_t)srow * K + sc8;
  size_t bbase = boff + (size_t)srow * K + sc8;
  const size_t half = (size_t)64 * K;

  for (int k0 = 0; k0 < K; k0 += BK) {
    bf16x8 av0 = load8(A, abase + k0, fA);
    bf16x8 av1 = load8(A, abase + half + k0, fA);
    bf16x8 bv0 = load8(B, bbase + k0, fB);
    bf16x8 bv1 = load8(B, bbase + half + k0, fB);
    __syncthreads();
    *(bf16x8*)(As + srow * LDK + sc8)        = av0;
    *(bf16x8*)(As + (srow + 64) * LDK + sc8) = av1;
    *(bf16x8*)(Bs + srow * LDK + sc8)        = bv0;
    *(bf16x8*)(Bs + (srow + 64) * LDK + sc8) = bv1;
    __syncthreads();

    bf16x8 af[4], bfr[4];
#pragma unroll
    for (int mi = 0; mi < 4; ++mi)
      af[mi] = *(const bf16x8*)(As + (wm + mi * 16 + r) * LDK + q * 8);
#pragma unroll
    for (int ni = 0; ni < 4; ++ni)
      bfr[ni] = *(const bf16x8*)(Bs + (wn + ni * 16 + r) * LDK + q * 8);
#pragma unroll
    for (int mi = 0; mi < 4; ++mi)
#pragma unroll
      for (int ni = 0; ni < 4; ++ni)
        acc[mi][ni] = __builtin_amdgcn_mfma_f32_16x16x32_bf16(
            af[mi], bfr[ni], acc[mi][ni], 0, 0, 0);
  }
}

__global__ __launch_bounds__(256) void gemm1_gelu(
    const void* __restrict__ A, size_t aoff, const void* __restrict__ B,
    size_t boff, const u16* __restrict__ bias, size_t bioff,
    u16* __restrict__ H, const int* __restrict__ flags, int iA, int iB,
    int N, int K) {
  __shared__ u16 As[BM * LDK];
  __shared__ u16 Bs[BN * LDK];
  int fA = flags[iA], fB = flags[iB];
  floatx4 acc[4][4];
  floatx4 zero = {0.f, 0.f, 0.f, 0.f};
#pragma unroll
  for (int i = 0; i < 4; ++i)
#pragma unroll
    for (int j = 0; j < 4; ++j) acc[i][j] = zero;

  int bm = blockIdx.y * BM, bn = blockIdx.x * BN;
  gemm_core(A, aoff + (size_t)bm * K, fA, B, boff + (size_t)bn * K, fB, K,
            As, Bs, acc);

  int tid = threadIdx.x, wave = tid >> 6, lane = tid & 63;
  int wm = (wave >> 1) * 64, wn = (wave & 1) * 64;
  int r = lane & 15, q = lane >> 4;
#pragma unroll
  for (int mi = 0; mi < 4; ++mi)
#pragma unroll
    for (int ni = 0; ni < 4; ++ni) {
      int col = bn + wn + ni * 16 + r;
      float bv = bf2f(bias[bioff + col]);
#pragma unroll
      for (int rr = 0; rr < 4; ++rr) {
        int row = bm + wm + mi * 16 + q * 4 + rr;
        float v = acc[mi][ni][rr] + bv;
        H[(size_t)row * N + col] = f2bf(fast_gelu(v));
      }
    }
}

__global__ __launch_bounds__(256) void gemm2_acc(
    const u16* __restrict__ A, const void* __restrict__ B, size_t boff,
    const u16* __restrict__ bias, size_t bioff, float* __restrict__ outf,
    void* __restrict__ outb, const float* __restrict__ cw,
    const int* __restrict__ flags, int iB, int expert, int accum,
    int row0, int N, int K) {
  __shared__ u16 As[BT2 * LDK];
  __shared__ u16 Bs[BT2 * LDK];
  int fB = flags[iB], fO = flags[6];
  floatx4 acc[2][2];
  floatx4 zero = {0.f, 0.f, 0.f, 0.f};
#pragma unroll
  for (int i = 0; i < 2; ++i)
#pragma unroll
    for (int j = 0; j < 2; ++j) acc[i][j] = zero;

  int bm = blockIdx.y * BT2, bn = blockIdx.x * BT2;
  int tid  = threadIdx.x;
  int lane = tid & 63, wave = tid >> 6;
  int wm = (wave >> 1) * 32, wn = (wave & 1) * 32;
  int r = lane & 15, q = lane >> 4;
  int srow = tid >> 2;
  int sc8  = (tid & 3) * 8;
  size_t abase = (size_t)(bm + srow) * K + sc8;
  size_t bbase = boff + (size_t)(bn + srow) * K + sc8;

  for (int k0 = 0; k0 < K; k0 += BK) {
    bf16x8 av = *(const bf16x8*)(A + abase + k0);
    bf16x8 bv = load8(B, bbase + k0, fB);
    __syncthreads();
    *(bf16x8*)(As + srow * LDK + sc8) = av;
    *(bf16x8*)(Bs + srow * LDK + sc8) = bv;
    __syncthreads();

    bf16x8 af[2], bfr[2];
#pragma unroll
    for (int mi = 0; mi < 2; ++mi)
      af[mi] = *(const bf16x8*)(As + (wm + mi * 16 + r) * LDK + q * 8);
#pragma unroll
    for (int ni = 0; ni < 2; ++ni)
      bfr[ni] = *(const bf16x8*)(Bs + (wn + ni * 16 + r) * LDK + q * 8);
#pragma unroll
    for (int mi = 0; mi < 2; ++mi)
#pragma unroll
      for (int ni = 0; ni < 2; ++ni)
        acc[mi][ni] = __builtin_amdgcn_mfma_f32_16x16x32_bf16(
            af[mi], bfr[ni], acc[mi][ni], 0, 0, 0);
  }

#pragma unroll
  for (int mi = 0; mi < 2; ++mi)
#pragma unroll
    for (int rr = 0; rr < 4; ++rr) {
      int grow = row0 + bm + wm + mi * 16 + q * 4 + rr;
      float s = cw ? cw[grow * EE + expert] : 1.0f;
#pragma unroll
      for (int ni = 0; ni < 2; ++ni) {
        int col = bn + wn + ni * 16 + r;
        float v = acc[mi][ni][rr] + bf2f(bias[bioff + col]);
        size_t idx = (size_t)grow * N + col;
        if (outf) {
          float prev = accum ? outf[idx] : 0.0f;
          outf[idx] = prev + s * v;
        } else if (fO) {
          float* ob = (float*)outb;
          float prev = accum ? ob[idx] : 0.0f;
          ob[idx] = prev + s * v;
        } else {
          u16* ob = (u16*)outb;
          float prev = accum ? bf2f(ob[idx]) : 0.0f;
          ob[idx] = f2bf(prev + s * v);
        }
      }
    }
}

__global__ __launch_bounds__(256) void convert_out(
    const float* __restrict__ acc, void* __restrict__ out,
    const int* __restrict__ flags, int n) {
  int i = blockIdx.x * blockDim.x + threadIdx.x;
  if (i >= n) return;
  if (flags[6]) ((float*)out)[i] = acc[i];
  else ((u16*)out)[i] = f2bf(acc[i]);
}

extern "C" void kernel_launch(void* const* d_in, const int* in_sizes, int n_in,
                              void* d_out, int out_size, void* d_ws, size_t ws_size,
                              hipStream_t stream) {
  (void)in_sizes; (void)n_in; (void)out_size;
  const void* x   = d_in[0];
  const void* gw  = d_in[1];
  const u16*  gb  = (const u16*)d_in[2];
  const void* sw1 = d_in[3];
  const u16*  sb1 = (const u16*)d_in[4];
  const void* sw2 = d_in[5];
  const u16*  sb2 = (const u16*)d_in[6];
  const void* rw1 = d_in[7];
  const u16*  rb1 = (const u16*)d_in[8];
  const void* rw2 = d_in[9];
  const u16*  rb2 = (const u16*)d_in[10];

  const size_t NX   = (size_t)T_TOK * DD;
  const size_t NW1S = (size_t)NSH * FF * DD;
  const size_t NW1R = (size_t)EE * FF * DD;
  const size_t NW2S = (size_t)NSH * DD * FF;
  const size_t NW2R = (size_t)EE * DD * FF;

  // fast-path layout
  size_t off = 0;
  const size_t flO   = off; off += 256;
  const size_t cwO   = off; off += (size_t)T_TOK * EE * 4;
  const size_t tixO  = off; off += (size_t)T_TOK * 8;
  const size_t metaO = off; off += 256;
  const size_t listO = off; off += (size_t)EE * CAP * 4;
  const size_t srecO = off; off += (size_t)T_TOK * 16;
  const size_t accO  = off; off += (size_t)NSH * T_TOK * DD * 4;
  const size_t hshO  = off; off += (size_t)T_TOK * NSH * FF * 2;
  const size_t hrtO  = off; off += (size_t)NSLOT * FF * 2;
  const size_t ortO  = off; off += (size_t)NSLOT * DD * 4;
  const size_t xbO   = off; off += NX * 2;
  const size_t s1O   = off; off += NW1S * 2;
  const size_t r1O   = off; off += NW1R * 2;
  const size_t s2O   = off; off += NW2S * 2;
  const size_t r2O   = off; off += NW2R * 2;
  const int fast = (off <= ws_size) ? 1 : 0;

  char* ws = (char*)d_ws;
  int*   flags = (int*)(ws + flO);
  float* cw    = (float*)(ws + cwO);
  dim3 blk(256);

  if (fast) {
    int2*     tix  = (int2*)(ws + tixO);
    int*      meta = (int*)(ws + metaO);
    unsigned* list = (unsigned*)(ws + listO);
    int4*     srec = (int4*)(ws + srecO);
    float*    oacc = (float*)(ws + accO);
    u16*      Hsh  = (u16*)(ws + hshO);
    u16*      Hrt  = (u16*)(ws + hrtO);
    float*    Ort  = (float*)(ws + ortO);
    u16*      xb   = (u16*)(ws + xbO);
    u16*      s1b  = (u16*)(ws + s1O);
    u16*      r1b  = (u16*)(ws + r1O);
    u16*      s2b  = (u16*)(ws + s2O);
    u16*      r2b  = (u16*)(ws + r2O);

    detect_kernel<<<1, 256, 0, stream>>>(x, gw, sw1, sw2, rw1, rw2, flags,
                                         meta);
    conv_all<<<U8_C4 / 256, 256, 0, stream>>>(x, sw1, rw1, sw2, rw2, xb, s1b,
                                              r1b, s2b, r2b, flags);
    router_v<<<T_TOK / 4, 256, 0, stream>>>(x, gw, gb, flags, cw, tix);
    build_pad<<<1, 1024, 0, stream>>>(tix, meta, list, srec);

    // FFN1: shared (z<2) + routed gather (z>=2), one dispatch
    dim3 gf1(16, T_TOK / BM, 2 + EE);            // 16 x 32 x 10
    g1_fused<<<gf1, blk, 0, stream>>>(x, xb, sw1, s1b, sb1, rw1, r1b, rb1,
                                      list, meta, flags, Hsh, Hrt);
    // FFN2: shared planes (z<NSH) + routed compact (z>=NSH), one dispatch
    dim3 gf2(DD / BN, CAP / BM, NSH + EE);       // 4 x 32 x 10
    g2_fused<<<gf2, blk, 0, stream>>>(Hsh, sw2, s2b, sb2, Hrt, rw2, r2b, rb2,
                                      list, meta, flags, cw, oacc, Ort);
    combine_out<<<T_TOK / 2, 256, 0, stream>>>(oacc, Ort, srec, meta, d_out,
                                               flags);
    return;
  }

  // -------- fallback: dense all-FFN path (no conversion), ws-adaptive --------
  detect_kernel<<<1, 256, 0, stream>>>(x, gw, sw1, sw2, rw1, rw2, flags,
                                       nullptr);
  const size_t flB = 256, cwB = (size_t)T_TOK * EE * 4, tixB = (size_t)T_TOK * 8;
  const size_t accB = (size_t)T_TOK * DD * 4;
  static const int tcs[4] = {4096, 2048, 1024, 512};
  int TC = 0, use_f32 = 1;
  for (int i = 0; i < 4; ++i)
    if (flB + cwB + tixB + accB + (size_t)tcs[i] * FF * 2 <= ws_size) { TC = tcs[i]; break; }
  if (!TC) {
    use_f32 = 0;
    for (int i = 0; i < 4; ++i)
      if (flB + cwB + tixB + (size_t)tcs[i] * FF * 2 <= ws_size) { TC = tcs[i]; break; }
  }
  if (!TC) { TC = 512; use_f32 = 0; }

  int2*  tix     = (int2*)(ws + flB + cwB);
  float* out_acc = use_f32 ? (float*)(ws + flB + cwB + tixB) : nullptr;
  u16*   H       = (u16*)(ws + flB + cwB + tixB + (use_f32 ? accB : 0));

  router_v<<<T_TOK / 4, 256, 0, stream>>>(x, gw, gb, flags, cw, tix);
  dim3 g1(FF / BN, TC / BM);
  dim3 g2(DD / BT2, TC / BT2);
  const int nchunk = T_TOK / TC;
  for (int f = 0; f < NSH + EE; ++f) {
    const void *w1, *w2; const u16 *b1, *b2; const float* cwp;
    int expert, i1, i2v; size_t w1off, w2off, b1off, b2off;
    if (f < NSH) {
      w1 = sw1; w2 = sw2; b1 = sb1; b2 = sb2;
      w1off = (size_t)f * FF * DD; w2off = (size_t)f * DD * FF;
      b1off = (size_t)f * FF; b2off = (size_t)f * DD;
      cwp = nullptr; expert = 0; i1 = 2; i2v = 3;
    } else {
      int e = f - NSH;
      w1 = rw1; w2 = rw2; b1 = rb1; b2 = rb2;
      w1off = (size_t)e * FF * DD; w2off = (size_t)e * DD * FF;
      b1off = (size_t)e * FF; b2off = (size_t)e * DD;
      cwp = cw; expert = e; i1 = 4; i2v = 5;
    }
    int accum = (f > 0) ? 1 : 0;
    for (int c = 0; c < nchunk; ++c) {
      size_t t0 = (size_t)c * TC;
      gemm1_gelu<<<g1, blk, 0, stream>>>(x, t0 * DD, w1, w1off, b1, b1off, H,
                                         flags, 0, i1, FF, DD);
      gemm2_acc<<<g2, blk, 0, stream>>>(H, w2, w2off, b2, b2off, out_acc,
                                        d_out, cwp, flags, i2v, expert, accum,
                                        (int)t0, DD, FF);
    }
  }
  if (use_f32)
    convert_out<<<(T_TOK * DD) / 256, 256, 0, stream>>>(out_acc, d_out, flags,
                                                        T_TOK * DD);
}

// Round 8
// 369.818 us; speedup vs baseline: 1.0153x; 1.0133x over previous
//
#include <hip/hip_runtime.h>
#include <math.h>

typedef unsigned short u16;
typedef __attribute__((ext_vector_type(8))) __bf16 bf16x8;
typedef __attribute__((ext_vector_type(4))) float floatx4;

#define T_TOK 4096
#define DD    512
#define FF    2048
#define EE    8
#define NSH   2

#define BM 128
#define BN 128
#define BK 32
#define LDK 40   // fallback kernels: padded LDS row stride
#define BT2 64   // fallback gemm2 N-tile
#define CAP 4096
#define PADF 0x80000000u
#define NSLOT (2 * T_TOK + EE * BM)   // 9216 compact rows max

__device__ __forceinline__ float bf2f(u16 v) {
  union { unsigned int u; float f; } c; c.u = ((unsigned int)v) << 16; return c.f;
}
__device__ __forceinline__ u16 f2bf(float f) {
  union { float ff; unsigned int u; } c; c.ff = f;
  unsigned int u = c.u;
  u += 0x7fffu + ((u >> 16) & 1u);   // RNE
  return (u16)(u >> 16);
}
__device__ __forceinline__ float decode(const void* p, size_t idx, int f) {
  return f ? ((const float*)p)[idx] : bf2f(((const u16*)p)[idx]);
}
__device__ __forceinline__ bf16x8 load8(const void* base, size_t idx, int f) {
  if (f) {
    const float* p = (const float*)base + idx;
    float4 a = *(const float4*)p;
    float4 b = *(const float4*)(p + 4);
    union { bf16x8 v; u16 s[8]; } u;
    u.s[0] = f2bf(a.x); u.s[1] = f2bf(a.y); u.s[2] = f2bf(a.z); u.s[3] = f2bf(a.w);
    u.s[4] = f2bf(b.x); u.s[5] = f2bf(b.y); u.s[6] = f2bf(b.z); u.s[7] = f2bf(b.w);
    return u.v;
  }
  return *(const bf16x8*)((const u16*)base + idx);
}
// full-precision 8-element load (fp32 stays fp32; bf16 widened) -- router path.
// Top-k selection is discontinuous in the logits: router must NOT quantize.
__device__ __forceinline__ void loadf8(const void* p, size_t idx, int f,
                                       float* o) {
  if (f) {
    const float* q = (const float*)p + idx;
    float4 a = *(const float4*)q;
    float4 b = *(const float4*)(q + 4);
    o[0] = a.x; o[1] = a.y; o[2] = a.z; o[3] = a.w;
    o[4] = b.x; o[5] = b.y; o[6] = b.z; o[7] = b.w;
  } else {
    union { bf16x8 v; u16 s[8]; } u;
    u.v = *(const bf16x8*)((const u16*)p + idx);
#pragma unroll
    for (int j = 0; j < 8; ++j) o[j] = bf2f(u.s[j]);
  }
}

// fast exact-GELU: erf via Abramowitz-Stegun 7.1.26 (|err| 1.5e-7), native rcp/exp
__device__ __forceinline__ float fast_gelu(float v) {
  float x  = v * 0.70710678118654752f;
  float ax = fabsf(x);
  float t  = __builtin_amdgcn_rcpf(fmaf(0.3275911f, ax, 1.0f));
  float p  = fmaf(t, 1.061405429f, -1.453152027f);
  p = fmaf(t, p, 1.421413741f);
  p = fmaf(t, p, -0.284496736f);
  p = fmaf(t, p, 0.254829592f);
  p = p * t;
  float e  = __expf(-ax * ax);
  float er = fmaf(-p, e, 1.0f);          // erf(|x|)
  er = (x < 0.f) ? -er : er;
  return 0.5f * v * (1.0f + er);
}

// async 16B global->LDS. LDS dest is wave-uniform base; HW writes base+lane*16.
__device__ __forceinline__ void gll16(const void* g, void* l) {
  __builtin_amdgcn_global_load_lds(
      (const __attribute__((address_space(1))) void*)g,
      (__attribute__((address_space(3))) void*)l, 16, 0, 0);
}

#define BK2 64
#define TILEU (BM * BK2)   // 8192 u16 = 16KB per buffer

// stage one 128x64 k-slab (8 global_load_lds = 8 vmcnt increments per wave)
__device__ __forceinline__ void stage8(
    const u16* gA0, const u16* gA1, const u16* gA2, const u16* gA3,
    const u16* gB0, const u16* gB1, const u16* gB2, const u16* gB3,
    u16* Asb, u16* Bsb, int wave, int k0) {
  gll16(gA0 + k0, Asb + wave * 512);
  gll16(gA1 + k0, Asb + 2048 + wave * 512);
  gll16(gA2 + k0, Asb + 4096 + wave * 512);
  gll16(gA3 + k0, Asb + 6144 + wave * 512);
  gll16(gB0 + k0, Bsb + wave * 512);
  gll16(gB1 + k0, Bsb + 2048 + wave * 512);
  gll16(gB2 + k0, Bsb + 4096 + wave * 512);
  gll16(gB3 + k0, Bsb + 6144 + wave * 512);
}

// ===== T3+T4 pipelined 128x128 core: 2-deep LDS dbuf, COUNTED vmcnt(8) so
// next tile's 8 loads stay in flight ACROSS the barrier (round-4's failure
// was __syncthreads' implicit vmcnt(0) drain). Raw s_barrier + sched_barrier
// fences (rule #18). Swizzle from round 6 kept (bank-conflict 4.29M -> 0):
// linear LDS dest, inverse-swz global source, same swz on ds_read.
__device__ __forceinline__ void core128pipe(
    const u16* gA0, const u16* gA1, const u16* gA2, const u16* gA3,
    const u16* gB0, const u16* gB1, const u16* gB2, const u16* gB3,
    int K, u16* As, u16* Bs, floatx4 acc[4][4],
    int wave, int wm, int wn, int r, int q) {
  const int rs = r & 7;                 // fragment-row low bits (R&7 == r&7)
  stage8(gA0, gA1, gA2, gA3, gB0, gB1, gB2, gB3, As, Bs, wave, 0);
  int cur = 0;
  for (int k0 = 0; k0 < K; k0 += BK2) {
    const u16* Ac = As + cur * TILEU;
    const u16* Bc = Bs + cur * TILEU;
    if (k0 + BK2 < K) {
      stage8(gA0, gA1, gA2, gA3, gB0, gB1, gB2, gB3,
             As + (cur ^ 1) * TILEU, Bs + (cur ^ 1) * TILEU, wave, k0 + BK2);
      // wait for THIS tile's 8 loads; leave next tile's 8 in flight
      asm volatile("s_waitcnt vmcnt(8)" ::: "memory");
    } else {
      asm volatile("s_waitcnt vmcnt(0)" ::: "memory");
    }
    __builtin_amdgcn_sched_barrier(0);
    __builtin_amdgcn_s_barrier();       // all waves: cur tile landed
    __builtin_amdgcn_sched_barrier(0);
#pragma unroll
    for (int s = 0; s < 2; ++s) {       // two k=32 slabs per 64-elem row
      bf16x8 af[4], bfr[4];
#pragma unroll
      for (int mi = 0; mi < 4; ++mi) {
        int R = wm + mi * 16 + r;
        int u = (s * 4 + q) ^ rs;
        af[mi] = *(const bf16x8*)(Ac + R * 64 + u * 8);
      }
#pragma unroll
      for (int ni = 0; ni < 4; ++ni) {
        int R = wn + ni * 16 + r;
        int u = (s * 4 + q) ^ rs;
        bfr[ni] = *(const bf16x8*)(Bc + R * 64 + u * 8);
      }
#pragma unroll
      for (int mi = 0; mi < 4; ++mi)
#pragma unroll
        for (int ni = 0; ni < 4; ++ni)
          acc[mi][ni] = __builtin_amdgcn_mfma_f32_16x16x32_bf16(
              af[mi], bfr[ni], acc[mi][ni], 0, 0, 0);
    }
    __builtin_amdgcn_sched_barrier(0);
    __builtin_amdgcn_s_barrier();       // all waves done reading cur
    cur ^= 1;
  }
}

// Probe: classify tensors fp32(1)/bf16(0); zero meta (fast path).
__global__ __launch_bounds__(256) void detect_kernel(
    const void* x, const void* gw, const void* sw1, const void* sw2,
    const void* rw1, const void* rw2, int* flags, int* meta) {
  __shared__ int cnt;
  __shared__ int sflags[6];
  const void* ptrs[6] = {x, gw, sw1, sw2, rw1, rw2};
  for (int tnum = 0; tnum < 6; ++tnum) {
    if (threadIdx.x == 0) cnt = 0;
    __syncthreads();
    const u16* p = (const u16*)ptrs[tnum];
    int local = 0;
    for (int i = threadIdx.x; i < 4096; i += 256) {
      unsigned ef = (p[i] >> 7) & 0xFFu;
      if (ef >= 0xE0u) ++local;
    }
    if (local) atomicAdd(&cnt, local);
    __syncthreads();
    if (threadIdx.x == 0) sflags[tnum] = (cnt >= 16) ? 1 : 0;
    __syncthreads();
  }
  if (threadIdx.x == 0) {
#pragma unroll
    for (int i = 0; i < 6; ++i) flags[i] = sflags[i];
    flags[6] = sflags[0];  // output dtype follows x
    flags[7] = 0;          // ws bf16 buffers
  }
  if (meta && threadIdx.x < 24) meta[threadIdx.x] = 0;
}

// merged conversion over x + 4 weight tensors; per-segment flag early-exit
// (bf16 inputs are consumed raw downstream -- skip-copy).
#define U8_X  (T_TOK * DD / 8)
#define U8_S1 (NSH * FF * DD / 8)
#define U8_R1 (EE * FF * DD / 8)
#define U8_S2 (NSH * DD * FF / 8)
#define U8_R2 (EE * DD * FF / 8)
#define U8_C0 (U8_X)
#define U8_C1 (U8_C0 + U8_S1)
#define U8_C2 (U8_C1 + U8_R1)
#define U8_C3 (U8_C2 + U8_S2)
#define U8_C4 (U8_C3 + U8_R2)
__global__ __launch_bounds__(256) void conv_all(
    const void* __restrict__ x, const void* __restrict__ sw1,
    const void* __restrict__ rw1, const void* __restrict__ sw2,
    const void* __restrict__ rw2, u16* __restrict__ xb,
    u16* __restrict__ s1b, u16* __restrict__ r1b, u16* __restrict__ s2b,
    u16* __restrict__ r2b, const int* __restrict__ flags) {
  size_t u = (size_t)blockIdx.x * 256 + threadIdx.x;
  const void* src; u16* dst; int fi; size_t base;
  if (u < U8_C0)      { src = x;   dst = xb;  fi = 0; base = 0; }
  else if (u < U8_C1) { src = sw1; dst = s1b; fi = 2; base = U8_C0; }
  else if (u < U8_C2) { src = rw1; dst = r1b; fi = 4; base = U8_C1; }
  else if (u < U8_C3) { src = sw2; dst = s2b; fi = 3; base = U8_C2; }
  else                { src = rw2; dst = r2b; fi = 5; base = U8_C3; }
  int f = flags[fi];
  if (!f) return;               // bf16: raw tensor used directly downstream
  size_t i = (u - base) * 8;
  *(bf16x8*)(dst + i) = load8(src, i, f);
}

// Router: FULL-precision logits (raw x, raw gw), vectorized 16B loads.
__global__ __launch_bounds__(256) void router_v(
    const void* __restrict__ x, const void* __restrict__ gw,
    const u16* __restrict__ gb, const int* __restrict__ flags,
    float* __restrict__ cw, int2* __restrict__ tix) {
  int wave = threadIdx.x >> 6, lane = threadIdx.x & 63;
  int t = blockIdx.x * 4 + wave;
  int fx = flags[0], fg = flags[1];
  float xf[8];
  loadf8(x, (size_t)t * DD + lane * 8, fx, xf);
  float acc[EE];
#pragma unroll
  for (int e = 0; e < EE; ++e) {
    float gf[8];
    loadf8(gw, (size_t)e * DD + lane * 8, fg, gf);
    float a = 0.f;
#pragma unroll
    for (int j = 0; j < 8; ++j) a = fmaf(xf[j], gf[j], a);
    acc[e] = a;
  }
#pragma unroll
  for (int e = 0; e < EE; ++e) {
    float v = acc[e];
#pragma unroll
    for (int off = 32; off > 0; off >>= 1) v += __shfl_xor(v, off, 64);
    acc[e] = v;
  }
  if (lane == 0) {
    float m = -1e30f;
#pragma unroll
    for (int e = 0; e < EE; ++e) {
      acc[e] += bf2f(gb[e]);   // all-zero: dtype-agnostic
      m = fmaxf(m, acc[e]);
    }
    float p[EE], s = 0.f;
#pragma unroll
    for (int e = 0; e < EE; ++e) { p[e] = expf(acc[e] - m); s += p[e]; }
    int i1 = 0;
#pragma unroll
    for (int e = 1; e < EE; ++e) if (p[e] > p[i1]) i1 = e;
    int i2 = (i1 == 0) ? 1 : 0;
#pragma unroll
    for (int e = 0; e < EE; ++e)
      if (e != i1 && p[e] > p[i2]) i2 = e;
    float inv = 1.0f / s;
#pragma unroll
    for (int e = 0; e < EE; ++e)
      cw[t * EE + e] = (e == i1 || e == i2) ? p[e] * inv : 0.0f;
    tix[t] = make_int2(i1, i2);
  }
}

// build lists + pad, ONE single-block kernel (all-lane atomics: TA/L2
// combines same-address lanes -- NOT the round-2 single-lane mistake).
// meta: [0..7]=cnt, [8..15]=pc (padded), [16..23]=row prefix
__global__ __launch_bounds__(1024) void build_pad(
    const int2* __restrict__ tix, int* __restrict__ meta,
    unsigned* __restrict__ list, int4* __restrict__ srec) {
  for (int t = threadIdx.x; t < T_TOK; t += 1024) {
    int2 ii = tix[t];
    int p0 = atomicAdd(&meta[ii.x], 1);
    list[(size_t)ii.x * CAP + p0] = (unsigned)t;
    int p1 = atomicAdd(&meta[ii.y], 1);
    list[(size_t)ii.y * CAP + p1] = (unsigned)t;
    srec[t] = make_int4(ii.x, p0, ii.y, p1);
  }
  __syncthreads();
  if (threadIdx.x == 0) {
    int off = 0;
    for (int e = 0; e < EE; ++e) {
      int c = meta[e];
      int pc = (c + BM - 1) & ~(BM - 1);
      meta[8 + e] = pc;
      meta[16 + e] = off;
      off += pc;
    }
  }
  __syncthreads();
#pragma unroll
  for (int e = 0; e < EE; ++e) {
    int c = meta[e], pc = meta[8 + e];
    for (int i = c + threadIdx.x; i < pc; i += 1024)
      list[(size_t)e * CAP + i] = PADF;
  }
}

// ========== fast path: pipelined swizzled BK=64 128x128 GEMMs ==========

// FFN1 (shared + routed gather) in ONE dispatch. grid (16, 32, 10).
// Plain block mapping (round-7 XCD remap REVERTED: FETCH 65->91MB, dur +4).
__global__ __launch_bounds__(256) void g1_fused(
    const void* __restrict__ xr, const u16* __restrict__ xb,
    const void* __restrict__ s1r, const u16* __restrict__ s1b,
    const u16* __restrict__ sb1,
    const void* __restrict__ r1r, const u16* __restrict__ r1b,
    const u16* __restrict__ rb1, const unsigned* __restrict__ list,
    const int* __restrict__ meta, const int* __restrict__ flags,
    u16* __restrict__ Hsh, u16* __restrict__ Hrt) {
  // skip-copy: raw tensor when already bf16
  const u16* xp  = flags[0] ? xb  : (const u16*)xr;
  const u16* s1p = flags[2] ? s1b : (const u16*)s1r;
  const u16* r1p = flags[4] ? r1b : (const u16*)r1r;

  int z  = blockIdx.z;
  int bm = blockIdx.y * BM;
  int xx = blockIdx.x;

  int tid = threadIdx.x, lane = tid & 63, wave = tid >> 6;
  int wm = (wave >> 1) * 64, wn = (wave & 1) * 64;
  int r = lane & 15, q = lane >> 4;
  const int K = DD;

  // staging geometry: idx = c*256+tid; row = c*32 + (tid>>3); unit = tid&7
  int rsub = tid >> 3;
  int us = (tid & 7) ^ (rsub & 7);   // pre-swizzled source unit

  __shared__ u16 As[2 * TILEU];   // 32KB (2-deep dbuf)
  __shared__ u16 Bs[2 * TILEU];   // 32KB

  const u16 *gA[4], *gB[4];
  int e = 0, ho = 0, bn;
  if (z < 2) {
    bn = (z * 16 + xx) * BN;
#pragma unroll
    for (int c = 0; c < 4; ++c) {
      gA[c] = xp + (size_t)(bm + c * 32 + rsub) * K + us * 8;
      gB[c] = s1p + (size_t)(bn + c * 32 + rsub) * K + us * 8;
    }
  } else {
    e = z - 2;
    if (bm >= meta[8 + e]) return;
    ho = meta[16 + e];
    bn = xx * BN;
#pragma unroll
    for (int c = 0; c < 4; ++c) {
      unsigned tk = list[(size_t)e * CAP + bm + c * 32 + rsub] & 0x7fffffffu;
      gA[c] = xp + (size_t)tk * K + us * 8;
      gB[c] = r1p + (size_t)e * FF * DD + (size_t)(bn + c * 32 + rsub) * K +
              us * 8;
    }
  }

  floatx4 acc[4][4];
  floatx4 zero = {0.f, 0.f, 0.f, 0.f};
#pragma unroll
  for (int i = 0; i < 4; ++i)
#pragma unroll
    for (int j = 0; j < 4; ++j) acc[i][j] = zero;

  core128pipe(gA[0], gA[1], gA[2], gA[3], gB[0], gB[1], gB[2], gB[3],
              K, As, Bs, acc, wave, wm, wn, r, q);

  if (z < 2) {
#pragma unroll
    for (int mi = 0; mi < 4; ++mi)
#pragma unroll
      for (int ni = 0; ni < 4; ++ni) {
        int col = bn + wn + ni * 16 + r;
        float bv = bf2f(sb1[col]);
#pragma unroll
        for (int rr = 0; rr < 4; ++rr) {
          int row = bm + wm + mi * 16 + q * 4 + rr;
          float v = acc[mi][ni][rr] + bv;
          Hsh[(size_t)row * (NSH * FF) + col] = f2bf(fast_gelu(v));
        }
      }
  } else {
#pragma unroll
    for (int mi = 0; mi < 4; ++mi)
#pragma unroll
      for (int ni = 0; ni < 4; ++ni) {
        int col = bn + wn + ni * 16 + r;
        float bv = bf2f(rb1[(size_t)e * FF + col]);
#pragma unroll
        for (int rr = 0; rr < 4; ++rr) {
          int slot = bm + wm + mi * 16 + q * 4 + rr;
          float v = acc[mi][ni][rr] + bv;
          Hrt[(size_t)(ho + slot) * FF + col] = f2bf(fast_gelu(v));
        }
      }
  }
}

// FFN2 (shared planes + routed compact) in ONE dispatch. grid (4, 32, 10).
// XCD remap kept (round 7: g2 left top-5 after it).
__global__ __launch_bounds__(256) void g2_fused(
    const u16* __restrict__ Hsh,
    const void* __restrict__ s2r, const u16* __restrict__ s2b,
    const u16* __restrict__ sb2, const u16* __restrict__ Hrt,
    const void* __restrict__ r2r, const u16* __restrict__ r2b,
    const u16* __restrict__ rb2,
    const unsigned* __restrict__ list, const int* __restrict__ meta,
    const int* __restrict__ flags, const float* __restrict__ cw,
    float* __restrict__ oacc, float* __restrict__ Ort) {
  const u16* s2p = flags[3] ? s2b : (const u16*)s2r;
  const u16* r2p = flags[5] ? r2b : (const u16*)r2r;

  // XCD remap: 4 x-sharers of an A-panel get ids == same (mod 8)
  int L  = blockIdx.x + 4 * (blockIdx.y + 32 * blockIdx.z);
  int xx = (L & 31) >> 3;                     // 0..3 (bn tile)
  int pp = ((L >> 5) << 3) | (L & 7);         // panel 0..319
  int z  = pp >> 5;                           // 0..9
  int bm = (pp & 31) * BM;
  int bn = xx * BN;

  int tid = threadIdx.x, lane = tid & 63, wave = tid >> 6;
  int wm = (wave >> 1) * 64, wn = (wave & 1) * 64;
  int r = lane & 15, q = lane >> 4;
  const int K = FF;

  int rsub = tid >> 3;
  int us = (tid & 7) ^ (rsub & 7);

  __shared__ u16 As[2 * TILEU];
  __shared__ u16 Bs[2 * TILEU];

  const u16 *gA[4], *gB[4];
  int e = 0, ho = 0;
  if (z < NSH) {
    const int ldA = NSH * FF;
#pragma unroll
    for (int c = 0; c < 4; ++c) {
      gA[c] = Hsh + (size_t)(bm + c * 32 + rsub) * ldA + (size_t)z * FF +
              us * 8;
      gB[c] = s2p + (size_t)z * DD * FF + (size_t)(bn + c * 32 + rsub) * K +
              us * 8;
    }
  } else {
    e = z - NSH;
    if (bm >= meta[8 + e]) return;
    ho = meta[16 + e];
#pragma unroll
    for (int c = 0; c < 4; ++c) {
      gA[c] = Hrt + (size_t)(ho + bm + c * 32 + rsub) * K + us * 8;
      gB[c] = r2p + (size_t)e * DD * FF + (size_t)(bn + c * 32 + rsub) * K +
              us * 8;
    }
  }

  floatx4 acc[4][4];
  floatx4 zero = {0.f, 0.f, 0.f, 0.f};
#pragma unroll
  for (int i = 0; i < 4; ++i)
#pragma unroll
    for (int j = 0; j < 4; ++j) acc[i][j] = zero;

  core128pipe(gA[0], gA[1], gA[2], gA[3], gB[0], gB[1], gB[2], gB[3],
              K, As, Bs, acc, wave, wm, wn, r, q);

  if (z < NSH) {
    float* op = oacc + (size_t)z * T_TOK * DD;
#pragma unroll
    for (int mi = 0; mi < 4; ++mi)
#pragma unroll
      for (int ni = 0; ni < 4; ++ni) {
        int col = bn + wn + ni * 16 + r;
        float bv = bf2f(sb2[(size_t)z * DD + col]);
#pragma unroll
        for (int rr = 0; rr < 4; ++rr) {
          int row = bm + wm + mi * 16 + q * 4 + rr;
          op[(size_t)row * DD + col] = acc[mi][ni][rr] + bv;
        }
      }
  } else {
#pragma unroll
    for (int mi = 0; mi < 4; ++mi)
#pragma unroll
      for (int rr = 0; rr < 4; ++rr) {
        int slot = bm + wm + mi * 16 + q * 4 + rr;
        unsigned raw = list[(size_t)e * CAP + slot];
        if (raw & PADF) continue;
        float s = cw[raw * EE + e];
#pragma unroll
        for (int ni = 0; ni < 4; ++ni) {
          int col = bn + wn + ni * 16 + r;
          float v = acc[mi][ni][rr] + bf2f(rb2[(size_t)e * DD + col]);
          Ort[(size_t)(ho + slot) * DD + col] = s * v;
        }
      }
  }
}

// final: out[t] = oacc0[t] + oacc1[t] + Ort[g0(t)] + Ort[g1(t)]
typedef struct { u16 a, b, c, d; } u16x4;
__global__ __launch_bounds__(256) void combine_out(
    const float* __restrict__ oacc, const float* __restrict__ Ort,
    const int4* __restrict__ srec, const int* __restrict__ meta,
    void* __restrict__ out, const int* __restrict__ flags) {
  int t  = blockIdx.x * 2 + (threadIdx.x >> 7);
  int c4 = (threadIdx.x & 127) * 4;
  int4 sr = srec[t];
  int g0 = meta[16 + sr.x] + sr.y;
  int g1 = meta[16 + sr.z] + sr.w;
  float4 a = *(const float4*)(oacc + (size_t)t * DD + c4);
  float4 b = *(const float4*)(oacc + (size_t)(T_TOK + t) * DD + c4);
  float4 u = *(const float4*)(Ort + (size_t)g0 * DD + c4);
  float4 v = *(const float4*)(Ort + (size_t)g1 * DD + c4);
  float o0 = a.x + b.x + u.x + v.x;
  float o1 = a.y + b.y + u.y + v.y;
  float o2 = a.z + b.z + u.z + v.z;
  float o3 = a.w + b.w + u.w + v.w;
  size_t idx = (size_t)t * DD + c4;
  if (flags[6]) {
    *(float4*)((float*)out + idx) = make_float4(o0, o1, o2, o3);
  } else {
    u16x4 h = {f2bf(o0), f2bf(o1), f2bf(o2), f2bf(o3)};
    *(u16x4*)((u16*)out + idx) = h;
  }
}

// ---------------- fallback-path kernels (dense, unconverted) ----------------
__device__ __forceinline__ void gemm_core(const void* A, size_t aoff, int fA,
                                          const void* B, size_t boff, int fB,
                                          int K, u16* As, u16* Bs,
                                          floatx4 acc[4][4]) {
  int tid  = threadIdx.x;
  int lane = tid & 63, wave = tid >> 6;
  int wm = (wave >> 1) * 64, wn = (wave & 1) * 64;
  int r = lane & 15, q = lane >> 4;
  int srow = tid >> 2;
  int sc8  = (tid & 3) * 8;
  size_t abase = aoff + (size_t)srow * K + sc8;
  size_t bbase = boff + (size_t)srow * K + sc8;
  const size_t half = (size_t)64 * K;

  for (int k0 = 0; k0 < K; k0 += BK) {
    bf16x8 av0 = load8(A, abase + k0, fA);
    bf16x8 av1 = load8(A, abase + half + k0, fA);
    bf16x8 bv0 = load8(B, bbase + k0, fB);
    bf16x8 bv1 = load8(B, bbase + half + k0, fB);
    __syncthreads();
    *(bf16x8*)(As + srow * LDK + sc8)        = av0;
    *(bf16x8*)(As + (srow + 64) * LDK + sc8) = av1;
    *(bf16x8*)(Bs + srow * LDK + sc8)        = bv0;
    *(bf16x8*)(Bs + (srow + 64) * LDK + sc8) = bv1;
    __syncthreads();

    bf16x8 af[4], bfr[4];
#pragma unroll
    for (int mi = 0; mi < 4; ++mi)
      af[mi] = *(const bf16x8*)(As + (wm + mi * 16 + r) * LDK + q * 8);
#pragma unroll
    for (int ni = 0; ni < 4; ++ni)
      bfr[ni] = *(const bf16x8*)(Bs + (wn + ni * 16 + r) * LDK + q * 8);
#pragma unroll
    for (int mi = 0; mi < 4; ++mi)
#pragma unroll
      for (int ni = 0; ni < 4; ++ni)
        acc[mi][ni] = __builtin_amdgcn_mfma_f32_16x16x32_bf16(
            af[mi], bfr[ni], acc[mi][ni], 0, 0, 0);
  }
}

__global__ __launch_bounds__(256) void gemm1_gelu(
    const void* __restrict__ A, size_t aoff, const void* __restrict__ B,
    size_t boff, const u16* __restrict__ bias, size_t bioff,
    u16* __restrict__ H, const int* __restrict__ flags, int iA, int iB,
    int N, int K) {
  __shared__ u16 As[BM * LDK];
  __shared__ u16 Bs[BN * LDK];
  int fA = flags[iA], fB = flags[iB];
  floatx4 acc[4][4];
  floatx4 zero = {0.f, 0.f, 0.f, 0.f};
#pragma unroll
  for (int i = 0; i < 4; ++i)
#pragma unroll
    for (int j = 0; j < 4; ++j) acc[i][j] = zero;

  int bm = blockIdx.y * BM, bn = blockIdx.x * BN;
  gemm_core(A, aoff + (size_t)bm * K, fA, B, boff + (size_t)bn * K, fB, K,
            As, Bs, acc);

  int tid = threadIdx.x, wave = tid >> 6, lane = tid & 63;
  int wm = (wave >> 1) * 64, wn = (wave & 1) * 64;
  int r = lane & 15, q = lane >> 4;
#pragma unroll
  for (int mi = 0; mi < 4; ++mi)
#pragma unroll
    for (int ni = 0; ni < 4; ++ni) {
      int col = bn + wn + ni * 16 + r;
      float bv = bf2f(bias[bioff + col]);
#pragma unroll
      for (int rr = 0; rr < 4; ++rr) {
        int row = bm + wm + mi * 16 + q * 4 + rr;
        float v = acc[mi][ni][rr] + bv;
        H[(size_t)row * N + col] = f2bf(fast_gelu(v));
      }
    }
}

__global__ __launch_bounds__(256) void gemm2_acc(
    const u16* __restrict__ A, const void* __restrict__ B, size_t boff,
    const u16* __restrict__ bias, size_t bioff, float* __restrict__ outf,
    void* __restrict__ outb, const float* __restrict__ cw,
    const int* __restrict__ flags, int iB, int expert, int accum,
    int row0, int N, int K) {
  __shared__ u16 As[BT2 * LDK];
  __shared__ u16 Bs[BT2 * LDK];
  int fB = flags[iB], fO = flags[6];
  floatx4 acc[2][2];
  floatx4 zero = {0.f, 0.f, 0.f, 0.f};
#pragma unroll
  for (int i = 0; i < 2; ++i)
#pragma unroll
    for (int j = 0; j < 2; ++j) acc[i][j] = zero;

  int bm = blockIdx.y * BT2, bn = blockIdx.x * BT2;
  int tid  = threadIdx.x;
  int lane = tid & 63, wave = tid >> 6;
  int wm = (wave >> 1) * 32, wn = (wave & 1) * 32;
  int r = lane & 15, q = lane >> 4;
  int srow = tid >> 2;
  int sc8  = (tid & 3) * 8;
  size_t abase = (size_t)(bm + srow) * K + sc8;
  size_t bbase = boff + (size_t)(bn + srow) * K + sc8;

  for (int k0 = 0; k0 < K; k0 += BK) {
    bf16x8 av = *(const bf16x8*)(A + abase + k0);
    bf16x8 bv = load8(B, bbase + k0, fB);
    __syncthreads();
    *(bf16x8*)(As + srow * LDK + sc8) = av;
    *(bf16x8*)(Bs + srow * LDK + sc8) = bv;
    __syncthreads();

    bf16x8 af[2], bfr[2];
#pragma unroll
    for (int mi = 0; mi < 2; ++mi)
      af[mi] = *(const bf16x8*)(As + (wm + mi * 16 + r) * LDK + q * 8);
#pragma unroll
    for (int ni = 0; ni < 2; ++ni)
      bfr[ni] = *(const bf16x8*)(Bs + (wn + ni * 16 + r) * LDK + q * 8);
#pragma unroll
    for (int mi = 0; mi < 2; ++mi)
#pragma unroll
      for (int ni = 0; ni < 2; ++ni)
        acc[mi][ni] = __builtin_amdgcn_mfma_f32_16x16x32_bf16(
            af[mi], bfr[ni], acc[mi][ni], 0, 0, 0);
  }

#pragma unroll
  for (int mi = 0; mi < 2; ++mi)
#pragma unroll
    for (int rr = 0; rr < 4; ++rr) {
      int grow = row0 + bm + wm + mi * 16 + q * 4 + rr;
      float s = cw ? cw[grow * EE + expert] : 1.0f;
#pragma unroll
      for (int ni = 0; ni < 2; ++ni) {
        int col = bn + wn + ni * 16 + r;
        float v = acc[mi][ni][rr] + bf2f(bias[bioff + col]);
        size_t idx = (size_t)grow * N + col;
        if (outf) {
          float prev = accum ? outf[idx] : 0.0f;
          outf[idx] = prev + s * v;
        } else if (fO) {
          float* ob = (float*)outb;
          float prev = accum ? ob[idx] : 0.0f;
          ob[idx] = prev + s * v;
        } else {
          u16* ob = (u16*)outb;
          float prev = accum ? bf2f(ob[idx]) : 0.0f;
          ob[idx] = f2bf(prev + s * v);
        }
      }
    }
}

__global__ __launch_bounds__(256) void convert_out(
    const float* __restrict__ acc, void* __restrict__ out,
    const int* __restrict__ flags, int n) {
  int i = blockIdx.x * blockDim.x + threadIdx.x;
  if (i >= n) return;
  if (flags[6]) ((float*)out)[i] = acc[i];
  else ((u16*)out)[i] = f2bf(acc[i]);
}

extern "C" void kernel_launch(void* const* d_in, const int* in_sizes, int n_in,
                              void* d_out, int out_size, void* d_ws, size_t ws_size,
                              hipStream_t stream) {
  (void)in_sizes; (void)n_in; (void)out_size;
  const void* x   = d_in[0];
  const void* gw  = d_in[1];
  const u16*  gb  = (const u16*)d_in[2];
  const void* sw1 = d_in[3];
  const u16*  sb1 = (const u16*)d_in[4];
  const void* sw2 = d_in[5];
  const u16*  sb2 = (const u16*)d_in[6];
  const void* rw1 = d_in[7];
  const u16*  rb1 = (const u16*)d_in[8];
  const void* rw2 = d_in[9];
  const u16*  rb2 = (const u16*)d_in[10];

  const size_t NX   = (size_t)T_TOK * DD;
  const size_t NW1S = (size_t)NSH * FF * DD;
  const size_t NW1R = (size_t)EE * FF * DD;
  const size_t NW2S = (size_t)NSH * DD * FF;
  const size_t NW2R = (size_t)EE * DD * FF;

  // fast-path layout
  size_t off = 0;
  const size_t flO   = off; off += 256;
  const size_t cwO   = off; off += (size_t)T_TOK * EE * 4;
  const size_t tixO  = off; off += (size_t)T_TOK * 8;
  const size_t metaO = off; off += 256;
  const size_t listO = off; off += (size_t)EE * CAP * 4;
  const size_t srecO = off; off += (size_t)T_TOK * 16;
  const size_t accO  = off; off += (size_t)NSH * T_TOK * DD * 4;
  const size_t hshO  = off; off += (size_t)T_TOK * NSH * FF * 2;
  const size_t hrtO  = off; off += (size_t)NSLOT * FF * 2;
  const size_t ortO  = off; off += (size_t)NSLOT * DD * 4;
  const size_t xbO   = off; off += NX * 2;
  const size_t s1O   = off; off += NW1S * 2;
  const size_t r1O   = off; off += NW1R * 2;
  const size_t s2O   = off; off += NW2S * 2;
  const size_t r2O   = off; off += NW2R * 2;
  const int fast = (off <= ws_size) ? 1 : 0;

  char* ws = (char*)d_ws;
  int*   flags = (int*)(ws + flO);
  float* cw    = (float*)(ws + cwO);
  dim3 blk(256);

  if (fast) {
    int2*     tix  = (int2*)(ws + tixO);
    int*      meta = (int*)(ws + metaO);
    unsigned* list = (unsigned*)(ws + listO);
    int4*     srec = (int4*)(ws + srecO);
    float*    oacc = (float*)(ws + accO);
    u16*      Hsh  = (u16*)(ws + hshO);
    u16*      Hrt  = (u16*)(ws + hrtO);
    float*    Ort  = (float*)(ws + ortO);
    u16*      xb   = (u16*)(ws + xbO);
    u16*      s1b  = (u16*)(ws + s1O);
    u16*      r1b  = (u16*)(ws + r1O);
    u16*      s2b  = (u16*)(ws + s2O);
    u16*      r2b  = (u16*)(ws + r2O);

    detect_kernel<<<1, 256, 0, stream>>>(x, gw, sw1, sw2, rw1, rw2, flags,
                                         meta);
    conv_all<<<U8_C4 / 256, 256, 0, stream>>>(x, sw1, rw1, sw2, rw2, xb, s1b,
                                              r1b, s2b, r2b, flags);
    router_v<<<T_TOK / 4, 256, 0, stream>>>(x, gw, gb, flags, cw, tix);
    build_pad<<<1, 1024, 0, stream>>>(tix, meta, list, srec);

    // FFN1: shared (z<2) + routed gather (z>=2), one dispatch
    dim3 gf1(16, T_TOK / BM, 2 + EE);            // 16 x 32 x 10
    g1_fused<<<gf1, blk, 0, stream>>>(x, xb, sw1, s1b, sb1, rw1, r1b, rb1,
                                      list, meta, flags, Hsh, Hrt);
    // FFN2: shared planes (z<NSH) + routed compact (z>=NSH), one dispatch
    dim3 gf2(DD / BN, CAP / BM, NSH + EE);       // 4 x 32 x 10
    g2_fused<<<gf2, blk, 0, stream>>>(Hsh, sw2, s2b, sb2, Hrt, rw2, r2b, rb2,
                                      list, meta, flags, cw, oacc, Ort);
    combine_out<<<T_TOK / 2, 256, 0, stream>>>(oacc, Ort, srec, meta, d_out,
                                               flags);
    return;
  }

  // -------- fallback: dense all-FFN path (no conversion), ws-adaptive --------
  detect_kernel<<<1, 256, 0, stream>>>(x, gw, sw1, sw2, rw1, rw2, flags,
                                       nullptr);
  const size_t flB = 256, cwB = (size_t)T_TOK * EE * 4, tixB = (size_t)T_TOK * 8;
  const size_t accB = (size_t)T_TOK * DD * 4;
  static const int tcs[4] = {4096, 2048, 1024, 512};
  int TC = 0, use_f32 = 1;
  for (int i = 0; i < 4; ++i)
    if (flB + cwB + tixB + accB + (size_t)tcs[i] * FF * 2 <= ws_size) { TC = tcs[i]; break; }
  if (!TC) {
    use_f32 = 0;
    for (int i = 0; i < 4; ++i)
      if (flB + cwB + tixB + (size_t)tcs[i] * FF * 2 <= ws_size) { TC = tcs[i]; break; }
  }
  if (!TC) { TC = 512; use_f32 = 0; }

  int2*  tix     = (int2*)(ws + flB + cwB);
  float* out_acc = use_f32 ? (float*)(ws + flB + cwB + tixB) : nullptr;
  u16*   H       = (u16*)(ws + flB + cwB + tixB + (use_f32 ? accB : 0));

  router_v<<<T_TOK / 4, 256, 0, stream>>>(x, gw, gb, flags, cw, tix);
  dim3 g1(FF / BN, TC / BM);
  dim3 g2(DD / BT2, TC / BT2);
  const int nchunk = T_TOK / TC;
  for (int f = 0; f < NSH + EE; ++f) {
    const void *w1, *w2; const u16 *b1, *b2; const float* cwp;
    int expert, i1, i2v; size_t w1off, w2off, b1off, b2off;
    if (f < NSH) {
      w1 = sw1; w2 = sw2; b1 = sb1; b2 = sb2;
      w1off = (size_t)f * FF * DD; w2off = (size_t)f * DD * FF;
      b1off = (size_t)f * FF; b2off = (size_t)f * DD;
      cwp = nullptr; expert = 0; i1 = 2; i2v = 3;
    } else {
      int e = f - NSH;
      w1 = rw1; w2 = rw2; b1 = rb1; b2 = rb2;
      w1off = (size_t)e * FF * DD; w2off = (size_t)e * DD * FF;
      b1off = (size_t)e * FF; b2off = (size_t)e * DD;
      cwp = cw; expert = e; i1 = 4; i2v = 5;
    }
    int accum = (f > 0) ? 1 : 0;
    for (int c = 0; c < nchunk; ++c) {
      size_t t0 = (size_t)c * TC;
      gemm1_gelu<<<g1, blk, 0, stream>>>(x, t0 * DD, w1, w1off, b1, b1off, H,
                                         flags, 0, i1, FF, DD);
      gemm2_acc<<<g2, blk, 0, stream>>>(H, w2, w2off, b2, b2off, out_acc,
                                        d_out, cwp, flags, i2v, expert, accum,
                                        (int)t0, DD, FF);
    }
  }
  if (use_f32)
    convert_out<<<(T_TOK * DD) / 256, 256, 0, stream>>>(out_acc, d_out, flags,
                                                        T_TOK * DD);
}

// Round 9
// 356.971 us; speedup vs baseline: 1.0518x; 1.0360x over previous
//
#include <hip/hip_runtime.h>
#include <math.h>

typedef unsigned short u16;
typedef __attribute__((ext_vector_type(8))) __bf16 bf16x8;
typedef __attribute__((ext_vector_type(4))) float floatx4;

#define T_TOK 4096
#define DD    512
#define FF    2048
#define EE    8
#define NSH   2

#define BM 128
#define BN 128
#define BK 32
#define LDK 40   // fallback kernels: padded LDS row stride
#define BT2 64   // fallback gemm2 N-tile
#define CAP 4096
#define PADF 0x80000000u
#define NSLOT (2 * T_TOK + EE * BM)   // 9216 compact rows max

__device__ __forceinline__ float bf2f(u16 v) {
  union { unsigned int u; float f; } c; c.u = ((unsigned int)v) << 16; return c.f;
}
__device__ __forceinline__ u16 f2bf(float f) {
  union { float ff; unsigned int u; } c; c.ff = f;
  unsigned int u = c.u;
  u += 0x7fffu + ((u >> 16) & 1u);   // RNE
  return (u16)(u >> 16);
}
__device__ __forceinline__ float decode(const void* p, size_t idx, int f) {
  return f ? ((const float*)p)[idx] : bf2f(((const u16*)p)[idx]);
}
__device__ __forceinline__ bf16x8 load8(const void* base, size_t idx, int f) {
  if (f) {
    const float* p = (const float*)base + idx;
    float4 a = *(const float4*)p;
    float4 b = *(const float4*)(p + 4);
    union { bf16x8 v; u16 s[8]; } u;
    u.s[0] = f2bf(a.x); u.s[1] = f2bf(a.y); u.s[2] = f2bf(a.z); u.s[3] = f2bf(a.w);
    u.s[4] = f2bf(b.x); u.s[5] = f2bf(b.y); u.s[6] = f2bf(b.z); u.s[7] = f2bf(b.w);
    return u.v;
  }
  return *(const bf16x8*)((const u16*)base + idx);
}
// full-precision 8-element load (fp32 stays fp32; bf16 widened) -- router path.
// Top-k selection is discontinuous in the logits: router must NOT quantize.
__device__ __forceinline__ void loadf8(const void* p, size_t idx, int f,
                                       float* o) {
  if (f) {
    const float* q = (const float*)p + idx;
    float4 a = *(const float4*)q;
    float4 b = *(const float4*)(q + 4);
    o[0] = a.x; o[1] = a.y; o[2] = a.z; o[3] = a.w;
    o[4] = b.x; o[5] = b.y; o[6] = b.z; o[7] = b.w;
  } else {
    union { bf16x8 v; u16 s[8]; } u;
    u.v = *(const bf16x8*)((const u16*)p + idx);
#pragma unroll
    for (int j = 0; j < 8; ++j) o[j] = bf2f(u.s[j]);
  }
}

// fast exact-GELU: erf via Abramowitz-Stegun 7.1.26 (|err| 1.5e-7), native rcp/exp
__device__ __forceinline__ float fast_gelu(float v) {
  float x  = v * 0.70710678118654752f;
  float ax = fabsf(x);
  float t  = __builtin_amdgcn_rcpf(fmaf(0.3275911f, ax, 1.0f));
  float p  = fmaf(t, 1.061405429f, -1.453152027f);
  p = fmaf(t, p, 1.421413741f);
  p = fmaf(t, p, -0.284496736f);
  p = fmaf(t, p, 0.254829592f);
  p = p * t;
  float e  = __expf(-ax * ax);
  float er = fmaf(-p, e, 1.0f);          // erf(|x|)
  er = (x < 0.f) ? -er : er;
  return 0.5f * v * (1.0f + er);
}

// async 16B global->LDS. LDS dest is wave-uniform base; HW writes base+lane*16.
__device__ __forceinline__ void gll16(const void* g, void* l) {
  __builtin_amdgcn_global_load_lds(
      (const __attribute__((address_space(1))) void*)g,
      (__attribute__((address_space(3))) void*)l, 16, 0, 0);
}

#define BK2 64
#define TILEU (BM * BK2)   // 8192 u16 = 16KB per buffer

// stage one 128x64 k-slab (8 global_load_lds = 8 vmcnt increments per wave)
__device__ __forceinline__ void stage8(
    const u16* gA0, const u16* gA1, const u16* gA2, const u16* gA3,
    const u16* gB0, const u16* gB1, const u16* gB2, const u16* gB3,
    u16* Asb, u16* Bsb, int wave, int k0) {
  gll16(gA0 + k0, Asb + wave * 512);
  gll16(gA1 + k0, Asb + 2048 + wave * 512);
  gll16(gA2 + k0, Asb + 4096 + wave * 512);
  gll16(gA3 + k0, Asb + 6144 + wave * 512);
  gll16(gB0 + k0, Bsb + wave * 512);
  gll16(gB1 + k0, Bsb + 2048 + wave * 512);
  gll16(gB2 + k0, Bsb + 4096 + wave * 512);
  gll16(gB3 + k0, Bsb + 6144 + wave * 512);
}

// ===== single-buffer swizzled core (g1's best: round 6, <=82.7us).
// 32KB LDS -> 5 blocks/CU; inter-wave TLP does the latency hiding.
// Swizzle: linear LDS dest, inverse-swz global source, same swz on ds_read
// (bank-conflict 4.29M -> 0, round 6).
__device__ __forceinline__ void core128swz(
    const u16* gA0, const u16* gA1, const u16* gA2, const u16* gA3,
    const u16* gB0, const u16* gB1, const u16* gB2, const u16* gB3,
    int K, u16* As, u16* Bs, floatx4 acc[4][4],
    int wave, int wm, int wn, int r, int q) {
  const int rs = r & 7;                 // fragment-row low bits (R&7 == r&7)
  for (int k0 = 0; k0 < K; k0 += BK2) {
    __syncthreads();
    stage8(gA0, gA1, gA2, gA3, gB0, gB1, gB2, gB3, As, Bs, wave, k0);
    __syncthreads();   // compiler drains vmcnt before barrier
#pragma unroll
    for (int s = 0; s < 2; ++s) {       // two k=32 slabs per 64-elem row
      bf16x8 af[4], bfr[4];
#pragma unroll
      for (int mi = 0; mi < 4; ++mi) {
        int R = wm + mi * 16 + r;
        int u = (s * 4 + q) ^ rs;
        af[mi] = *(const bf16x8*)(As + R * 64 + u * 8);
      }
#pragma unroll
      for (int ni = 0; ni < 4; ++ni) {
        int R = wn + ni * 16 + r;
        int u = (s * 4 + q) ^ rs;
        bfr[ni] = *(const bf16x8*)(Bs + R * 64 + u * 8);
      }
#pragma unroll
      for (int mi = 0; mi < 4; ++mi)
#pragma unroll
        for (int ni = 0; ni < 4; ++ni)
          acc[mi][ni] = __builtin_amdgcn_mfma_f32_16x16x32_bf16(
              af[mi], bfr[ni], acc[mi][ni], 0, 0, 0);
    }
  }
}

// ===== T3+T4 pipelined core (g2's best: round 8 -- K=2048's 32 iters
// amortize the prologue; counted vmcnt(8) keeps next tile's loads in
// flight ACROSS the barrier). K-dependent: REGRESSED g1 (K=512, 8 iters,
// 64KB LDS -> 2 blocks/CU kills TLP; round 8: 83.8 -> 116.8us).
__device__ __forceinline__ void core128pipe(
    const u16* gA0, const u16* gA1, const u16* gA2, const u16* gA3,
    const u16* gB0, const u16* gB1, const u16* gB2, const u16* gB3,
    int K, u16* As, u16* Bs, floatx4 acc[4][4],
    int wave, int wm, int wn, int r, int q) {
  const int rs = r & 7;                 // fragment-row low bits (R&7 == r&7)
  stage8(gA0, gA1, gA2, gA3, gB0, gB1, gB2, gB3, As, Bs, wave, 0);
  int cur = 0;
  for (int k0 = 0; k0 < K; k0 += BK2) {
    const u16* Ac = As + cur * TILEU;
    const u16* Bc = Bs + cur * TILEU;
    if (k0 + BK2 < K) {
      stage8(gA0, gA1, gA2, gA3, gB0, gB1, gB2, gB3,
             As + (cur ^ 1) * TILEU, Bs + (cur ^ 1) * TILEU, wave, k0 + BK2);
      // wait for THIS tile's 8 loads; leave next tile's 8 in flight
      asm volatile("s_waitcnt vmcnt(8)" ::: "memory");
    } else {
      asm volatile("s_waitcnt vmcnt(0)" ::: "memory");
    }
    __builtin_amdgcn_sched_barrier(0);
    __builtin_amdgcn_s_barrier();       // all waves: cur tile landed
    __builtin_amdgcn_sched_barrier(0);
#pragma unroll
    for (int s = 0; s < 2; ++s) {       // two k=32 slabs per 64-elem row
      bf16x8 af[4], bfr[4];
#pragma unroll
      for (int mi = 0; mi < 4; ++mi) {
        int R = wm + mi * 16 + r;
        int u = (s * 4 + q) ^ rs;
        af[mi] = *(const bf16x8*)(Ac + R * 64 + u * 8);
      }
#pragma unroll
      for (int ni = 0; ni < 4; ++ni) {
        int R = wn + ni * 16 + r;
        int u = (s * 4 + q) ^ rs;
        bfr[ni] = *(const bf16x8*)(Bc + R * 64 + u * 8);
      }
#pragma unroll
      for (int mi = 0; mi < 4; ++mi)
#pragma unroll
        for (int ni = 0; ni < 4; ++ni)
          acc[mi][ni] = __builtin_amdgcn_mfma_f32_16x16x32_bf16(
              af[mi], bfr[ni], acc[mi][ni], 0, 0, 0);
    }
    __builtin_amdgcn_sched_barrier(0);
    __builtin_amdgcn_s_barrier();       // all waves done reading cur
    cur ^= 1;
  }
}

// Probe: classify tensors fp32(1)/bf16(0); zero meta (fast path).
__global__ __launch_bounds__(256) void detect_kernel(
    const void* x, const void* gw, const void* sw1, const void* sw2,
    const void* rw1, const void* rw2, int* flags, int* meta) {
  __shared__ int cnt;
  __shared__ int sflags[6];
  const void* ptrs[6] = {x, gw, sw1, sw2, rw1, rw2};
  for (int tnum = 0; tnum < 6; ++tnum) {
    if (threadIdx.x == 0) cnt = 0;
    __syncthreads();
    const u16* p = (const u16*)ptrs[tnum];
    int local = 0;
    for (int i = threadIdx.x; i < 4096; i += 256) {
      unsigned ef = (p[i] >> 7) & 0xFFu;
      if (ef >= 0xE0u) ++local;
    }
    if (local) atomicAdd(&cnt, local);
    __syncthreads();
    if (threadIdx.x == 0) sflags[tnum] = (cnt >= 16) ? 1 : 0;
    __syncthreads();
  }
  if (threadIdx.x == 0) {
#pragma unroll
    for (int i = 0; i < 6; ++i) flags[i] = sflags[i];
    flags[6] = sflags[0];  // output dtype follows x
    flags[7] = 0;          // ws bf16 buffers
  }
  if (meta && threadIdx.x < 24) meta[threadIdx.x] = 0;
}

// merged conversion over x + 4 weight tensors; per-segment flag early-exit
// (bf16 inputs are consumed raw downstream -- skip-copy).
#define U8_X  (T_TOK * DD / 8)
#define U8_S1 (NSH * FF * DD / 8)
#define U8_R1 (EE * FF * DD / 8)
#define U8_S2 (NSH * DD * FF / 8)
#define U8_R2 (EE * DD * FF / 8)
#define U8_C0 (U8_X)
#define U8_C1 (U8_C0 + U8_S1)
#define U8_C2 (U8_C1 + U8_R1)
#define U8_C3 (U8_C2 + U8_S2)
#define U8_C4 (U8_C3 + U8_R2)
__global__ __launch_bounds__(256) void conv_all(
    const void* __restrict__ x, const void* __restrict__ sw1,
    const void* __restrict__ rw1, const void* __restrict__ sw2,
    const void* __restrict__ rw2, u16* __restrict__ xb,
    u16* __restrict__ s1b, u16* __restrict__ r1b, u16* __restrict__ s2b,
    u16* __restrict__ r2b, const int* __restrict__ flags) {
  size_t u = (size_t)blockIdx.x * 256 + threadIdx.x;
  const void* src; u16* dst; int fi; size_t base;
  if (u < U8_C0)      { src = x;   dst = xb;  fi = 0; base = 0; }
  else if (u < U8_C1) { src = sw1; dst = s1b; fi = 2; base = U8_C0; }
  else if (u < U8_C2) { src = rw1; dst = r1b; fi = 4; base = U8_C1; }
  else if (u < U8_C3) { src = sw2; dst = s2b; fi = 3; base = U8_C2; }
  else                { src = rw2; dst = r2b; fi = 5; base = U8_C3; }
  int f = flags[fi];
  if (!f) return;               // bf16: raw tensor used directly downstream
  size_t i = (u - base) * 8;
  *(bf16x8*)(dst + i) = load8(src, i, f);
}

// Router: FULL-precision logits (raw x, raw gw), vectorized 16B loads.
__global__ __launch_bounds__(256) void router_v(
    const void* __restrict__ x, const void* __restrict__ gw,
    const u16* __restrict__ gb, const int* __restrict__ flags,
    float* __restrict__ cw, int2* __restrict__ tix) {
  int wave = threadIdx.x >> 6, lane = threadIdx.x & 63;
  int t = blockIdx.x * 4 + wave;
  int fx = flags[0], fg = flags[1];
  float xf[8];
  loadf8(x, (size_t)t * DD + lane * 8, fx, xf);
  float acc[EE];
#pragma unroll
  for (int e = 0; e < EE; ++e) {
    float gf[8];
    loadf8(gw, (size_t)e * DD + lane * 8, fg, gf);
    float a = 0.f;
#pragma unroll
    for (int j = 0; j < 8; ++j) a = fmaf(xf[j], gf[j], a);
    acc[e] = a;
  }
#pragma unroll
  for (int e = 0; e < EE; ++e) {
    float v = acc[e];
#pragma unroll
    for (int off = 32; off > 0; off >>= 1) v += __shfl_xor(v, off, 64);
    acc[e] = v;
  }
  if (lane == 0) {
    float m = -1e30f;
#pragma unroll
    for (int e = 0; e < EE; ++e) {
      acc[e] += bf2f(gb[e]);   // all-zero: dtype-agnostic
      m = fmaxf(m, acc[e]);
    }
    float p[EE], s = 0.f;
#pragma unroll
    for (int e = 0; e < EE; ++e) { p[e] = expf(acc[e] - m); s += p[e]; }
    int i1 = 0;
#pragma unroll
    for (int e = 1; e < EE; ++e) if (p[e] > p[i1]) i1 = e;
    int i2 = (i1 == 0) ? 1 : 0;
#pragma unroll
    for (int e = 0; e < EE; ++e)
      if (e != i1 && p[e] > p[i2]) i2 = e;
    float inv = 1.0f / s;
#pragma unroll
    for (int e = 0; e < EE; ++e)
      cw[t * EE + e] = (e == i1 || e == i2) ? p[e] * inv : 0.0f;
    tix[t] = make_int2(i1, i2);
  }
}

// build lists + pad, ONE single-block kernel (all-lane atomics: TA/L2
// combines same-address lanes -- NOT the round-2 single-lane mistake).
// meta: [0..7]=cnt, [8..15]=pc (padded), [16..23]=row prefix
__global__ __launch_bounds__(1024) void build_pad(
    const int2* __restrict__ tix, int* __restrict__ meta,
    unsigned* __restrict__ list, int4* __restrict__ srec) {
  for (int t = threadIdx.x; t < T_TOK; t += 1024) {
    int2 ii = tix[t];
    int p0 = atomicAdd(&meta[ii.x], 1);
    list[(size_t)ii.x * CAP + p0] = (unsigned)t;
    int p1 = atomicAdd(&meta[ii.y], 1);
    list[(size_t)ii.y * CAP + p1] = (unsigned)t;
    srec[t] = make_int4(ii.x, p0, ii.y, p1);
  }
  __syncthreads();
  if (threadIdx.x == 0) {
    int off = 0;
    for (int e = 0; e < EE; ++e) {
      int c = meta[e];
      int pc = (c + BM - 1) & ~(BM - 1);
      meta[8 + e] = pc;
      meta[16 + e] = off;
      off += pc;
    }
  }
  __syncthreads();
#pragma unroll
  for (int e = 0; e < EE; ++e) {
    int c = meta[e], pc = meta[8 + e];
    for (int i = c + threadIdx.x; i < pc; i += 1024)
      list[(size_t)e * CAP + i] = PADF;
  }
}

// ========== fast path GEMMs: per-kernel best cores (round-8 A/B) ==========

// FFN1 (shared + routed gather) in ONE dispatch. grid (16, 32, 10).
// Single-buffer core (best measured: round 6); plain block mapping.
__global__ __launch_bounds__(256) void g1_fused(
    const void* __restrict__ xr, const u16* __restrict__ xb,
    const void* __restrict__ s1r, const u16* __restrict__ s1b,
    const u16* __restrict__ sb1,
    const void* __restrict__ r1r, const u16* __restrict__ r1b,
    const u16* __restrict__ rb1, const unsigned* __restrict__ list,
    const int* __restrict__ meta, const int* __restrict__ flags,
    u16* __restrict__ Hsh, u16* __restrict__ Hrt) {
  // skip-copy: raw tensor when already bf16
  const u16* xp  = flags[0] ? xb  : (const u16*)xr;
  const u16* s1p = flags[2] ? s1b : (const u16*)s1r;
  const u16* r1p = flags[4] ? r1b : (const u16*)r1r;

  int z  = blockIdx.z;
  int bm = blockIdx.y * BM;
  int xx = blockIdx.x;

  int tid = threadIdx.x, lane = tid & 63, wave = tid >> 6;
  int wm = (wave >> 1) * 64, wn = (wave & 1) * 64;
  int r = lane & 15, q = lane >> 4;
  const int K = DD;

  // staging geometry: idx = c*256+tid; row = c*32 + (tid>>3); unit = tid&7
  int rsub = tid >> 3;
  int us = (tid & 7) ^ (rsub & 7);   // pre-swizzled source unit

  __shared__ u16 As[TILEU];   // 16KB single buffer (5 blocks/CU)
  __shared__ u16 Bs[TILEU];   // 16KB

  const u16 *gA[4], *gB[4];
  int e = 0, ho = 0, bn;
  if (z < 2) {
    bn = (z * 16 + xx) * BN;
#pragma unroll
    for (int c = 0; c < 4; ++c) {
      gA[c] = xp + (size_t)(bm + c * 32 + rsub) * K + us * 8;
      gB[c] = s1p + (size_t)(bn + c * 32 + rsub) * K + us * 8;
    }
  } else {
    e = z - 2;
    if (bm >= meta[8 + e]) return;
    ho = meta[16 + e];
    bn = xx * BN;
#pragma unroll
    for (int c = 0; c < 4; ++c) {
      unsigned tk = list[(size_t)e * CAP + bm + c * 32 + rsub] & 0x7fffffffu;
      gA[c] = xp + (size_t)tk * K + us * 8;
      gB[c] = r1p + (size_t)e * FF * DD + (size_t)(bn + c * 32 + rsub) * K +
              us * 8;
    }
  }

  floatx4 acc[4][4];
  floatx4 zero = {0.f, 0.f, 0.f, 0.f};
#pragma unroll
  for (int i = 0; i < 4; ++i)
#pragma unroll
    for (int j = 0; j < 4; ++j) acc[i][j] = zero;

  core128swz(gA[0], gA[1], gA[2], gA[3], gB[0], gB[1], gB[2], gB[3],
             K, As, Bs, acc, wave, wm, wn, r, q);

  if (z < 2) {
#pragma unroll
    for (int mi = 0; mi < 4; ++mi)
#pragma unroll
      for (int ni = 0; ni < 4; ++ni) {
        int col = bn + wn + ni * 16 + r;
        float bv = bf2f(sb1[col]);
#pragma unroll
        for (int rr = 0; rr < 4; ++rr) {
          int row = bm + wm + mi * 16 + q * 4 + rr;
          float v = acc[mi][ni][rr] + bv;
          Hsh[(size_t)row * (NSH * FF) + col] = f2bf(fast_gelu(v));
        }
      }
  } else {
#pragma unroll
    for (int mi = 0; mi < 4; ++mi)
#pragma unroll
      for (int ni = 0; ni < 4; ++ni) {
        int col = bn + wn + ni * 16 + r;
        float bv = bf2f(rb1[(size_t)e * FF + col]);
#pragma unroll
        for (int rr = 0; rr < 4; ++rr) {
          int slot = bm + wm + mi * 16 + q * 4 + rr;
          float v = acc[mi][ni][rr] + bv;
          Hrt[(size_t)(ho + slot) * FF + col] = f2bf(fast_gelu(v));
        }
      }
  }
}

// FFN2 (shared planes + routed compact) in ONE dispatch. grid (4, 32, 10).
// Pipelined core + XCD remap kept (round 8: g2 improved, left top-5).
__global__ __launch_bounds__(256) void g2_fused(
    const u16* __restrict__ Hsh,
    const void* __restrict__ s2r, const u16* __restrict__ s2b,
    const u16* __restrict__ sb2, const u16* __restrict__ Hrt,
    const void* __restrict__ r2r, const u16* __restrict__ r2b,
    const u16* __restrict__ rb2,
    const unsigned* __restrict__ list, const int* __restrict__ meta,
    const int* __restrict__ flags, const float* __restrict__ cw,
    float* __restrict__ oacc, float* __restrict__ Ort) {
  const u16* s2p = flags[3] ? s2b : (const u16*)s2r;
  const u16* r2p = flags[5] ? r2b : (const u16*)r2r;

  // XCD remap: 4 x-sharers of an A-panel get ids == same (mod 8)
  int L  = blockIdx.x + 4 * (blockIdx.y + 32 * blockIdx.z);
  int xx = (L & 31) >> 3;                     // 0..3 (bn tile)
  int pp = ((L >> 5) << 3) | (L & 7);         // panel 0..319
  int z  = pp >> 5;                           // 0..9
  int bm = (pp & 31) * BM;
  int bn = xx * BN;

  int tid = threadIdx.x, lane = tid & 63, wave = tid >> 6;
  int wm = (wave >> 1) * 64, wn = (wave & 1) * 64;
  int r = lane & 15, q = lane >> 4;
  const int K = FF;

  int rsub = tid >> 3;
  int us = (tid & 7) ^ (rsub & 7);

  __shared__ u16 As[2 * TILEU];   // 32KB (2-deep dbuf)
  __shared__ u16 Bs[2 * TILEU];   // 32KB

  const u16 *gA[4], *gB[4];
  int e = 0, ho = 0;
  if (z < NSH) {
    const int ldA = NSH * FF;
#pragma unroll
    for (int c = 0; c < 4; ++c) {
      gA[c] = Hsh + (size_t)(bm + c * 32 + rsub) * ldA + (size_t)z * FF +
              us * 8;
      gB[c] = s2p + (size_t)z * DD * FF + (size_t)(bn + c * 32 + rsub) * K +
              us * 8;
    }
  } else {
    e = z - NSH;
    if (bm >= meta[8 + e]) return;
    ho = meta[16 + e];
#pragma unroll
    for (int c = 0; c < 4; ++c) {
      gA[c] = Hrt + (size_t)(ho + bm + c * 32 + rsub) * K + us * 8;
      gB[c] = r2p + (size_t)e * DD * FF + (size_t)(bn + c * 32 + rsub) * K +
              us * 8;
    }
  }

  floatx4 acc[4][4];
  floatx4 zero = {0.f, 0.f, 0.f, 0.f};
#pragma unroll
  for (int i = 0; i < 4; ++i)
#pragma unroll
    for (int j = 0; j < 4; ++j) acc[i][j] = zero;

  core128pipe(gA[0], gA[1], gA[2], gA[3], gB[0], gB[1], gB[2], gB[3],
              K, As, Bs, acc, wave, wm, wn, r, q);

  if (z < NSH) {
    float* op = oacc + (size_t)z * T_TOK * DD;
#pragma unroll
    for (int mi = 0; mi < 4; ++mi)
#pragma unroll
      for (int ni = 0; ni < 4; ++ni) {
        int col = bn + wn + ni * 16 + r;
        float bv = bf2f(sb2[(size_t)z * DD + col]);
#pragma unroll
        for (int rr = 0; rr < 4; ++rr) {
          int row = bm + wm + mi * 16 + q * 4 + rr;
          op[(size_t)row * DD + col] = acc[mi][ni][rr] + bv;
        }
      }
  } else {
#pragma unroll
    for (int mi = 0; mi < 4; ++mi)
#pragma unroll
      for (int rr = 0; rr < 4; ++rr) {
        int slot = bm + wm + mi * 16 + q * 4 + rr;
        unsigned raw = list[(size_t)e * CAP + slot];
        if (raw & PADF) continue;
        float s = cw[raw * EE + e];
#pragma unroll
        for (int ni = 0; ni < 4; ++ni) {
          int col = bn + wn + ni * 16 + r;
          float v = acc[mi][ni][rr] + bf2f(rb2[(size_t)e * DD + col]);
          Ort[(size_t)(ho + slot) * DD + col] = s * v;
        }
      }
  }
}

// final: out[t] = oacc0[t] + oacc1[t] + Ort[g0(t)] + Ort[g1(t)]
typedef struct { u16 a, b, c, d; } u16x4;
__global__ __launch_bounds__(256) void combine_out(
    const float* __restrict__ oacc, const float* __restrict__ Ort,
    const int4* __restrict__ srec, const int* __restrict__ meta,
    void* __restrict__ out, const int* __restrict__ flags) {
  int t  = blockIdx.x * 2 + (threadIdx.x >> 7);
  int c4 = (threadIdx.x & 127) * 4;
  int4 sr = srec[t];
  int g0 = meta[16 + sr.x] + sr.y;
  int g1 = meta[16 + sr.z] + sr.w;
  float4 a = *(const float4*)(oacc + (size_t)t * DD + c4);
  float4 b = *(const float4*)(oacc + (size_t)(T_TOK + t) * DD + c4);
  float4 u = *(const float4*)(Ort + (size_t)g0 * DD + c4);
  float4 v = *(const float4*)(Ort + (size_t)g1 * DD + c4);
  float o0 = a.x + b.x + u.x + v.x;
  float o1 = a.y + b.y + u.y + v.y;
  float o2 = a.z + b.z + u.z + v.z;
  float o3 = a.w + b.w + u.w + v.w;
  size_t idx = (size_t)t * DD + c4;
  if (flags[6]) {
    *(float4*)((float*)out + idx) = make_float4(o0, o1, o2, o3);
  } else {
    u16x4 h = {f2bf(o0), f2bf(o1), f2bf(o2), f2bf(o3)};
    *(u16x4*)((u16*)out + idx) = h;
  }
}

// ---------------- fallback-path kernels (dense, unconverted) ----------------
__device__ __forceinline__ void gemm_core(const void* A, size_t aoff, int fA,
                                          const void* B, size_t boff, int fB,
                                          int K, u16* As, u16* Bs,
                                          floatx4 acc[4][4]) {
  int tid  = threadIdx.x;
  int lane = tid & 63, wave = tid >> 6;
  int wm = (wave >> 1) * 64, wn = (wave & 1) * 64;
  int r = lane & 15, q = lane >> 4;
  int srow = tid >> 2;
  int sc8  = (tid & 3) * 8;
  size_t abase = aoff + (size_t)srow * K + sc8;
  size_t bbase = boff + (size_t)srow * K + sc8;
  const size_t half = (size_t)64 * K;

  for (int k0 = 0; k0 < K; k0 += BK) {
    bf16x8 av0 = load8(A, abase + k0, fA);
    bf16x8 av1 = load8(A, abase + half + k0, fA);
    bf16x8 bv0 = load8(B, bbase + k0, fB);
    bf16x8 bv1 = load8(B, bbase + half + k0, fB);
    __syncthreads();
    *(bf16x8*)(As + srow * LDK + sc8)        = av0;
    *(bf16x8*)(As + (srow + 64) * LDK + sc8) = av1;
    *(bf16x8*)(Bs + srow * LDK + sc8)        = bv0;
    *(bf16x8*)(Bs + (srow + 64) * LDK + sc8) = bv1;
    __syncthreads();

    bf16x8 af[4], bfr[4];
#pragma unroll
    for (int mi = 0; mi < 4; ++mi)
      af[mi] = *(const bf16x8*)(As + (wm + mi * 16 + r) * LDK + q * 8);
#pragma unroll
    for (int ni = 0; ni < 4; ++ni)
      bfr[ni] = *(const bf16x8*)(Bs + (wn + ni * 16 + r) * LDK + q * 8);
#pragma unroll
    for (int mi = 0; mi < 4; ++mi)
#pragma unroll
      for (int ni = 0; ni < 4; ++ni)
        acc[mi][ni] = __builtin_amdgcn_mfma_f32_16x16x32_bf16(
            af[mi], bfr[ni], acc[mi][ni], 0, 0, 0);
  }
}

__global__ __launch_bounds__(256) void gemm1_gelu(
    const void* __restrict__ A, size_t aoff, const void* __restrict__ B,
    size_t boff, const u16* __restrict__ bias, size_t bioff,
    u16* __restrict__ H, const int* __restrict__ flags, int iA, int iB,
    int N, int K) {
  __shared__ u16 As[BM * LDK];
  __shared__ u16 Bs[BN * LDK];
  int fA = flags[iA], fB = flags[iB];
  floatx4 acc[4][4];
  floatx4 zero = {0.f, 0.f, 0.f, 0.f};
#pragma unroll
  for (int i = 0; i < 4; ++i)
#pragma unroll
    for (int j = 0; j < 4; ++j) acc[i][j] = zero;

  int bm = blockIdx.y * BM, bn = blockIdx.x * BN;
  gemm_core(A, aoff + (size_t)bm * K, fA, B, boff + (size_t)bn * K, fB, K,
            As, Bs, acc);

  int tid = threadIdx.x, wave = tid >> 6, lane = tid & 63;
  int wm = (wave >> 1) * 64, wn = (wave & 1) * 64;
  int r = lane & 15, q = lane >> 4;
#pragma unroll
  for (int mi = 0; mi < 4; ++mi)
#pragma unroll
    for (int ni = 0; ni < 4; ++ni) {
      int col = bn + wn + ni * 16 + r;
      float bv = bf2f(bias[bioff + col]);
#pragma unroll
      for (int rr = 0; rr < 4; ++rr) {
        int row = bm + wm + mi * 16 + q * 4 + rr;
        float v = acc[mi][ni][rr] + bv;
        H[(size_t)row * N + col] = f2bf(fast_gelu(v));
      }
    }
}

__global__ __launch_bounds__(256) void gemm2_acc(
    const u16* __restrict__ A, const void* __restrict__ B, size_t boff,
    const u16* __restrict__ bias, size_t bioff, float* __restrict__ outf,
    void* __restrict__ outb, const float* __restrict__ cw,
    const int* __restrict__ flags, int iB, int expert, int accum,
    int row0, int N, int K) {
  __shared__ u16 As[BT2 * LDK];
  __shared__ u16 Bs[BT2 * LDK];
  int fB = flags[iB], fO = flags[6];
  floatx4 acc[2][2];
  floatx4 zero = {0.f, 0.f, 0.f, 0.f};
#pragma unroll
  for (int i = 0; i < 2; ++i)
#pragma unroll
    for (int j = 0; j < 2; ++j) acc[i][j] = zero;

  int bm = blockIdx.y * BT2, bn = blockIdx.x * BT2;
  int tid  = threadIdx.x;
  int lane = tid & 63, wave = tid >> 6;
  int wm = (wave >> 1) * 32, wn = (wave & 1) * 32;
  int r = lane & 15, q = lane >> 4;
  int srow = tid >> 2;
  int sc8  = (tid & 3) * 8;
  size_t abase = (size_t)(bm + srow) * K + sc8;
  size_t bbase = boff + (size_t)(bn + srow) * K + sc8;

  for (int k0 = 0; k0 < K; k0 += BK) {
    bf16x8 av = *(const bf16x8*)(A + abase + k0);
    bf16x8 bv = load8(B, bbase + k0, fB);
    __syncthreads();
    *(bf16x8*)(As + srow * LDK + sc8) = av;
    *(bf16x8*)(Bs + srow * LDK + sc8) = bv;
    __syncthreads();

    bf16x8 af[2], bfr[2];
#pragma unroll
    for (int mi = 0; mi < 2; ++mi)
      af[mi] = *(const bf16x8*)(As + (wm + mi * 16 + r) * LDK + q * 8);
#pragma unroll
    for (int ni = 0; ni < 2; ++ni)
      bfr[ni] = *(const bf16x8*)(Bs + (wn + ni * 16 + r) * LDK + q * 8);
#pragma unroll
    for (int mi = 0; mi < 2; ++mi)
#pragma unroll
      for (int ni = 0; ni < 2; ++ni)
        acc[mi][ni] = __builtin_amdgcn_mfma_f32_16x16x32_bf16(
            af[mi], bfr[ni], acc[mi][ni], 0, 0, 0);
  }

#pragma unroll
  for (int mi = 0; mi < 2; ++mi)
#pragma unroll
    for (int rr = 0; rr < 4; ++rr) {
      int grow = row0 + bm + wm + mi * 16 + q * 4 + rr;
      float s = cw ? cw[grow * EE + expert] : 1.0f;
#pragma unroll
      for (int ni = 0; ni < 2; ++ni) {
        int col = bn + wn + ni * 16 + r;
        float v = acc[mi][ni][rr] + bf2f(bias[bioff + col]);
        size_t idx = (size_t)grow * N + col;
        if (outf) {
          float prev = accum ? outf[idx] : 0.0f;
          outf[idx] = prev + s * v;
        } else if (fO) {
          float* ob = (float*)outb;
          float prev = accum ? ob[idx] : 0.0f;
          ob[idx] = prev + s * v;
        } else {
          u16* ob = (u16*)outb;
          float prev = accum ? bf2f(ob[idx]) : 0.0f;
          ob[idx] = f2bf(prev + s * v);
        }
      }
    }
}

__global__ __launch_bounds__(256) void convert_out(
    const float* __restrict__ acc, void* __restrict__ out,
    const int* __restrict__ flags, int n) {
  int i = blockIdx.x * blockDim.x + threadIdx.x;
  if (i >= n) return;
  if (flags[6]) ((float*)out)[i] = acc[i];
  else ((u16*)out)[i] = f2bf(acc[i]);
}

extern "C" void kernel_launch(void* const* d_in, const int* in_sizes, int n_in,
                              void* d_out, int out_size, void* d_ws, size_t ws_size,
                              hipStream_t stream) {
  (void)in_sizes; (void)n_in; (void)out_size;
  const void* x   = d_in[0];
  const void* gw  = d_in[1];
  const u16*  gb  = (const u16*)d_in[2];
  const void* sw1 = d_in[3];
  const u16*  sb1 = (const u16*)d_in[4];
  const void* sw2 = d_in[5];
  const u16*  sb2 = (const u16*)d_in[6];
  const void* rw1 = d_in[7];
  const u16*  rb1 = (const u16*)d_in[8];
  const void* rw2 = d_in[9];
  const u16*  rb2 = (const u16*)d_in[10];

  const size_t NX   = (size_t)T_TOK * DD;
  const size_t NW1S = (size_t)NSH * FF * DD;
  const size_t NW1R = (size_t)EE * FF * DD;
  const size_t NW2S = (size_t)NSH * DD * FF;
  const size_t NW2R = (size_t)EE * DD * FF;

  // fast-path layout
  size_t off = 0;
  const size_t flO   = off; off += 256;
  const size_t cwO   = off; off += (size_t)T_TOK * EE * 4;
  const size_t tixO  = off; off += (size_t)T_TOK * 8;
  const size_t metaO = off; off += 256;
  const size_t listO = off; off += (size_t)EE * CAP * 4;
  const size_t srecO = off; off += (size_t)T_TOK * 16;
  const size_t accO  = off; off += (size_t)NSH * T_TOK * DD * 4;
  const size_t hshO  = off; off += (size_t)T_TOK * NSH * FF * 2;
  const size_t hrtO  = off; off += (size_t)NSLOT * FF * 2;
  const size_t ortO  = off; off += (size_t)NSLOT * DD * 4;
  const size_t xbO   = off; off += NX * 2;
  const size_t s1O   = off; off += NW1S * 2;
  const size_t r1O   = off; off += NW1R * 2;
  const size_t s2O   = off; off += NW2S * 2;
  const size_t r2O   = off; off += NW2R * 2;
  const int fast = (off <= ws_size) ? 1 : 0;

  char* ws = (char*)d_ws;
  int*   flags = (int*)(ws + flO);
  float* cw    = (float*)(ws + cwO);
  dim3 blk(256);

  if (fast) {
    int2*     tix  = (int2*)(ws + tixO);
    int*      meta = (int*)(ws + metaO);
    unsigned* list = (unsigned*)(ws + listO);
    int4*     srec = (int4*)(ws + srecO);
    float*    oacc = (float*)(ws + accO);
    u16*      Hsh  = (u16*)(ws + hshO);
    u16*      Hrt  = (u16*)(ws + hrtO);
    float*    Ort  = (float*)(ws + ortO);
    u16*      xb   = (u16*)(ws + xbO);
    u16*      s1b  = (u16*)(ws + s1O);
    u16*      r1b  = (u16*)(ws + r1O);
    u16*      s2b  = (u16*)(ws + s2O);
    u16*      r2b  = (u16*)(ws + r2O);

    detect_kernel<<<1, 256, 0, stream>>>(x, gw, sw1, sw2, rw1, rw2, flags,
                                         meta);
    conv_all<<<U8_C4 / 256, 256, 0, stream>>>(x, sw1, rw1, sw2, rw2, xb, s1b,
                                              r1b, s2b, r2b, flags);
    router_v<<<T_TOK / 4, 256, 0, stream>>>(x, gw, gb, flags, cw, tix);
    build_pad<<<1, 1024, 0, stream>>>(tix, meta, list, srec);

    // FFN1: shared (z<2) + routed gather (z>=2), one dispatch
    dim3 gf1(16, T_TOK / BM, 2 + EE);            // 16 x 32 x 10
    g1_fused<<<gf1, blk, 0, stream>>>(x, xb, sw1, s1b, sb1, rw1, r1b, rb1,
                                      list, meta, flags, Hsh, Hrt);
    // FFN2: shared planes (z<NSH) + routed compact (z>=NSH), one dispatch
    dim3 gf2(DD / BN, CAP / BM, NSH + EE);       // 4 x 32 x 10
    g2_fused<<<gf2, blk, 0, stream>>>(Hsh, sw2, s2b, sb2, Hrt, rw2, r2b, rb2,
                                      list, meta, flags, cw, oacc, Ort);
    combine_out<<<T_TOK / 2, 256, 0, stream>>>(oacc, Ort, srec, meta, d_out,
                                               flags);
    return;
  }

  // -------- fallback: dense all-FFN path (no conversion), ws-adaptive --------
  detect_kernel<<<1, 256, 0, stream>>>(x, gw, sw1, sw2, rw1, rw2, flags,
                                       nullptr);
  const size_t flB = 256, cwB = (size_t)T_TOK * EE * 4, tixB = (size_t)T_TOK * 8;
  const size_t accB = (size_t)T_TOK * DD * 4;
  static const int tcs[4] = {4096, 2048, 1024, 512};
  int TC = 0, use_f32 = 1;
  for (int i = 0; i < 4; ++i)
    if (flB + cwB + tixB + accB + (size_t)tcs[i] * FF * 2 <= ws_size) { TC = tcs[i]; break; }
  if (!TC) {
    use_f32 = 0;
    for (int i = 0; i < 4; ++i)
      if (flB + cwB + tixB + (size_t)tcs[i] * FF * 2 <= ws_size) { TC = tcs[i]; break; }
  }
  if (!TC) { TC = 512; use_f32 = 0; }

  int2*  tix     = (int2*)(ws + flB + cwB);
  float* out_acc = use_f32 ? (float*)(ws + flB + cwB + tixB) : nullptr;
  u16*   H       = (u16*)(ws + flB + cwB + tixB + (use_f32 ? accB : 0));

  router_v<<<T_TOK / 4, 256, 0, stream>>>(x, gw, gb, flags, cw, tix);
  dim3 g1(FF / BN, TC / BM);
  dim3 g2(DD / BT2, TC / BT2);
  const int nchunk = T_TOK / TC;
  for (int f = 0; f < NSH + EE; ++f) {
    const void *w1, *w2; const u16 *b1, *b2; const float* cwp;
    int expert, i1, i2v; size_t w1off, w2off, b1off, b2off;
    if (f < NSH) {
      w1 = sw1; w2 = sw2; b1 = sb1; b2 = sb2;
      w1off = (size_t)f * FF * DD; w2off = (size_t)f * DD * FF;
      b1off = (size_t)f * FF; b2off = (size_t)f * DD;
      cwp = nullptr; expert = 0; i1 = 2; i2v = 3;
    } else {
      int e = f - NSH;
      w1 = rw1; w2 = rw2; b1 = rb1; b2 = rb2;
      w1off = (size_t)e * FF * DD; w2off = (size_t)e * DD * FF;
      b1off = (size_t)e * FF; b2off = (size_t)e * DD;
      cwp = cw; expert = e; i1 = 4; i2v = 5;
    }
    int accum = (f > 0) ? 1 : 0;
    for (int c = 0; c < nchunk; ++c) {
      size_t t0 = (size_t)c * TC;
      gemm1_gelu<<<g1, blk, 0, stream>>>(x, t0 * DD, w1, w1off, b1, b1off, H,
                                         flags, 0, i1, FF, DD);
      gemm2_acc<<<g2, blk, 0, stream>>>(H, w2, w2off, b2, b2off, out_acc,
                                        d_out, cwp, flags, i2v, expert, accum,
                                        (int)t0, DD, FF);
    }
  }
  if (use_f32)
    convert_out<<<(T_TOK * DD) / 256, 256, 0, stream>>>(out_acc, d_out, flags,
                                                        T_TOK * DD);
}

// Round 10
// 335.954 us; speedup vs baseline: 1.1176x; 1.0626x over previous
//
#include <hip/hip_runtime.h>
#include <math.h>

typedef unsigned short u16;
typedef __attribute__((ext_vector_type(8))) __bf16 bf16x8;
typedef __attribute__((ext_vector_type(4))) float floatx4;

#define T_TOK 4096
#define DD    512
#define FF    2048
#define EE    8
#define NSH   2

#define BM 128
#define BN 128
#define BK 32
#define LDK 40   // fallback kernels: padded LDS row stride
#define BT2 64   // fallback gemm2 N-tile
#define CAP 4096
#define PADF 0x80000000u
#define NSLOT (2 * T_TOK + EE * BM)   // 9216 compact rows max

__device__ __forceinline__ float bf2f(u16 v) {
  union { unsigned int u; float f; } c; c.u = ((unsigned int)v) << 16; return c.f;
}
__device__ __forceinline__ u16 f2bf(float f) {
  union { float ff; unsigned int u; } c; c.ff = f;
  unsigned int u = c.u;
  u += 0x7fffu + ((u >> 16) & 1u);   // RNE
  return (u16)(u >> 16);
}
__device__ __forceinline__ float decode(const void* p, size_t idx, int f) {
  return f ? ((const float*)p)[idx] : bf2f(((const u16*)p)[idx]);
}
__device__ __forceinline__ bf16x8 load8(const void* base, size_t idx, int f) {
  if (f) {
    const float* p = (const float*)base + idx;
    float4 a = *(const float4*)p;
    float4 b = *(const float4*)(p + 4);
    union { bf16x8 v; u16 s[8]; } u;
    u.s[0] = f2bf(a.x); u.s[1] = f2bf(a.y); u.s[2] = f2bf(a.z); u.s[3] = f2bf(a.w);
    u.s[4] = f2bf(b.x); u.s[5] = f2bf(b.y); u.s[6] = f2bf(b.z); u.s[7] = f2bf(b.w);
    return u.v;
  }
  return *(const bf16x8*)((const u16*)base + idx);
}
// full-precision 8-element load (fp32 stays fp32; bf16 widened) -- router path.
// Top-k selection is discontinuous in the logits: router must NOT quantize.
__device__ __forceinline__ void loadf8(const void* p, size_t idx, int f,
                                       float* o) {
  if (f) {
    const float* q = (const float*)p + idx;
    float4 a = *(const float4*)q;
    float4 b = *(const float4*)(q + 4);
    o[0] = a.x; o[1] = a.y; o[2] = a.z; o[3] = a.w;
    o[4] = b.x; o[5] = b.y; o[6] = b.z; o[7] = b.w;
  } else {
    union { bf16x8 v; u16 s[8]; } u;
    u.v = *(const bf16x8*)((const u16*)p + idx);
#pragma unroll
    for (int j = 0; j < 8; ++j) o[j] = bf2f(u.s[j]);
  }
}

// fast exact-GELU: erf via Abramowitz-Stegun 7.1.26 (|err| 1.5e-7), native rcp/exp
__device__ __forceinline__ float fast_gelu(float v) {
  float x  = v * 0.70710678118654752f;
  float ax = fabsf(x);
  float t  = __builtin_amdgcn_rcpf(fmaf(0.3275911f, ax, 1.0f));
  float p  = fmaf(t, 1.061405429f, -1.453152027f);
  p = fmaf(t, p, 1.421413741f);
  p = fmaf(t, p, -0.284496736f);
  p = fmaf(t, p, 0.254829592f);
  p = p * t;
  float e  = __expf(-ax * ax);
  float er = fmaf(-p, e, 1.0f);          // erf(|x|)
  er = (x < 0.f) ? -er : er;
  return 0.5f * v * (1.0f + er);
}

// async 16B global->LDS. LDS dest is wave-uniform base; HW writes base+lane*16.
__device__ __forceinline__ void gll16(const void* g, void* l) {
  __builtin_amdgcn_global_load_lds(
      (const __attribute__((address_space(1))) void*)g,
      (__attribute__((address_space(3))) void*)l, 16, 0, 0);
}

#define BK2 64
#define TILEU (BM * BK2)   // 8192 u16 = 16KB per buffer

// stage one 128x64 k-slab (8 global_load_lds = 8 vmcnt increments per wave)
__device__ __forceinline__ void stage8(
    const u16* gA0, const u16* gA1, const u16* gA2, const u16* gA3,
    const u16* gB0, const u16* gB1, const u16* gB2, const u16* gB3,
    u16* Asb, u16* Bsb, int wave, int k0) {
  gll16(gA0 + k0, Asb + wave * 512);
  gll16(gA1 + k0, Asb + 2048 + wave * 512);
  gll16(gA2 + k0, Asb + 4096 + wave * 512);
  gll16(gA3 + k0, Asb + 6144 + wave * 512);
  gll16(gB0 + k0, Bsb + wave * 512);
  gll16(gB1 + k0, Bsb + 2048 + wave * 512);
  gll16(gB2 + k0, Bsb + 4096 + wave * 512);
  gll16(gB3 + k0, Bsb + 6144 + wave * 512);
}

// ===== single-buffer swizzled core (g1's best: round 6, <=82.7us).
// 32KB LDS -> 5 blocks/CU; inter-wave TLP does the latency hiding.
// Swizzle: linear LDS dest, inverse-swz global source, same swz on ds_read
// (bank-conflict 4.29M -> 0, round 6).
__device__ __forceinline__ void core128swz(
    const u16* gA0, const u16* gA1, const u16* gA2, const u16* gA3,
    const u16* gB0, const u16* gB1, const u16* gB2, const u16* gB3,
    int K, u16* As, u16* Bs, floatx4 acc[4][4],
    int wave, int wm, int wn, int r, int q) {
  const int rs = r & 7;                 // fragment-row low bits (R&7 == r&7)
  for (int k0 = 0; k0 < K; k0 += BK2) {
    __syncthreads();
    stage8(gA0, gA1, gA2, gA3, gB0, gB1, gB2, gB3, As, Bs, wave, k0);
    __syncthreads();   // compiler drains vmcnt before barrier
#pragma unroll
    for (int s = 0; s < 2; ++s) {       // two k=32 slabs per 64-elem row
      bf16x8 af[4], bfr[4];
#pragma unroll
      for (int mi = 0; mi < 4; ++mi) {
        int R = wm + mi * 16 + r;
        int u = (s * 4 + q) ^ rs;
        af[mi] = *(const bf16x8*)(As + R * 64 + u * 8);
      }
#pragma unroll
      for (int ni = 0; ni < 4; ++ni) {
        int R = wn + ni * 16 + r;
        int u = (s * 4 + q) ^ rs;
        bfr[ni] = *(const bf16x8*)(Bs + R * 64 + u * 8);
      }
#pragma unroll
      for (int mi = 0; mi < 4; ++mi)
#pragma unroll
        for (int ni = 0; ni < 4; ++ni)
          acc[mi][ni] = __builtin_amdgcn_mfma_f32_16x16x32_bf16(
              af[mi], bfr[ni], acc[mi][ni], 0, 0, 0);
    }
  }
}

// ===== T3+T4 pipelined core (g2's best: round 8 -- K=2048's 32 iters
// amortize the prologue; counted vmcnt(8) keeps next tile's loads in
// flight ACROSS the barrier). K-dependent: REGRESSED g1 (K=512, 8 iters,
// 64KB LDS -> 2 blocks/CU kills TLP; round 8: 83.8 -> 116.8us).
__device__ __forceinline__ void core128pipe(
    const u16* gA0, const u16* gA1, const u16* gA2, const u16* gA3,
    const u16* gB0, const u16* gB1, const u16* gB2, const u16* gB3,
    int K, u16* As, u16* Bs, floatx4 acc[4][4],
    int wave, int wm, int wn, int r, int q) {
  const int rs = r & 7;                 // fragment-row low bits (R&7 == r&7)
  stage8(gA0, gA1, gA2, gA3, gB0, gB1, gB2, gB3, As, Bs, wave, 0);
  int cur = 0;
  for (int k0 = 0; k0 < K; k0 += BK2) {
    const u16* Ac = As + cur * TILEU;
    const u16* Bc = Bs + cur * TILEU;
    if (k0 + BK2 < K) {
      stage8(gA0, gA1, gA2, gA3, gB0, gB1, gB2, gB3,
             As + (cur ^ 1) * TILEU, Bs + (cur ^ 1) * TILEU, wave, k0 + BK2);
      // wait for THIS tile's 8 loads; leave next tile's 8 in flight
      asm volatile("s_waitcnt vmcnt(8)" ::: "memory");
    } else {
      asm volatile("s_waitcnt vmcnt(0)" ::: "memory");
    }
    __builtin_amdgcn_sched_barrier(0);
    __builtin_amdgcn_s_barrier();       // all waves: cur tile landed
    __builtin_amdgcn_sched_barrier(0);
#pragma unroll
    for (int s = 0; s < 2; ++s) {       // two k=32 slabs per 64-elem row
      bf16x8 af[4], bfr[4];
#pragma unroll
      for (int mi = 0; mi < 4; ++mi) {
        int R = wm + mi * 16 + r;
        int u = (s * 4 + q) ^ rs;
        af[mi] = *(const bf16x8*)(Ac + R * 64 + u * 8);
      }
#pragma unroll
      for (int ni = 0; ni < 4; ++ni) {
        int R = wn + ni * 16 + r;
        int u = (s * 4 + q) ^ rs;
        bfr[ni] = *(const bf16x8*)(Bc + R * 64 + u * 8);
      }
#pragma unroll
      for (int mi = 0; mi < 4; ++mi)
#pragma unroll
        for (int ni = 0; ni < 4; ++ni)
          acc[mi][ni] = __builtin_amdgcn_mfma_f32_16x16x32_bf16(
              af[mi], bfr[ni], acc[mi][ni], 0, 0, 0);
    }
    __builtin_amdgcn_sched_barrier(0);
    __builtin_amdgcn_s_barrier();       // all waves done reading cur
    cur ^= 1;
  }
}

// Probe: classify tensors fp32(1)/bf16(0) -- 6 blocks, one tensor each
// (round-7's 1-block version serialized 6 scans + 12 barriers on one CU).
// Block 0 also writes flags[6..7] and zeroes meta.
__global__ __launch_bounds__(256) void detect_kernel(
    const void* x, const void* gw, const void* sw1, const void* sw2,
    const void* rw1, const void* rw2, int* flags, int* meta) {
  __shared__ int cnt;
  const void* ptrs[6] = {x, gw, sw1, sw2, rw1, rw2};
  int b = blockIdx.x;
  if (threadIdx.x == 0) cnt = 0;
  __syncthreads();
  const u16* p = (const u16*)ptrs[b];
  int local = 0;
  for (int i = threadIdx.x; i < 4096; i += 256) {
    unsigned ef = (p[i] >> 7) & 0xFFu;
    if (ef >= 0xE0u) ++local;
  }
  if (local) atomicAdd(&cnt, local);
  __syncthreads();
  if (threadIdx.x == 0) {
    int f = (cnt >= 16) ? 1 : 0;
    flags[b] = f;
    if (b == 0) {
      flags[6] = f;   // output dtype follows x
      flags[7] = 0;   // ws bf16 buffers
    }
  }
  if (b == 0 && meta && threadIdx.x < 24) meta[threadIdx.x] = 0;
}

// merged conversion over x + 4 weight tensors; per-segment flag early-exit
// (bf16 inputs are consumed raw downstream -- skip-copy).
#define U8_X  (T_TOK * DD / 8)
#define U8_S1 (NSH * FF * DD / 8)
#define U8_R1 (EE * FF * DD / 8)
#define U8_S2 (NSH * DD * FF / 8)
#define U8_R2 (EE * DD * FF / 8)
#define U8_C0 (U8_X)
#define U8_C1 (U8_C0 + U8_S1)
#define U8_C2 (U8_C1 + U8_R1)
#define U8_C3 (U8_C2 + U8_S2)
#define U8_C4 (U8_C3 + U8_R2)
__global__ __launch_bounds__(256) void conv_all(
    const void* __restrict__ x, const void* __restrict__ sw1,
    const void* __restrict__ rw1, const void* __restrict__ sw2,
    const void* __restrict__ rw2, u16* __restrict__ xb,
    u16* __restrict__ s1b, u16* __restrict__ r1b, u16* __restrict__ s2b,
    u16* __restrict__ r2b, const int* __restrict__ flags) {
  size_t u = (size_t)blockIdx.x * 256 + threadIdx.x;
  const void* src; u16* dst; int fi; size_t base;
  if (u < U8_C0)      { src = x;   dst = xb;  fi = 0; base = 0; }
  else if (u < U8_C1) { src = sw1; dst = s1b; fi = 2; base = U8_C0; }
  else if (u < U8_C2) { src = rw1; dst = r1b; fi = 4; base = U8_C1; }
  else if (u < U8_C3) { src = sw2; dst = s2b; fi = 3; base = U8_C2; }
  else                { src = rw2; dst = r2b; fi = 5; base = U8_C3; }
  int f = flags[fi];
  if (!f) return;               // bf16: raw tensor used directly downstream
  size_t i = (u - base) * 8;
  *(bf16x8*)(dst + i) = load8(src, i, f);
}

// Router: FULL-precision logits (raw x, raw gw), vectorized 16B loads.
__global__ __launch_bounds__(256) void router_v(
    const void* __restrict__ x, const void* __restrict__ gw,
    const u16* __restrict__ gb, const int* __restrict__ flags,
    float* __restrict__ cw, int2* __restrict__ tix) {
  int wave = threadIdx.x >> 6, lane = threadIdx.x & 63;
  int t = blockIdx.x * 4 + wave;
  int fx = flags[0], fg = flags[1];
  float xf[8];
  loadf8(x, (size_t)t * DD + lane * 8, fx, xf);
  float acc[EE];
#pragma unroll
  for (int e = 0; e < EE; ++e) {
    float gf[8];
    loadf8(gw, (size_t)e * DD + lane * 8, fg, gf);
    float a = 0.f;
#pragma unroll
    for (int j = 0; j < 8; ++j) a = fmaf(xf[j], gf[j], a);
    acc[e] = a;
  }
#pragma unroll
  for (int e = 0; e < EE; ++e) {
    float v = acc[e];
#pragma unroll
    for (int off = 32; off > 0; off >>= 1) v += __shfl_xor(v, off, 64);
    acc[e] = v;
  }
  if (lane == 0) {
    float m = -1e30f;
#pragma unroll
    for (int e = 0; e < EE; ++e) {
      acc[e] += bf2f(gb[e]);   // all-zero: dtype-agnostic
      m = fmaxf(m, acc[e]);
    }
    float p[EE], s = 0.f;
#pragma unroll
    for (int e = 0; e < EE; ++e) { p[e] = expf(acc[e] - m); s += p[e]; }
    int i1 = 0;
#pragma unroll
    for (int e = 1; e < EE; ++e) if (p[e] > p[i1]) i1 = e;
    int i2 = (i1 == 0) ? 1 : 0;
#pragma unroll
    for (int e = 0; e < EE; ++e)
      if (e != i1 && p[e] > p[i2]) i2 = e;
    float inv = 1.0f / s;
#pragma unroll
    for (int e = 0; e < EE; ++e)
      cw[t * EE + e] = (e == i1 || e == i2) ? p[e] * inv : 0.0f;
    tix[t] = make_int2(i1, i2);
  }
}

// build lists: 16 blocks, all-lane atomics (TA/L2 combines same-address
// lanes); round-5-verified structure. Single-block fusion (round 7) cost
// ~25us of serialization for a 3us launch saving -- reverted.
__global__ __launch_bounds__(256) void build_lists(
    const int2* __restrict__ tix, int* __restrict__ meta,
    unsigned* __restrict__ list, int4* __restrict__ srec) {
  int t = blockIdx.x * 256 + threadIdx.x;
  if (t >= T_TOK) return;
  int2 ii = tix[t];
  int p0 = atomicAdd(&meta[ii.x], 1);
  list[(size_t)ii.x * CAP + p0] = (unsigned)t;
  int p1 = atomicAdd(&meta[ii.y], 1);
  list[(size_t)ii.y * CAP + p1] = (unsigned)t;
  srec[t] = make_int4(ii.x, p0, ii.y, p1);
}
// meta: [0..7]=cnt, [8..15]=pc (padded), [16..23]=row prefix
__global__ __launch_bounds__(256) void pad_lists(int* meta, unsigned* list) {
  if (threadIdx.x == 0) {
    int off = 0;
    for (int e = 0; e < EE; ++e) {
      int c = meta[e];
      int pc = (c + BM - 1) & ~(BM - 1);
      meta[8 + e] = pc;
      meta[16 + e] = off;
      off += pc;
    }
  }
  __syncthreads();
#pragma unroll
  for (int e = 0; e < EE; ++e) {
    int c = meta[e], pc = meta[8 + e];
    int i = c + threadIdx.x;
    if (i < pc) list[(size_t)e * CAP + i] = PADF;
  }
}

// ========== fast path GEMMs: per-kernel best cores (round-8 A/B) ==========

// FFN1 (shared + routed gather) in ONE dispatch. grid (16, 32, 10).
// Single-buffer core (best measured: round 6); plain block mapping.
__global__ __launch_bounds__(256) void g1_fused(
    const void* __restrict__ xr, const u16* __restrict__ xb,
    const void* __restrict__ s1r, const u16* __restrict__ s1b,
    const u16* __restrict__ sb1,
    const void* __restrict__ r1r, const u16* __restrict__ r1b,
    const u16* __restrict__ rb1, const unsigned* __restrict__ list,
    const int* __restrict__ meta, const int* __restrict__ flags,
    u16* __restrict__ Hsh, u16* __restrict__ Hrt) {
  // skip-copy: raw tensor when already bf16
  const u16* xp  = flags[0] ? xb  : (const u16*)xr;
  const u16* s1p = flags[2] ? s1b : (const u16*)s1r;
  const u16* r1p = flags[4] ? r1b : (const u16*)r1r;

  int z  = blockIdx.z;
  int bm = blockIdx.y * BM;
  int xx = blockIdx.x;

  int tid = threadIdx.x, lane = tid & 63, wave = tid >> 6;
  int wm = (wave >> 1) * 64, wn = (wave & 1) * 64;
  int r = lane & 15, q = lane >> 4;
  const int K = DD;

  // staging geometry: idx = c*256+tid; row = c*32 + (tid>>3); unit = tid&7
  int rsub = tid >> 3;
  int us = (tid & 7) ^ (rsub & 7);   // pre-swizzled source unit

  __shared__ u16 As[TILEU];   // 16KB single buffer (5 blocks/CU)
  __shared__ u16 Bs[TILEU];   // 16KB

  const u16 *gA[4], *gB[4];
  int e = 0, ho = 0, bn;
  if (z < 2) {
    bn = (z * 16 + xx) * BN;
#pragma unroll
    for (int c = 0; c < 4; ++c) {
      gA[c] = xp + (size_t)(bm + c * 32 + rsub) * K + us * 8;
      gB[c] = s1p + (size_t)(bn + c * 32 + rsub) * K + us * 8;
    }
  } else {
    e = z - 2;
    if (bm >= meta[8 + e]) return;
    ho = meta[16 + e];
    bn = xx * BN;
#pragma unroll
    for (int c = 0; c < 4; ++c) {
      unsigned tk = list[(size_t)e * CAP + bm + c * 32 + rsub] & 0x7fffffffu;
      gA[c] = xp + (size_t)tk * K + us * 8;
      gB[c] = r1p + (size_t)e * FF * DD + (size_t)(bn + c * 32 + rsub) * K +
              us * 8;
    }
  }

  floatx4 acc[4][4];
  floatx4 zero = {0.f, 0.f, 0.f, 0.f};
#pragma unroll
  for (int i = 0; i < 4; ++i)
#pragma unroll
    for (int j = 0; j < 4; ++j) acc[i][j] = zero;

  core128swz(gA[0], gA[1], gA[2], gA[3], gB[0], gB[1], gB[2], gB[3],
             K, As, Bs, acc, wave, wm, wn, r, q);

  if (z < 2) {
#pragma unroll
    for (int mi = 0; mi < 4; ++mi)
#pragma unroll
      for (int ni = 0; ni < 4; ++ni) {
        int col = bn + wn + ni * 16 + r;
        float bv = bf2f(sb1[col]);
#pragma unroll
        for (int rr = 0; rr < 4; ++rr) {
          int row = bm + wm + mi * 16 + q * 4 + rr;
          float v = acc[mi][ni][rr] + bv;
          Hsh[(size_t)row * (NSH * FF) + col] = f2bf(fast_gelu(v));
        }
      }
  } else {
#pragma unroll
    for (int mi = 0; mi < 4; ++mi)
#pragma unroll
      for (int ni = 0; ni < 4; ++ni) {
        int col = bn + wn + ni * 16 + r;
        float bv = bf2f(rb1[(size_t)e * FF + col]);
#pragma unroll
        for (int rr = 0; rr < 4; ++rr) {
          int slot = bm + wm + mi * 16 + q * 4 + rr;
          float v = acc[mi][ni][rr] + bv;
          Hrt[(size_t)(ho + slot) * FF + col] = f2bf(fast_gelu(v));
        }
      }
  }
}

// FFN2 (shared planes + routed compact) in ONE dispatch. grid (4, 32, 10).
// Pipelined core + XCD remap kept (round 8: g2 improved, left top-5).
__global__ __launch_bounds__(256) void g2_fused(
    const u16* __restrict__ Hsh,
    const void* __restrict__ s2r, const u16* __restrict__ s2b,
    const u16* __restrict__ sb2, const u16* __restrict__ Hrt,
    const void* __restrict__ r2r, const u16* __restrict__ r2b,
    const u16* __restrict__ rb2,
    const unsigned* __restrict__ list, const int* __restrict__ meta,
    const int* __restrict__ flags, const float* __restrict__ cw,
    float* __restrict__ oacc, float* __restrict__ Ort) {
  const u16* s2p = flags[3] ? s2b : (const u16*)s2r;
  const u16* r2p = flags[5] ? r2b : (const u16*)r2r;

  // XCD remap: 4 x-sharers of an A-panel get ids == same (mod 8)
  int L  = blockIdx.x + 4 * (blockIdx.y + 32 * blockIdx.z);
  int xx = (L & 31) >> 3;                     // 0..3 (bn tile)
  int pp = ((L >> 5) << 3) | (L & 7);         // panel 0..319
  int z  = pp >> 5;                           // 0..9
  int bm = (pp & 31) * BM;
  int bn = xx * BN;

  int tid = threadIdx.x, lane = tid & 63, wave = tid >> 6;
  int wm = (wave >> 1) * 64, wn = (wave & 1) * 64;
  int r = lane & 15, q = lane >> 4;
  const int K = FF;

  int rsub = tid >> 3;
  int us = (tid & 7) ^ (rsub & 7);

  __shared__ u16 As[2 * TILEU];   // 32KB (2-deep dbuf)
  __shared__ u16 Bs[2 * TILEU];   // 32KB

  const u16 *gA[4], *gB[4];
  int e = 0, ho = 0;
  if (z < NSH) {
    const int ldA = NSH * FF;
#pragma unroll
    for (int c = 0; c < 4; ++c) {
      gA[c] = Hsh + (size_t)(bm + c * 32 + rsub) * ldA + (size_t)z * FF +
              us * 8;
      gB[c] = s2p + (size_t)z * DD * FF + (size_t)(bn + c * 32 + rsub) * K +
              us * 8;
    }
  } else {
    e = z - NSH;
    if (bm >= meta[8 + e]) return;
    ho = meta[16 + e];
#pragma unroll
    for (int c = 0; c < 4; ++c) {
      gA[c] = Hrt + (size_t)(ho + bm + c * 32 + rsub) * K + us * 8;
      gB[c] = r2p + (size_t)e * DD * FF + (size_t)(bn + c * 32 + rsub) * K +
              us * 8;
    }
  }

  floatx4 acc[4][4];
  floatx4 zero = {0.f, 0.f, 0.f, 0.f};
#pragma unroll
  for (int i = 0; i < 4; ++i)
#pragma unroll
    for (int j = 0; j < 4; ++j) acc[i][j] = zero;

  core128pipe(gA[0], gA[1], gA[2], gA[3], gB[0], gB[1], gB[2], gB[3],
              K, As, Bs, acc, wave, wm, wn, r, q);

  if (z < NSH) {
    float* op = oacc + (size_t)z * T_TOK * DD;
#pragma unroll
    for (int mi = 0; mi < 4; ++mi)
#pragma unroll
      for (int ni = 0; ni < 4; ++ni) {
        int col = bn + wn + ni * 16 + r;
        float bv = bf2f(sb2[(size_t)z * DD + col]);
#pragma unroll
        for (int rr = 0; rr < 4; ++rr) {
          int row = bm + wm + mi * 16 + q * 4 + rr;
          op[(size_t)row * DD + col] = acc[mi][ni][rr] + bv;
        }
      }
  } else {
#pragma unroll
    for (int mi = 0; mi < 4; ++mi)
#pragma unroll
      for (int rr = 0; rr < 4; ++rr) {
        int slot = bm + wm + mi * 16 + q * 4 + rr;
        unsigned raw = list[(size_t)e * CAP + slot];
        if (raw & PADF) continue;
        float s = cw[raw * EE + e];
#pragma unroll
        for (int ni = 0; ni < 4; ++ni) {
          int col = bn + wn + ni * 16 + r;
          float v = acc[mi][ni][rr] + bf2f(rb2[(size_t)e * DD + col]);
          Ort[(size_t)(ho + slot) * DD + col] = s * v;
        }
      }
  }
}

// final: out[t] = oacc0[t] + oacc1[t] + Ort[g0(t)] + Ort[g1(t)]
typedef struct { u16 a, b, c, d; } u16x4;
__global__ __launch_bounds__(256) void combine_out(
    const float* __restrict__ oacc, const float* __restrict__ Ort,
    const int4* __restrict__ srec, const int* __restrict__ meta,
    void* __restrict__ out, const int* __restrict__ flags) {
  int t  = blockIdx.x * 2 + (threadIdx.x >> 7);
  int c4 = (threadIdx.x & 127) * 4;
  int4 sr = srec[t];
  int g0 = meta[16 + sr.x] + sr.y;
  int g1 = meta[16 + sr.z] + sr.w;
  float4 a = *(const float4*)(oacc + (size_t)t * DD + c4);
  float4 b = *(const float4*)(oacc + (size_t)(T_TOK + t) * DD + c4);
  float4 u = *(const float4*)(Ort + (size_t)g0 * DD + c4);
  float4 v = *(const float4*)(Ort + (size_t)g1 * DD + c4);
  float o0 = a.x + b.x + u.x + v.x;
  float o1 = a.y + b.y + u.y + v.y;
  float o2 = a.z + b.z + u.z + v.z;
  float o3 = a.w + b.w + u.w + v.w;
  size_t idx = (size_t)t * DD + c4;
  if (flags[6]) {
    *(float4*)((float*)out + idx) = make_float4(o0, o1, o2, o3);
  } else {
    u16x4 h = {f2bf(o0), f2bf(o1), f2bf(o2), f2bf(o3)};
    *(u16x4*)((u16*)out + idx) = h;
  }
}

// ---------------- fallback-path kernels (dense, unconverted) ----------------
__device__ __forceinline__ void gemm_core(const void* A, size_t aoff, int fA,
                                          const void* B, size_t boff, int fB,
                                          int K, u16* As, u16* Bs,
                                          floatx4 acc[4][4]) {
  int tid  = threadIdx.x;
  int lane = tid & 63, wave = tid >> 6;
  int wm = (wave >> 1) * 64, wn = (wave & 1) * 64;
  int r = lane & 15, q = lane >> 4;
  int srow = tid >> 2;
  int sc8  = (tid & 3) * 8;
  size_t abase = aoff + (size_t)srow * K + sc8;
  size_t bbase = boff + (size_t)srow * K + sc8;
  const size_t half = (size_t)64 * K;

  for (int k0 = 0; k0 < K; k0 += BK) {
    bf16x8 av0 = load8(A, abase + k0, fA);
    bf16x8 av1 = load8(A, abase + half + k0, fA);
    bf16x8 bv0 = load8(B, bbase + k0, fB);
    bf16x8 bv1 = load8(B, bbase + half + k0, fB);
    __syncthreads();
    *(bf16x8*)(As + srow * LDK + sc8)        = av0;
    *(bf16x8*)(As + (srow + 64) * LDK + sc8) = av1;
    *(bf16x8*)(Bs + srow * LDK + sc8)        = bv0;
    *(bf16x8*)(Bs + (srow + 64) * LDK + sc8) = bv1;
    __syncthreads();

    bf16x8 af[4], bfr[4];
#pragma unroll
    for (int mi = 0; mi < 4; ++mi)
      af[mi] = *(const bf16x8*)(As + (wm + mi * 16 + r) * LDK + q * 8);
#pragma unroll
    for (int ni = 0; ni < 4; ++ni)
      bfr[ni] = *(const bf16x8*)(Bs + (wn + ni * 16 + r) * LDK + q * 8);
#pragma unroll
    for (int mi = 0; mi < 4; ++mi)
#pragma unroll
      for (int ni = 0; ni < 4; ++ni)
        acc[mi][ni] = __builtin_amdgcn_mfma_f32_16x16x32_bf16(
            af[mi], bfr[ni], acc[mi][ni], 0, 0, 0);
  }
}

__global__ __launch_bounds__(256) void gemm1_gelu(
    const void* __restrict__ A, size_t aoff, const void* __restrict__ B,
    size_t boff, const u16* __restrict__ bias, size_t bioff,
    u16* __restrict__ H, const int* __restrict__ flags, int iA, int iB,
    int N, int K) {
  __shared__ u16 As[BM * LDK];
  __shared__ u16 Bs[BN * LDK];
  int fA = flags[iA], fB = flags[iB];
  floatx4 acc[4][4];
  floatx4 zero = {0.f, 0.f, 0.f, 0.f};
#pragma unroll
  for (int i = 0; i < 4; ++i)
#pragma unroll
    for (int j = 0; j < 4; ++j) acc[i][j] = zero;

  int bm = blockIdx.y * BM, bn = blockIdx.x * BN;
  gemm_core(A, aoff + (size_t)bm * K, fA, B, boff + (size_t)bn * K, fB, K,
            As, Bs, acc);

  int tid = threadIdx.x, wave = tid >> 6, lane = tid & 63;
  int wm = (wave >> 1) * 64, wn = (wave & 1) * 64;
  int r = lane & 15, q = lane >> 4;
#pragma unroll
  for (int mi = 0; mi < 4; ++mi)
#pragma unroll
    for (int ni = 0; ni < 4; ++ni) {
      int col = bn + wn + ni * 16 + r;
      float bv = bf2f(bias[bioff + col]);
#pragma unroll
      for (int rr = 0; rr < 4; ++rr) {
        int row = bm + wm + mi * 16 + q * 4 + rr;
        float v = acc[mi][ni][rr] + bv;
        H[(size_t)row * N + col] = f2bf(fast_gelu(v));
      }
    }
}

__global__ __launch_bounds__(256) void gemm2_acc(
    const u16* __restrict__ A, const void* __restrict__ B, size_t boff,
    const u16* __restrict__ bias, size_t bioff, float* __restrict__ outf,
    void* __restrict__ outb, const float* __restrict__ cw,
    const int* __restrict__ flags, int iB, int expert, int accum,
    int row0, int N, int K) {
  __shared__ u16 As[BT2 * LDK];
  __shared__ u16 Bs[BT2 * LDK];
  int fB = flags[iB], fO = flags[6];
  floatx4 acc[2][2];
  floatx4 zero = {0.f, 0.f, 0.f, 0.f};
#pragma unroll
  for (int i = 0; i < 2; ++i)
#pragma unroll
    for (int j = 0; j < 2; ++j) acc[i][j] = zero;

  int bm = blockIdx.y * BT2, bn = blockIdx.x * BT2;
  int tid  = threadIdx.x;
  int lane = tid & 63, wave = tid >> 6;
  int wm = (wave >> 1) * 32, wn = (wave & 1) * 32;
  int r = lane & 15, q = lane >> 4;
  int srow = tid >> 2;
  int sc8  = (tid & 3) * 8;
  size_t abase = (size_t)(bm + srow) * K + sc8;
  size_t bbase = boff + (size_t)(bn + srow) * K + sc8;

  for (int k0 = 0; k0 < K; k0 += BK) {
    bf16x8 av = *(const bf16x8*)(A + abase + k0);
    bf16x8 bv = load8(B, bbase + k0, fB);
    __syncthreads();
    *(bf16x8*)(As + srow * LDK + sc8) = av;
    *(bf16x8*)(Bs + srow * LDK + sc8) = bv;
    __syncthreads();

    bf16x8 af[2], bfr[2];
#pragma unroll
    for (int mi = 0; mi < 2; ++mi)
      af[mi] = *(const bf16x8*)(As + (wm + mi * 16 + r) * LDK + q * 8);
#pragma unroll
    for (int ni = 0; ni < 2; ++ni)
      bfr[ni] = *(const bf16x8*)(Bs + (wn + ni * 16 + r) * LDK + q * 8);
#pragma unroll
    for (int mi = 0; mi < 2; ++mi)
#pragma unroll
      for (int ni = 0; ni < 2; ++ni)
        acc[mi][ni] = __builtin_amdgcn_mfma_f32_16x16x32_bf16(
            af[mi], bfr[ni], acc[mi][ni], 0, 0, 0);
  }

#pragma unroll
  for (int mi = 0; mi < 2; ++mi)
#pragma unroll
    for (int rr = 0; rr < 4; ++rr) {
      int grow = row0 + bm + wm + mi * 16 + q * 4 + rr;
      float s = cw ? cw[grow * EE + expert] : 1.0f;
#pragma unroll
      for (int ni = 0; ni < 2; ++ni) {
        int col = bn + wn + ni * 16 + r;
        float v = acc[mi][ni][rr] + bf2f(bias[bioff + col]);
        size_t idx = (size_t)grow * N + col;
        if (outf) {
          float prev = accum ? outf[idx] : 0.0f;
          outf[idx] = prev + s * v;
        } else if (fO) {
          float* ob = (float*)outb;
          float prev = accum ? ob[idx] : 0.0f;
          ob[idx] = prev + s * v;
        } else {
          u16* ob = (u16*)outb;
          float prev = accum ? bf2f(ob[idx]) : 0.0f;
          ob[idx] = f2bf(prev + s * v);
        }
      }
    }
}

__global__ __launch_bounds__(256) void convert_out(
    const float* __restrict__ acc, void* __restrict__ out,
    const int* __restrict__ flags, int n) {
  int i = blockIdx.x * blockDim.x + threadIdx.x;
  if (i >= n) return;
  if (flags[6]) ((float*)out)[i] = acc[i];
  else ((u16*)out)[i] = f2bf(acc[i]);
}

extern "C" void kernel_launch(void* const* d_in, const int* in_sizes, int n_in,
                              void* d_out, int out_size, void* d_ws, size_t ws_size,
                              hipStream_t stream) {
  (void)in_sizes; (void)n_in; (void)out_size;
  const void* x   = d_in[0];
  const void* gw  = d_in[1];
  const u16*  gb  = (const u16*)d_in[2];
  const void* sw1 = d_in[3];
  const u16*  sb1 = (const u16*)d_in[4];
  const void* sw2 = d_in[5];
  const u16*  sb2 = (const u16*)d_in[6];
  const void* rw1 = d_in[7];
  const u16*  rb1 = (const u16*)d_in[8];
  const void* rw2 = d_in[9];
  const u16*  rb2 = (const u16*)d_in[10];

  const size_t NX   = (size_t)T_TOK * DD;
  const size_t NW1S = (size_t)NSH * FF * DD;
  const size_t NW1R = (size_t)EE * FF * DD;
  const size_t NW2S = (size_t)NSH * DD * FF;
  const size_t NW2R = (size_t)EE * DD * FF;

  // fast-path layout
  size_t off = 0;
  const size_t flO   = off; off += 256;
  const size_t cwO   = off; off += (size_t)T_TOK * EE * 4;
  const size_t tixO  = off; off += (size_t)T_TOK * 8;
  const size_t metaO = off; off += 256;
  const size_t listO = off; off += (size_t)EE * CAP * 4;
  const size_t srecO = off; off += (size_t)T_TOK * 16;
  const size_t accO  = off; off += (size_t)NSH * T_TOK * DD * 4;
  const size_t hshO  = off; off += (size_t)T_TOK * NSH * FF * 2;
  const size_t hrtO  = off; off += (size_t)NSLOT * FF * 2;
  const size_t ortO  = off; off += (size_t)NSLOT * DD * 4;
  const size_t xbO   = off; off += NX * 2;
  const size_t s1O   = off; off += NW1S * 2;
  const size_t r1O   = off; off += NW1R * 2;
  const size_t s2O   = off; off += NW2S * 2;
  const size_t r2O   = off; off += NW2R * 2;
  const int fast = (off <= ws_size) ? 1 : 0;

  char* ws = (char*)d_ws;
  int*   flags = (int*)(ws + flO);
  float* cw    = (float*)(ws + cwO);
  dim3 blk(256);

  if (fast) {
    int2*     tix  = (int2*)(ws + tixO);
    int*      meta = (int*)(ws + metaO);
    unsigned* list = (unsigned*)(ws + listO);
    int4*     srec = (int4*)(ws + srecO);
    float*    oacc = (float*)(ws + accO);
    u16*      Hsh  = (u16*)(ws + hshO);
    u16*      Hrt  = (u16*)(ws + hrtO);
    float*    Ort  = (float*)(ws + ortO);
    u16*      xb   = (u16*)(ws + xbO);
    u16*      s1b  = (u16*)(ws + s1O);
    u16*      r1b  = (u16*)(ws + r1O);
    u16*      s2b  = (u16*)(ws + s2O);
    u16*      r2b  = (u16*)(ws + r2O);

    detect_kernel<<<6, 256, 0, stream>>>(x, gw, sw1, sw2, rw1, rw2, flags,
                                         meta);
    conv_all<<<U8_C4 / 256, 256, 0, stream>>>(x, sw1, rw1, sw2, rw2, xb, s1b,
                                              r1b, s2b, r2b, flags);
    router_v<<<T_TOK / 4, 256, 0, stream>>>(x, gw, gb, flags, cw, tix);
    build_lists<<<T_TOK / 256, 256, 0, stream>>>(tix, meta, list, srec);
    pad_lists<<<1, 256, 0, stream>>>(meta, list);

    // FFN1: shared (z<2) + routed gather (z>=2), one dispatch
    dim3 gf1(16, T_TOK / BM, 2 + EE);            // 16 x 32 x 10
    g1_fused<<<gf1, blk, 0, stream>>>(x, xb, sw1, s1b, sb1, rw1, r1b, rb1,
                                      list, meta, flags, Hsh, Hrt);
    // FFN2: shared planes (z<NSH) + routed compact (z>=NSH), one dispatch
    dim3 gf2(DD / BN, CAP / BM, NSH + EE);       // 4 x 32 x 10
    g2_fused<<<gf2, blk, 0, stream>>>(Hsh, sw2, s2b, sb2, Hrt, rw2, r2b, rb2,
                                      list, meta, flags, cw, oacc, Ort);
    combine_out<<<T_TOK / 2, 256, 0, stream>>>(oacc, Ort, srec, meta, d_out,
                                               flags);
    return;
  }

  // -------- fallback: dense all-FFN path (no conversion), ws-adaptive --------
  detect_kernel<<<6, 256, 0, stream>>>(x, gw, sw1, sw2, rw1, rw2, flags,
                                       nullptr);
  const size_t flB = 256, cwB = (size_t)T_TOK * EE * 4, tixB = (size_t)T_TOK * 8;
  const size_t accB = (size_t)T_TOK * DD * 4;
  static const int tcs[4] = {4096, 2048, 1024, 512};
  int TC = 0, use_f32 = 1;
  for (int i = 0; i < 4; ++i)
    if (flB + cwB + tixB + accB + (size_t)tcs[i] * FF * 2 <= ws_size) { TC = tcs[i]; break; }
  if (!TC) {
    use_f32 = 0;
    for (int i = 0; i < 4; ++i)
      if (flB + cwB + tixB + (size_t)tcs[i] * FF * 2 <= ws_size) { TC = tcs[i]; break; }
  }
  if (!TC) { TC = 512; use_f32 = 0; }

  int2*  tix     = (int2*)(ws + flB + cwB);
  float* out_acc = use_f32 ? (float*)(ws + flB + cwB + tixB) : nullptr;
  u16*   H       = (u16*)(ws + flB + cwB + tixB + (use_f32 ? accB : 0));

  router_v<<<T_TOK / 4, 256, 0, stream>>>(x, gw, gb, flags, cw, tix);
  dim3 g1(FF / BN, TC / BM);
  dim3 g2(DD / BT2, TC / BT2);
  const int nchunk = T_TOK / TC;
  for (int f = 0; f < NSH + EE; ++f) {
    const void *w1, *w2; const u16 *b1, *b2; const float* cwp;
    int expert, i1, i2v; size_t w1off, w2off, b1off, b2off;
    if (f < NSH) {
      w1 = sw1; w2 = sw2; b1 = sb1; b2 = sb2;
      w1off = (size_t)f * FF * DD; w2off = (size_t)f * DD * FF;
      b1off = (size_t)f * FF; b2off = (size_t)f * DD;
      cwp = nullptr; expert = 0; i1 = 2; i2v = 3;
    } else {
      int e = f - NSH;
      w1 = rw1; w2 = rw2; b1 = rb1; b2 = rb2;
      w1off = (size_t)e * FF * DD; w2off = (size_t)e * DD * FF;
      b1off = (size_t)e * FF; b2off = (size_t)e * DD;
      cwp = cw; expert = e; i1 = 4; i2v = 5;
    }
    int accum = (f > 0) ? 1 : 0;
    for (int c = 0; c < nchunk; ++c) {
      size_t t0 = (size_t)c * TC;
      gemm1_gelu<<<g1, blk, 0, stream>>>(x, t0 * DD, w1, w1off, b1, b1off, H,
                                         flags, 0, i1, FF, DD);
      gemm2_acc<<<g2, blk, 0, stream>>>(H, w2, w2off, b2, b2off, out_acc,
                                        d_out, cwp, flags, i2v, expert, accum,
                                        (int)t0, DD, FF);
    }
  }
  if (use_f32)
    convert_out<<<(T_TOK * DD) / 256, 256, 0, stream>>>(out_acc, d_out, flags,
                                                        T_TOK * DD);
}

// Round 11
// 326.896 us; speedup vs baseline: 1.1486x; 1.0277x over previous
//
#include <hip/hip_runtime.h>
#include <math.h>

typedef unsigned short u16;
typedef __attribute__((ext_vector_type(8))) __bf16 bf16x8;
typedef __attribute__((ext_vector_type(4))) float floatx4;

#define T_TOK 4096
#define DD    512
#define FF    2048
#define EE    8
#define NSH   2

#define BM 128
#define BN 128
#define BK 32
#define LDK 40   // fallback kernels: padded LDS row stride
#define BT2 64   // fallback gemm2 N-tile
#define CAP 4096
#define PADF 0x80000000u
#define NSLOT (2 * T_TOK + EE * BM)   // 9216 compact rows max

__device__ __forceinline__ float bf2f(u16 v) {
  union { unsigned int u; float f; } c; c.u = ((unsigned int)v) << 16; return c.f;
}
__device__ __forceinline__ u16 f2bf(float f) {
  union { float ff; unsigned int u; } c; c.ff = f;
  unsigned int u = c.u;
  u += 0x7fffu + ((u >> 16) & 1u);   // RNE
  return (u16)(u >> 16);
}
__device__ __forceinline__ float decode(const void* p, size_t idx, int f) {
  return f ? ((const float*)p)[idx] : bf2f(((const u16*)p)[idx]);
}
__device__ __forceinline__ bf16x8 load8(const void* base, size_t idx, int f) {
  if (f) {
    const float* p = (const float*)base + idx;
    float4 a = *(const float4*)p;
    float4 b = *(const float4*)(p + 4);
    union { bf16x8 v; u16 s[8]; } u;
    u.s[0] = f2bf(a.x); u.s[1] = f2bf(a.y); u.s[2] = f2bf(a.z); u.s[3] = f2bf(a.w);
    u.s[4] = f2bf(b.x); u.s[5] = f2bf(b.y); u.s[6] = f2bf(b.z); u.s[7] = f2bf(b.w);
    return u.v;
  }
  return *(const bf16x8*)((const u16*)base + idx);
}
// full-precision 8-element load (fp32 stays fp32; bf16 widened) -- router path.
// Top-k selection is discontinuous in the logits: router must NOT quantize.
__device__ __forceinline__ void loadf8(const void* p, size_t idx, int f,
                                       float* o) {
  if (f) {
    const float* q = (const float*)p + idx;
    float4 a = *(const float4*)q;
    float4 b = *(const float4*)(q + 4);
    o[0] = a.x; o[1] = a.y; o[2] = a.z; o[3] = a.w;
    o[4] = b.x; o[5] = b.y; o[6] = b.z; o[7] = b.w;
  } else {
    union { bf16x8 v; u16 s[8]; } u;
    u.v = *(const bf16x8*)((const u16*)p + idx);
#pragma unroll
    for (int j = 0; j < 8; ++j) o[j] = bf2f(u.s[j]);
  }
}

// fast exact-GELU: erf via Abramowitz-Stegun 7.1.26 (|err| 1.5e-7), native rcp/exp
__device__ __forceinline__ float fast_gelu(float v) {
  float x  = v * 0.70710678118654752f;
  float ax = fabsf(x);
  float t  = __builtin_amdgcn_rcpf(fmaf(0.3275911f, ax, 1.0f));
  float p  = fmaf(t, 1.061405429f, -1.453152027f);
  p = fmaf(t, p, 1.421413741f);
  p = fmaf(t, p, -0.284496736f);
  p = fmaf(t, p, 0.254829592f);
  p = p * t;
  float e  = __expf(-ax * ax);
  float er = fmaf(-p, e, 1.0f);          // erf(|x|)
  er = (x < 0.f) ? -er : er;
  return 0.5f * v * (1.0f + er);
}

// async 16B global->LDS. LDS dest is wave-uniform base; HW writes base+lane*16.
__device__ __forceinline__ void gll16(const void* g, void* l) {
  __builtin_amdgcn_global_load_lds(
      (const __attribute__((address_space(1))) void*)g,
      (__attribute__((address_space(3))) void*)l, 16, 0, 0);
}

#define BK2 64
#define TILEU (BM * BK2)   // 8192 u16 = 16KB per buffer

// stage one 128x64 k-slab with 4 waves' worth of chunks (8 gll16 per wave
// pattern used by the 4-wave cores)
__device__ __forceinline__ void stage8(
    const u16* gA0, const u16* gA1, const u16* gA2, const u16* gA3,
    const u16* gB0, const u16* gB1, const u16* gB2, const u16* gB3,
    u16* Asb, u16* Bsb, int wave, int k0) {
  gll16(gA0 + k0, Asb + wave * 512);
  gll16(gA1 + k0, Asb + 2048 + wave * 512);
  gll16(gA2 + k0, Asb + 4096 + wave * 512);
  gll16(gA3 + k0, Asb + 6144 + wave * 512);
  gll16(gB0 + k0, Bsb + wave * 512);
  gll16(gB1 + k0, Bsb + 2048 + wave * 512);
  gll16(gB2 + k0, Bsb + 4096 + wave * 512);
  gll16(gB3 + k0, Bsb + 6144 + wave * 512);
}

// ===== T3+T4 pipelined core (g2's best: round 8 -- K=2048's 32 iters
// amortize the prologue; counted vmcnt(8) keeps next tile's loads in
// flight ACROSS the barrier). K-dependent: REGRESSED g1 (K=512).
__device__ __forceinline__ void core128pipe(
    const u16* gA0, const u16* gA1, const u16* gA2, const u16* gA3,
    const u16* gB0, const u16* gB1, const u16* gB2, const u16* gB3,
    int K, u16* As, u16* Bs, floatx4 acc[4][4],
    int wave, int wm, int wn, int r, int q) {
  const int rs = r & 7;                 // fragment-row low bits (R&7 == r&7)
  stage8(gA0, gA1, gA2, gA3, gB0, gB1, gB2, gB3, As, Bs, wave, 0);
  int cur = 0;
  for (int k0 = 0; k0 < K; k0 += BK2) {
    const u16* Ac = As + cur * TILEU;
    const u16* Bc = Bs + cur * TILEU;
    if (k0 + BK2 < K) {
      stage8(gA0, gA1, gA2, gA3, gB0, gB1, gB2, gB3,
             As + (cur ^ 1) * TILEU, Bs + (cur ^ 1) * TILEU, wave, k0 + BK2);
      // wait for THIS tile's 8 loads; leave next tile's 8 in flight
      asm volatile("s_waitcnt vmcnt(8)" ::: "memory");
    } else {
      asm volatile("s_waitcnt vmcnt(0)" ::: "memory");
    }
    __builtin_amdgcn_sched_barrier(0);
    __builtin_amdgcn_s_barrier();       // all waves: cur tile landed
    __builtin_amdgcn_sched_barrier(0);
#pragma unroll
    for (int s = 0; s < 2; ++s) {       // two k=32 slabs per 64-elem row
      bf16x8 af[4], bfr[4];
#pragma unroll
      for (int mi = 0; mi < 4; ++mi) {
        int R = wm + mi * 16 + r;
        int u = (s * 4 + q) ^ rs;
        af[mi] = *(const bf16x8*)(Ac + R * 64 + u * 8);
      }
#pragma unroll
      for (int ni = 0; ni < 4; ++ni) {
        int R = wn + ni * 16 + r;
        int u = (s * 4 + q) ^ rs;
        bfr[ni] = *(const bf16x8*)(Bc + R * 64 + u * 8);
      }
#pragma unroll
      for (int mi = 0; mi < 4; ++mi)
#pragma unroll
        for (int ni = 0; ni < 4; ++ni)
          acc[mi][ni] = __builtin_amdgcn_mfma_f32_16x16x32_bf16(
              af[mi], bfr[ni], acc[mi][ni], 0, 0, 0);
    }
    __builtin_amdgcn_sched_barrier(0);
    __builtin_amdgcn_s_barrier();       // all waves done reading cur
    cur ^= 1;
  }
}

// Probe: classify tensors fp32(1)/bf16(0) -- 6 blocks, one tensor each.
// Block 0 also writes flags[6..7] and zeroes meta.
__global__ __launch_bounds__(256) void detect_kernel(
    const void* x, const void* gw, const void* sw1, const void* sw2,
    const void* rw1, const void* rw2, int* flags, int* meta) {
  __shared__ int cnt;
  const void* ptrs[6] = {x, gw, sw1, sw2, rw1, rw2};
  int b = blockIdx.x;
  if (threadIdx.x == 0) cnt = 0;
  __syncthreads();
  const u16* p = (const u16*)ptrs[b];
  int local = 0;
  for (int i = threadIdx.x; i < 4096; i += 256) {
    unsigned ef = (p[i] >> 7) & 0xFFu;
    if (ef >= 0xE0u) ++local;
  }
  if (local) atomicAdd(&cnt, local);
  __syncthreads();
  if (threadIdx.x == 0) {
    int f = (cnt >= 16) ? 1 : 0;
    flags[b] = f;
    if (b == 0) {
      flags[6] = f;   // output dtype follows x
      flags[7] = 0;   // ws bf16 buffers
    }
  }
  if (b == 0 && meta && threadIdx.x < 24) meta[threadIdx.x] = 0;
}

// merged conversion over x + 4 weight tensors; per-segment flag early-exit
// (bf16 inputs are consumed raw downstream -- skip-copy).
#define U8_X  (T_TOK * DD / 8)
#define U8_S1 (NSH * FF * DD / 8)
#define U8_R1 (EE * FF * DD / 8)
#define U8_S2 (NSH * DD * FF / 8)
#define U8_R2 (EE * DD * FF / 8)
#define U8_C0 (U8_X)
#define U8_C1 (U8_C0 + U8_S1)
#define U8_C2 (U8_C1 + U8_R1)
#define U8_C3 (U8_C2 + U8_S2)
#define U8_C4 (U8_C3 + U8_R2)
__global__ __launch_bounds__(256) void conv_all(
    const void* __restrict__ x, const void* __restrict__ sw1,
    const void* __restrict__ rw1, const void* __restrict__ sw2,
    const void* __restrict__ rw2, u16* __restrict__ xb,
    u16* __restrict__ s1b, u16* __restrict__ r1b, u16* __restrict__ s2b,
    u16* __restrict__ r2b, const int* __restrict__ flags) {
  size_t u = (size_t)blockIdx.x * 256 + threadIdx.x;
  const void* src; u16* dst; int fi; size_t base;
  if (u < U8_C0)      { src = x;   dst = xb;  fi = 0; base = 0; }
  else if (u < U8_C1) { src = sw1; dst = s1b; fi = 2; base = U8_C0; }
  else if (u < U8_C2) { src = rw1; dst = r1b; fi = 4; base = U8_C1; }
  else if (u < U8_C3) { src = sw2; dst = s2b; fi = 3; base = U8_C2; }
  else                { src = rw2; dst = r2b; fi = 5; base = U8_C3; }
  int f = flags[fi];
  if (!f) return;               // bf16: raw tensor used directly downstream
  size_t i = (u - base) * 8;
  *(bf16x8*)(dst + i) = load8(src, i, f);
}

// Router: FULL-precision logits (raw x, raw gw), vectorized 16B loads.
__global__ __launch_bounds__(256) void router_v(
    const void* __restrict__ x, const void* __restrict__ gw,
    const u16* __restrict__ gb, const int* __restrict__ flags,
    float* __restrict__ cw, int2* __restrict__ tix) {
  int wave = threadIdx.x >> 6, lane = threadIdx.x & 63;
  int t = blockIdx.x * 4 + wave;
  int fx = flags[0], fg = flags[1];
  float xf[8];
  loadf8(x, (size_t)t * DD + lane * 8, fx, xf);
  float acc[EE];
#pragma unroll
  for (int e = 0; e < EE; ++e) {
    float gf[8];
    loadf8(gw, (size_t)e * DD + lane * 8, fg, gf);
    float a = 0.f;
#pragma unroll
    for (int j = 0; j < 8; ++j) a = fmaf(xf[j], gf[j], a);
    acc[e] = a;
  }
#pragma unroll
  for (int e = 0; e < EE; ++e) {
    float v = acc[e];
#pragma unroll
    for (int off = 32; off > 0; off >>= 1) v += __shfl_xor(v, off, 64);
    acc[e] = v;
  }
  if (lane == 0) {
    float m = -1e30f;
#pragma unroll
    for (int e = 0; e < EE; ++e) {
      acc[e] += bf2f(gb[e]);   // all-zero: dtype-agnostic
      m = fmaxf(m, acc[e]);
    }
    float p[EE], s = 0.f;
#pragma unroll
    for (int e = 0; e < EE; ++e) { p[e] = expf(acc[e] - m); s += p[e]; }
    int i1 = 0;
#pragma unroll
    for (int e = 1; e < EE; ++e) if (p[e] > p[i1]) i1 = e;
    int i2 = (i1 == 0) ? 1 : 0;
#pragma unroll
    for (int e = 0; e < EE; ++e)
      if (e != i1 && p[e] > p[i2]) i2 = e;
    float inv = 1.0f / s;
#pragma unroll
    for (int e = 0; e < EE; ++e)
      cw[t * EE + e] = (e == i1 || e == i2) ? p[e] * inv : 0.0f;
    tix[t] = make_int2(i1, i2);
  }
}

// build lists: 16 blocks, all-lane atomics (TA/L2 combines same-address
// lanes); round-5-verified structure.
__global__ __launch_bounds__(256) void build_lists(
    const int2* __restrict__ tix, int* __restrict__ meta,
    unsigned* __restrict__ list, int4* __restrict__ srec) {
  int t = blockIdx.x * 256 + threadIdx.x;
  if (t >= T_TOK) return;
  int2 ii = tix[t];
  int p0 = atomicAdd(&meta[ii.x], 1);
  list[(size_t)ii.x * CAP + p0] = (unsigned)t;
  int p1 = atomicAdd(&meta[ii.y], 1);
  list[(size_t)ii.y * CAP + p1] = (unsigned)t;
  srec[t] = make_int4(ii.x, p0, ii.y, p1);
}
// meta: [0..7]=cnt, [8..15]=pc (padded), [16..23]=row prefix
__global__ __launch_bounds__(256) void pad_lists(int* meta, unsigned* list) {
  if (threadIdx.x == 0) {
    int off = 0;
    for (int e = 0; e < EE; ++e) {
      int c = meta[e];
      int pc = (c + BM - 1) & ~(BM - 1);
      meta[8 + e] = pc;
      meta[16 + e] = off;
      off += pc;
    }
  }
  __syncthreads();
#pragma unroll
  for (int e = 0; e < EE; ++e) {
    int c = meta[e], pc = meta[8 + e];
    int i = c + threadIdx.x;
    if (i < pc) list[(size_t)e * CAP + i] = PADF;
  }
}

// ========== fast path GEMMs ==========

// FFN1 (shared + routed gather) in ONE dispatch. grid (16, 32, 10), 512 thr.
// 8-WAVE variant of the single-buffer swizzled core: same 128x128 tile, same
// linear-LDS + inverse-swz-source + swz-read layout (conflict-free, round 6),
// but 8 waves x 32x64 sub-tiles. Rationale: the 2-barrier structure relies on
// inter-wave TLP to hide the vmcnt(0) drain (m114); 4-wave/108-VGPR capped
// occupancy at ~6 waves/CU (19.6%). 512thr + acc[2][4] (~95 VGPR) + 32KB LDS
// -> 4 blocks x 8 waves = 32 waves/CU (100% cap).
__global__ __launch_bounds__(512) void g1_fused(
    const void* __restrict__ xr, const u16* __restrict__ xb,
    const void* __restrict__ s1r, const u16* __restrict__ s1b,
    const u16* __restrict__ sb1,
    const void* __restrict__ r1r, const u16* __restrict__ r1b,
    const u16* __restrict__ rb1, const unsigned* __restrict__ list,
    const int* __restrict__ meta, const int* __restrict__ flags,
    u16* __restrict__ Hsh, u16* __restrict__ Hrt) {
  // skip-copy: raw tensor when already bf16
  const u16* xp  = flags[0] ? xb  : (const u16*)xr;
  const u16* s1p = flags[2] ? s1b : (const u16*)s1r;
  const u16* r1p = flags[4] ? r1b : (const u16*)r1r;

  int z  = blockIdx.z;
  int bm = blockIdx.y * BM;
  int xx = blockIdx.x;

  int tid = threadIdx.x, lane = tid & 63, wave = tid >> 6;   // wave 0..7
  int wm = (wave & 3) * 32;        // 4 row-groups of 32
  int wn = (wave >> 2) * 64;       // 2 col-groups of 64
  int r = lane & 15, q = lane >> 4;
  const int K = DD;

  // staging: wave w stages chunks 2w,2w+1 of A and B (1KB each; rows
  // w*16+lrow and w*16+8+lrow). Chunk rows == lrow (mod 8), so the source
  // pre-swizzle is us = (lane&7) ^ lrow -- same involution as the ds_read.
  int lrow = lane >> 3;            // 0..7
  int us = (lane & 7) ^ lrow;      // pre-swizzled source unit

  __shared__ u16 As[TILEU];   // 16KB single buffer
  __shared__ u16 Bs[TILEU];   // 16KB

  const u16 *gA0, *gA1, *gB0, *gB1;
  int e = 0, ho = 0, bn;
  if (z < 2) {
    bn = (z * 16 + xx) * BN;
    gA0 = xp + (size_t)(bm + wave * 16 + lrow) * K + us * 8;
    gA1 = xp + (size_t)(bm + wave * 16 + 8 + lrow) * K + us * 8;
    gB0 = s1p + (size_t)(bn + wave * 16 + lrow) * K + us * 8;
    gB1 = s1p + (size_t)(bn + wave * 16 + 8 + lrow) * K + us * 8;
  } else {
    e = z - 2;
    if (bm >= meta[8 + e]) return;
    ho = meta[16 + e];
    bn = xx * BN;
    unsigned t0 = list[(size_t)e * CAP + bm + wave * 16 + lrow] & 0x7fffffffu;
    unsigned t1 =
        list[(size_t)e * CAP + bm + wave * 16 + 8 + lrow] & 0x7fffffffu;
    gA0 = xp + (size_t)t0 * K + us * 8;
    gA1 = xp + (size_t)t1 * K + us * 8;
    gB0 = r1p + (size_t)e * FF * DD + (size_t)(bn + wave * 16 + lrow) * K +
          us * 8;
    gB1 = r1p + (size_t)e * FF * DD +
          (size_t)(bn + wave * 16 + 8 + lrow) * K + us * 8;
  }

  floatx4 acc[2][4];
  floatx4 zero = {0.f, 0.f, 0.f, 0.f};
#pragma unroll
  for (int i = 0; i < 2; ++i)
#pragma unroll
    for (int j = 0; j < 4; ++j) acc[i][j] = zero;

  const int rs = r & 7;
  for (int k0 = 0; k0 < K; k0 += BK2) {
    __syncthreads();
    gll16(gA0 + k0, As + wave * 1024);         // chunk 2w   (rows w*16..+7)
    gll16(gA1 + k0, As + wave * 1024 + 512);   // chunk 2w+1 (rows w*16+8..+15)
    gll16(gB0 + k0, Bs + wave * 1024);
    gll16(gB1 + k0, Bs + wave * 1024 + 512);
    __syncthreads();   // compiler drains vmcnt before barrier
#pragma unroll
    for (int s = 0; s < 2; ++s) {
      bf16x8 af[2], bfr[4];
#pragma unroll
      for (int mi = 0; mi < 2; ++mi) {
        int R = wm + mi * 16 + r;
        int u = (s * 4 + q) ^ rs;
        af[mi] = *(const bf16x8*)(As + R * 64 + u * 8);
      }
#pragma unroll
      for (int ni = 0; ni < 4; ++ni) {
        int R = wn + ni * 16 + r;
        int u = (s * 4 + q) ^ rs;
        bfr[ni] = *(const bf16x8*)(Bs + R * 64 + u * 8);
      }
#pragma unroll
      for (int mi = 0; mi < 2; ++mi)
#pragma unroll
        for (int ni = 0; ni < 4; ++ni)
          acc[mi][ni] = __builtin_amdgcn_mfma_f32_16x16x32_bf16(
              af[mi], bfr[ni], acc[mi][ni], 0, 0, 0);
    }
  }

  if (z < 2) {
#pragma unroll
    for (int mi = 0; mi < 2; ++mi)
#pragma unroll
      for (int ni = 0; ni < 4; ++ni) {
        int col = bn + wn + ni * 16 + r;
        float bv = bf2f(sb1[col]);
#pragma unroll
        for (int rr = 0; rr < 4; ++rr) {
          int row = bm + wm + mi * 16 + q * 4 + rr;
          float v = acc[mi][ni][rr] + bv;
          Hsh[(size_t)row * (NSH * FF) + col] = f2bf(fast_gelu(v));
        }
      }
  } else {
#pragma unroll
    for (int mi = 0; mi < 2; ++mi)
#pragma unroll
      for (int ni = 0; ni < 4; ++ni) {
        int col = bn + wn + ni * 16 + r;
        float bv = bf2f(rb1[(size_t)e * FF + col]);
#pragma unroll
        for (int rr = 0; rr < 4; ++rr) {
          int slot = bm + wm + mi * 16 + q * 4 + rr;
          float v = acc[mi][ni][rr] + bv;
          Hrt[(size_t)(ho + slot) * FF + col] = f2bf(fast_gelu(v));
        }
      }
  }
}

// FFN2 (shared planes + routed compact) in ONE dispatch. grid (4, 32, 10).
// Pipelined core + XCD remap kept (round 8: g2 improved, left top-5).
__global__ __launch_bounds__(256) void g2_fused(
    const u16* __restrict__ Hsh,
    const void* __restrict__ s2r, const u16* __restrict__ s2b,
    const u16* __restrict__ sb2, const u16* __restrict__ Hrt,
    const void* __restrict__ r2r, const u16* __restrict__ r2b,
    const u16* __restrict__ rb2,
    const unsigned* __restrict__ list, const int* __restrict__ meta,
    const int* __restrict__ flags, const float* __restrict__ cw,
    float* __restrict__ oacc, float* __restrict__ Ort) {
  const u16* s2p = flags[3] ? s2b : (const u16*)s2r;
  const u16* r2p = flags[5] ? r2b : (const u16*)r2r;

  // XCD remap: 4 x-sharers of an A-panel get ids == same (mod 8)
  int L  = blockIdx.x + 4 * (blockIdx.y + 32 * blockIdx.z);
  int xx = (L & 31) >> 3;                     // 0..3 (bn tile)
  int pp = ((L >> 5) << 3) | (L & 7);         // panel 0..319
  int z  = pp >> 5;                           // 0..9
  int bm = (pp & 31) * BM;
  int bn = xx * BN;

  int tid = threadIdx.x, lane = tid & 63, wave = tid >> 6;
  int wm = (wave >> 1) * 64, wn = (wave & 1) * 64;
  int r = lane & 15, q = lane >> 4;
  const int K = FF;

  int rsub = tid >> 3;
  int us = (tid & 7) ^ (rsub & 7);

  __shared__ u16 As[2 * TILEU];   // 32KB (2-deep dbuf)
  __shared__ u16 Bs[2 * TILEU];   // 32KB

  const u16 *gA[4], *gB[4];
  int e = 0, ho = 0;
  if (z < NSH) {
    const int ldA = NSH * FF;
#pragma unroll
    for (int c = 0; c < 4; ++c) {
      gA[c] = Hsh + (size_t)(bm + c * 32 + rsub) * ldA + (size_t)z * FF +
              us * 8;
      gB[c] = s2p + (size_t)z * DD * FF + (size_t)(bn + c * 32 + rsub) * K +
              us * 8;
    }
  } else {
    e = z - NSH;
    if (bm >= meta[8 + e]) return;
    ho = meta[16 + e];
#pragma unroll
    for (int c = 0; c < 4; ++c) {
      gA[c] = Hrt + (size_t)(ho + bm + c * 32 + rsub) * K + us * 8;
      gB[c] = r2p + (size_t)e * DD * FF + (size_t)(bn + c * 32 + rsub) * K +
              us * 8;
    }
  }

  floatx4 acc[4][4];
  floatx4 zero = {0.f, 0.f, 0.f, 0.f};
#pragma unroll
  for (int i = 0; i < 4; ++i)
#pragma unroll
    for (int j = 0; j < 4; ++j) acc[i][j] = zero;

  core128pipe(gA[0], gA[1], gA[2], gA[3], gB[0], gB[1], gB[2], gB[3],
              K, As, Bs, acc, wave, wm, wn, r, q);

  if (z < NSH) {
    float* op = oacc + (size_t)z * T_TOK * DD;
#pragma unroll
    for (int mi = 0; mi < 4; ++mi)
#pragma unroll
      for (int ni = 0; ni < 4; ++ni) {
        int col = bn + wn + ni * 16 + r;
        float bv = bf2f(sb2[(size_t)z * DD + col]);
#pragma unroll
        for (int rr = 0; rr < 4; ++rr) {
          int row = bm + wm + mi * 16 + q * 4 + rr;
          op[(size_t)row * DD + col] = acc[mi][ni][rr] + bv;
        }
      }
  } else {
#pragma unroll
    for (int mi = 0; mi < 4; ++mi)
#pragma unroll
      for (int rr = 0; rr < 4; ++rr) {
        int slot = bm + wm + mi * 16 + q * 4 + rr;
        unsigned raw = list[(size_t)e * CAP + slot];
        if (raw & PADF) continue;
        float s = cw[raw * EE + e];
#pragma unroll
        for (int ni = 0; ni < 4; ++ni) {
          int col = bn + wn + ni * 16 + r;
          float v = acc[mi][ni][rr] + bf2f(rb2[(size_t)e * DD + col]);
          Ort[(size_t)(ho + slot) * DD + col] = s * v;
        }
      }
  }
}

// final: out[t] = oacc0[t] + oacc1[t] + Ort[g0(t)] + Ort[g1(t)]
typedef struct { u16 a, b, c, d; } u16x4;
__global__ __launch_bounds__(256) void combine_out(
    const float* __restrict__ oacc, const float* __restrict__ Ort,
    const int4* __restrict__ srec, const int* __restrict__ meta,
    void* __restrict__ out, const int* __restrict__ flags) {
  int t  = blockIdx.x * 2 + (threadIdx.x >> 7);
  int c4 = (threadIdx.x & 127) * 4;
  int4 sr = srec[t];
  int g0 = meta[16 + sr.x] + sr.y;
  int g1 = meta[16 + sr.z] + sr.w;
  float4 a = *(const float4*)(oacc + (size_t)t * DD + c4);
  float4 b = *(const float4*)(oacc + (size_t)(T_TOK + t) * DD + c4);
  float4 u = *(const float4*)(Ort + (size_t)g0 * DD + c4);
  float4 v = *(const float4*)(Ort + (size_t)g1 * DD + c4);
  float o0 = a.x + b.x + u.x + v.x;
  float o1 = a.y + b.y + u.y + v.y;
  float o2 = a.z + b.z + u.z + v.z;
  float o3 = a.w + b.w + u.w + v.w;
  size_t idx = (size_t)t * DD + c4;
  if (flags[6]) {
    *(float4*)((float*)out + idx) = make_float4(o0, o1, o2, o3);
  } else {
    u16x4 h = {f2bf(o0), f2bf(o1), f2bf(o2), f2bf(o3)};
    *(u16x4*)((u16*)out + idx) = h;
  }
}

// ---------------- fallback-path kernels (dense, unconverted) ----------------
__device__ __forceinline__ void gemm_core(const void* A, size_t aoff, int fA,
                                          const void* B, size_t boff, int fB,
                                          int K, u16* As, u16* Bs,
                                          floatx4 acc[4][4]) {
  int tid  = threadIdx.x;
  int lane = tid & 63, wave = tid >> 6;
  int wm = (wave >> 1) * 64, wn = (wave & 1) * 64;
  int r = lane & 15, q = lane >> 4;
  int srow = tid >> 2;
  int sc8  = (tid & 3) * 8;
  size_t abase = aoff + (size_t)srow * K + sc8;
  size_t bbase = boff + (size_t)srow * K + sc8;
  const size_t half = (size_t)64 * K;

  for (int k0 = 0; k0 < K; k0 += BK) {
    bf16x8 av0 = load8(A, abase + k0, fA);
    bf16x8 av1 = load8(A, abase + half + k0, fA);
    bf16x8 bv0 = load8(B, bbase + k0, fB);
    bf16x8 bv1 = load8(B, bbase + half + k0, fB);
    __syncthreads();
    *(bf16x8*)(As + srow * LDK + sc8)        = av0;
    *(bf16x8*)(As + (srow + 64) * LDK + sc8) = av1;
    *(bf16x8*)(Bs + srow * LDK + sc8)        = bv0;
    *(bf16x8*)(Bs + (srow + 64) * LDK + sc8) = bv1;
    __syncthreads();

    bf16x8 af[4], bfr[4];
#pragma unroll
    for (int mi = 0; mi < 4; ++mi)
      af[mi] = *(const bf16x8*)(As + (wm + mi * 16 + r) * LDK + q * 8);
#pragma unroll
    for (int ni = 0; ni < 4; ++ni)
      bfr[ni] = *(const bf16x8*)(Bs + (wn + ni * 16 + r) * LDK + q * 8);
#pragma unroll
    for (int mi = 0; mi < 4; ++mi)
#pragma unroll
      for (int ni = 0; ni < 4; ++ni)
        acc[mi][ni] = __builtin_amdgcn_mfma_f32_16x16x32_bf16(
            af[mi], bfr[ni], acc[mi][ni], 0, 0, 0);
  }
}

__global__ __launch_bounds__(256) void gemm1_gelu(
    const void* __restrict__ A, size_t aoff, const void* __restrict__ B,
    size_t boff, const u16* __restrict__ bias, size_t bioff,
    u16* __restrict__ H, const int* __restrict__ flags, int iA, int iB,
    int N, int K) {
  __shared__ u16 As[BM * LDK];
  __shared__ u16 Bs[BN * LDK];
  int fA = flags[iA], fB = flags[iB];
  floatx4 acc[4][4];
  floatx4 zero = {0.f, 0.f, 0.f, 0.f};
#pragma unroll
  for (int i = 0; i < 4; ++i)
#pragma unroll
    for (int j = 0; j < 4; ++j) acc[i][j] = zero;

  int bm = blockIdx.y * BM, bn = blockIdx.x * BN;
  gemm_core(A, aoff + (size_t)bm * K, fA, B, boff + (size_t)bn * K, fB, K,
            As, Bs, acc);

  int tid = threadIdx.x, wave = tid >> 6, lane = tid & 63;
  int wm = (wave >> 1) * 64, wn = (wave & 1) * 64;
  int r = lane & 15, q = lane >> 4;
#pragma unroll
  for (int mi = 0; mi < 4; ++mi)
#pragma unroll
    for (int ni = 0; ni < 4; ++ni) {
      int col = bn + wn + ni * 16 + r;
      float bv = bf2f(bias[bioff + col]);
#pragma unroll
      for (int rr = 0; rr < 4; ++rr) {
        int row = bm + wm + mi * 16 + q * 4 + rr;
        float v = acc[mi][ni][rr] + bv;
        H[(size_t)row * N + col] = f2bf(fast_gelu(v));
      }
    }
}

__global__ __launch_bounds__(256) void gemm2_acc(
    const u16* __restrict__ A, const void* __restrict__ B, size_t boff,
    const u16* __restrict__ bias, size_t bioff, float* __restrict__ outf,
    void* __restrict__ outb, const float* __restrict__ cw,
    const int* __restrict__ flags, int iB, int expert, int accum,
    int row0, int N, int K) {
  __shared__ u16 As[BT2 * LDK];
  __shared__ u16 Bs[BT2 * LDK];
  int fB = flags[iB], fO = flags[6];
  floatx4 acc[2][2];
  floatx4 zero = {0.f, 0.f, 0.f, 0.f};
#pragma unroll
  for (int i = 0; i < 2; ++i)
#pragma unroll
    for (int j = 0; j < 2; ++j) acc[i][j] = zero;

  int bm = blockIdx.y * BT2, bn = blockIdx.x * BT2;
  int tid  = threadIdx.x;
  int lane = tid & 63, wave = tid >> 6;
  int wm = (wave >> 1) * 32, wn = (wave & 1) * 32;
  int r = lane & 15, q = lane >> 4;
  int srow = tid >> 2;
  int sc8  = (tid & 3) * 8;
  size_t abase = (size_t)(bm + srow) * K + sc8;
  size_t bbase = boff + (size_t)(bn + srow) * K + sc8;

  for (int k0 = 0; k0 < K; k0 += BK) {
    bf16x8 av = *(const bf16x8*)(A + abase + k0);
    bf16x8 bv = load8(B, bbase + k0, fB);
    __syncthreads();
    *(bf16x8*)(As + srow * LDK + sc8) = av;
    *(bf16x8*)(Bs + srow * LDK + sc8) = bv;
    __syncthreads();

    bf16x8 af[2], bfr[2];
#pragma unroll
    for (int mi = 0; mi < 2; ++mi)
      af[mi] = *(const bf16x8*)(As + (wm + mi * 16 + r) * LDK + q * 8);
#pragma unroll
    for (int ni = 0; ni < 2; ++ni)
      bfr[ni] = *(const bf16x8*)(Bs + (wn + ni * 16 + r) * LDK + q * 8);
#pragma unroll
    for (int mi = 0; mi < 2; ++mi)
#pragma unroll
      for (int ni = 0; ni < 2; ++ni)
        acc[mi][ni] = __builtin_amdgcn_mfma_f32_16x16x32_bf16(
            af[mi], bfr[ni], acc[mi][ni], 0, 0, 0);
  }

#pragma unroll
  for (int mi = 0; mi < 2; ++mi)
#pragma unroll
    for (int rr = 0; rr < 4; ++rr) {
      int grow = row0 + bm + wm + mi * 16 + q * 4 + rr;
      float s = cw ? cw[grow * EE + expert] : 1.0f;
#pragma unroll
      for (int ni = 0; ni < 2; ++ni) {
        int col = bn + wn + ni * 16 + r;
        float v = acc[mi][ni][rr] + bf2f(bias[bioff + col]);
        size_t idx = (size_t)grow * N + col;
        if (outf) {
          float prev = accum ? outf[idx] : 0.0f;
          outf[idx] = prev + s * v;
        } else if (fO) {
          float* ob = (float*)outb;
          float prev = accum ? ob[idx] : 0.0f;
          ob[idx] = prev + s * v;
        } else {
          u16* ob = (u16*)outb;
          float prev = accum ? bf2f(ob[idx]) : 0.0f;
          ob[idx] = f2bf(prev + s * v);
        }
      }
    }
}

__global__ __launch_bounds__(256) void convert_out(
    const float* __restrict__ acc, void* __restrict__ out,
    const int* __restrict__ flags, int n) {
  int i = blockIdx.x * blockDim.x + threadIdx.x;
  if (i >= n) return;
  if (flags[6]) ((float*)out)[i] = acc[i];
  else ((u16*)out)[i] = f2bf(acc[i]);
}

extern "C" void kernel_launch(void* const* d_in, const int* in_sizes, int n_in,
                              void* d_out, int out_size, void* d_ws, size_t ws_size,
                              hipStream_t stream) {
  (void)in_sizes; (void)n_in; (void)out_size;
  const void* x   = d_in[0];
  const void* gw  = d_in[1];
  const u16*  gb  = (const u16*)d_in[2];
  const void* sw1 = d_in[3];
  const u16*  sb1 = (const u16*)d_in[4];
  const void* sw2 = d_in[5];
  const u16*  sb2 = (const u16*)d_in[6];
  const void* rw1 = d_in[7];
  const u16*  rb1 = (const u16*)d_in[8];
  const void* rw2 = d_in[9];
  const u16*  rb2 = (const u16*)d_in[10];

  const size_t NX   = (size_t)T_TOK * DD;
  const size_t NW1S = (size_t)NSH * FF * DD;
  const size_t NW1R = (size_t)EE * FF * DD;
  const size_t NW2S = (size_t)NSH * DD * FF;
  const size_t NW2R = (size_t)EE * DD * FF;

  // fast-path layout
  size_t off = 0;
  const size_t flO   = off; off += 256;
  const size_t cwO   = off; off += (size_t)T_TOK * EE * 4;
  const size_t tixO  = off; off += (size_t)T_TOK * 8;
  const size_t metaO = off; off += 256;
  const size_t listO = off; off += (size_t)EE * CAP * 4;
  const size_t srecO = off; off += (size_t)T_TOK * 16;
  const size_t accO  = off; off += (size_t)NSH * T_TOK * DD * 4;
  const size_t hshO  = off; off += (size_t)T_TOK * NSH * FF * 2;
  const size_t hrtO  = off; off += (size_t)NSLOT * FF * 2;
  const size_t ortO  = off; off += (size_t)NSLOT * DD * 4;
  const size_t xbO   = off; off += NX * 2;
  const size_t s1O   = off; off += NW1S * 2;
  const size_t r1O   = off; off += NW1R * 2;
  const size_t s2O   = off; off += NW2S * 2;
  const size_t r2O   = off; off += NW2R * 2;
  const int fast = (off <= ws_size) ? 1 : 0;

  char* ws = (char*)d_ws;
  int*   flags = (int*)(ws + flO);
  float* cw    = (float*)(ws + cwO);
  dim3 blk(256);

  if (fast) {
    int2*     tix  = (int2*)(ws + tixO);
    int*      meta = (int*)(ws + metaO);
    unsigned* list = (unsigned*)(ws + listO);
    int4*     srec = (int4*)(ws + srecO);
    float*    oacc = (float*)(ws + accO);
    u16*      Hsh  = (u16*)(ws + hshO);
    u16*      Hrt  = (u16*)(ws + hrtO);
    float*    Ort  = (float*)(ws + ortO);
    u16*      xb   = (u16*)(ws + xbO);
    u16*      s1b  = (u16*)(ws + s1O);
    u16*      r1b  = (u16*)(ws + r1O);
    u16*      s2b  = (u16*)(ws + s2O);
    u16*      r2b  = (u16*)(ws + r2O);

    detect_kernel<<<6, 256, 0, stream>>>(x, gw, sw1, sw2, rw1, rw2, flags,
                                         meta);
    conv_all<<<U8_C4 / 256, 256, 0, stream>>>(x, sw1, rw1, sw2, rw2, xb, s1b,
                                              r1b, s2b, r2b, flags);
    router_v<<<T_TOK / 4, 256, 0, stream>>>(x, gw, gb, flags, cw, tix);
    build_lists<<<T_TOK / 256, 256, 0, stream>>>(tix, meta, list, srec);
    pad_lists<<<1, 256, 0, stream>>>(meta, list);

    // FFN1: shared (z<2) + routed gather (z>=2), one dispatch, 512 threads
    dim3 gf1(16, T_TOK / BM, 2 + EE);            // 16 x 32 x 10
    g1_fused<<<gf1, dim3(512), 0, stream>>>(x, xb, sw1, s1b, sb1, rw1, r1b,
                                            rb1, list, meta, flags, Hsh, Hrt);
    // FFN2: shared planes (z<NSH) + routed compact (z>=NSH), one dispatch
    dim3 gf2(DD / BN, CAP / BM, NSH + EE);       // 4 x 32 x 10
    g2_fused<<<gf2, blk, 0, stream>>>(Hsh, sw2, s2b, sb2, Hrt, rw2, r2b, rb2,
                                      list, meta, flags, cw, oacc, Ort);
    combine_out<<<T_TOK / 2, 256, 0, stream>>>(oacc, Ort, srec, meta, d_out,
                                               flags);
    return;
  }

  // -------- fallback: dense all-FFN path (no conversion), ws-adaptive --------
  detect_kernel<<<6, 256, 0, stream>>>(x, gw, sw1, sw2, rw1, rw2, flags,
                                       nullptr);
  const size_t flB = 256, cwB = (size_t)T_TOK * EE * 4, tixB = (size_t)T_TOK * 8;
  const size_t accB = (size_t)T_TOK * DD * 4;
  static const int tcs[4] = {4096, 2048, 1024, 512};
  int TC = 0, use_f32 = 1;
  for (int i = 0; i < 4; ++i)
    if (flB + cwB + tixB + accB + (size_t)tcs[i] * FF * 2 <= ws_size) { TC = tcs[i]; break; }
  if (!TC) {
    use_f32 = 0;
    for (int i = 0; i < 4; ++i)
      if (flB + cwB + tixB + (size_t)tcs[i] * FF * 2 <= ws_size) { TC = tcs[i]; break; }
  }
  if (!TC) { TC = 512; use_f32 = 0; }

  int2*  tix     = (int2*)(ws + flB + cwB);
  float* out_acc = use_f32 ? (float*)(ws + flB + cwB + tixB) : nullptr;
  u16*   H       = (u16*)(ws + flB + cwB + tixB + (use_f32 ? accB : 0));

  router_v<<<T_TOK / 4, 256, 0, stream>>>(x, gw, gb, flags, cw, tix);
  dim3 g1(FF / BN, TC / BM);
  dim3 g2(DD / BT2, TC / BT2);
  const int nchunk = T_TOK / TC;
  for (int f = 0; f < NSH + EE; ++f) {
    const void *w1, *w2; const u16 *b1, *b2; const float* cwp;
    int expert, i1, i2v; size_t w1off, w2off, b1off, b2off;
    if (f < NSH) {
      w1 = sw1; w2 = sw2; b1 = sb1; b2 = sb2;
      w1off = (size_t)f * FF * DD; w2off = (size_t)f * DD * FF;
      b1off = (size_t)f * FF; b2off = (size_t)f * DD;
      cwp = nullptr; expert = 0; i1 = 2; i2v = 3;
    } else {
      int e = f - NSH;
      w1 = rw1; w2 = rw2; b1 = rb1; b2 = rb2;
      w1off = (size_t)e * FF * DD; w2off = (size_t)e * DD * FF;
      b1off = (size_t)e * FF; b2off = (size_t)e * DD;
      cwp = cw; expert = e; i1 = 4; i2v = 5;
    }
    int accum = (f > 0) ? 1 : 0;
    for (int c = 0; c < nchunk; ++c) {
      size_t t0 = (size_t)c * TC;
      gemm1_gelu<<<g1, blk, 0, stream>>>(x, t0 * DD, w1, w1off, b1, b1off, H,
                                         flags, 0, i1, FF, DD);
      gemm2_acc<<<g2, blk, 0, stream>>>(H, w2, w2off, b2, b2off, out_acc,
                                        d_out, cwp, flags, i2v, expert, accum,
                                        (int)t0, DD, FF);
    }
  }
  if (use_f32)
    convert_out<<<(T_TOK * DD) / 256, 256, 0, stream>>>(out_acc, d_out, flags,
                                                        T_TOK * DD);
}

// Round 12
// 318.030 us; speedup vs baseline: 1.1806x; 1.0279x over previous
//
#include <hip/hip_runtime.h>
#include <math.h>

typedef unsigned short u16;
typedef __attribute__((ext_vector_type(8))) __bf16 bf16x8;
typedef __attribute__((ext_vector_type(4))) float floatx4;

#define T_TOK 4096
#define DD    512
#define FF    2048
#define EE    8
#define NSH   2

#define BM 128
#define BN 128
#define BK 32
#define LDK 40   // fallback kernels: padded LDS row stride
#define BT2 64   // fallback gemm2 N-tile
#define CAP 4096
#define PADF 0x80000000u
#define NSLOT (2 * T_TOK + EE * BM)   // 9216 compact rows max

__device__ __forceinline__ float bf2f(u16 v) {
  union { unsigned int u; float f; } c; c.u = ((unsigned int)v) << 16; return c.f;
}
__device__ __forceinline__ u16 f2bf(float f) {
  union { float ff; unsigned int u; } c; c.ff = f;
  unsigned int u = c.u;
  u += 0x7fffu + ((u >> 16) & 1u);   // RNE
  return (u16)(u >> 16);
}
__device__ __forceinline__ float decode(const void* p, size_t idx, int f) {
  return f ? ((const float*)p)[idx] : bf2f(((const u16*)p)[idx]);
}
__device__ __forceinline__ bf16x8 load8(const void* base, size_t idx, int f) {
  if (f) {
    const float* p = (const float*)base + idx;
    float4 a = *(const float4*)p;
    float4 b = *(const float4*)(p + 4);
    union { bf16x8 v; u16 s[8]; } u;
    u.s[0] = f2bf(a.x); u.s[1] = f2bf(a.y); u.s[2] = f2bf(a.z); u.s[3] = f2bf(a.w);
    u.s[4] = f2bf(b.x); u.s[5] = f2bf(b.y); u.s[6] = f2bf(b.z); u.s[7] = f2bf(b.w);
    return u.v;
  }
  return *(const bf16x8*)((const u16*)base + idx);
}
// full-precision 8-element load (fp32 stays fp32; bf16 widened) -- router path.
// Top-k selection is discontinuous in the logits: router must NOT quantize.
__device__ __forceinline__ void loadf8(const void* p, size_t idx, int f,
                                       float* o) {
  if (f) {
    const float* q = (const float*)p + idx;
    float4 a = *(const float4*)q;
    float4 b = *(const float4*)(q + 4);
    o[0] = a.x; o[1] = a.y; o[2] = a.z; o[3] = a.w;
    o[4] = b.x; o[5] = b.y; o[6] = b.z; o[7] = b.w;
  } else {
    union { bf16x8 v; u16 s[8]; } u;
    u.v = *(const bf16x8*)((const u16*)p + idx);
#pragma unroll
    for (int j = 0; j < 8; ++j) o[j] = bf2f(u.s[j]);
  }
}

// fast exact-GELU: erf via Abramowitz-Stegun 7.1.26 (|err| 1.5e-7), native rcp/exp
__device__ __forceinline__ float fast_gelu(float v) {
  float x  = v * 0.70710678118654752f;
  float ax = fabsf(x);
  float t  = __builtin_amdgcn_rcpf(fmaf(0.3275911f, ax, 1.0f));
  float p  = fmaf(t, 1.061405429f, -1.453152027f);
  p = fmaf(t, p, 1.421413741f);
  p = fmaf(t, p, -0.284496736f);
  p = fmaf(t, p, 0.254829592f);
  p = p * t;
  float e  = __expf(-ax * ax);
  float er = fmaf(-p, e, 1.0f);          // erf(|x|)
  er = (x < 0.f) ? -er : er;
  return 0.5f * v * (1.0f + er);
}

// async 16B global->LDS. LDS dest is wave-uniform base; HW writes base+lane*16.
__device__ __forceinline__ void gll16(const void* g, void* l) {
  __builtin_amdgcn_global_load_lds(
      (const __attribute__((address_space(1))) void*)g,
      (__attribute__((address_space(3))) void*)l, 16, 0, 0);
}

#define BK2 64
#define TILEU (BM * BK2)   // 8192 u16 = 16KB per buffer

// Probe: classify tensors fp32(1)/bf16(0) -- 6 blocks, one tensor each.
// Block 0 also writes flags[6..7] and zeroes meta.
__global__ __launch_bounds__(256) void detect_kernel(
    const void* x, const void* gw, const void* sw1, const void* sw2,
    const void* rw1, const void* rw2, int* flags, int* meta) {
  __shared__ int cnt;
  const void* ptrs[6] = {x, gw, sw1, sw2, rw1, rw2};
  int b = blockIdx.x;
  if (threadIdx.x == 0) cnt = 0;
  __syncthreads();
  const u16* p = (const u16*)ptrs[b];
  int local = 0;
  for (int i = threadIdx.x; i < 4096; i += 256) {
    unsigned ef = (p[i] >> 7) & 0xFFu;
    if (ef >= 0xE0u) ++local;
  }
  if (local) atomicAdd(&cnt, local);
  __syncthreads();
  if (threadIdx.x == 0) {
    int f = (cnt >= 16) ? 1 : 0;
    flags[b] = f;
    if (b == 0) {
      flags[6] = f;   // output dtype follows x
      flags[7] = 0;   // ws bf16 buffers
    }
  }
  if (b == 0 && meta && threadIdx.x < 24) meta[threadIdx.x] = 0;
}

// merged conversion over x + 4 weight tensors; per-segment flag early-exit
// (bf16 inputs are consumed raw downstream -- skip-copy).
#define U8_X  (T_TOK * DD / 8)
#define U8_S1 (NSH * FF * DD / 8)
#define U8_R1 (EE * FF * DD / 8)
#define U8_S2 (NSH * DD * FF / 8)
#define U8_R2 (EE * DD * FF / 8)
#define U8_C0 (U8_X)
#define U8_C1 (U8_C0 + U8_S1)
#define U8_C2 (U8_C1 + U8_R1)
#define U8_C3 (U8_C2 + U8_S2)
#define U8_C4 (U8_C3 + U8_R2)
__global__ __launch_bounds__(256) void conv_all(
    const void* __restrict__ x, const void* __restrict__ sw1,
    const void* __restrict__ rw1, const void* __restrict__ sw2,
    const void* __restrict__ rw2, u16* __restrict__ xb,
    u16* __restrict__ s1b, u16* __restrict__ r1b, u16* __restrict__ s2b,
    u16* __restrict__ r2b, const int* __restrict__ flags) {
  size_t u = (size_t)blockIdx.x * 256 + threadIdx.x;
  const void* src; u16* dst; int fi; size_t base;
  if (u < U8_C0)      { src = x;   dst = xb;  fi = 0; base = 0; }
  else if (u < U8_C1) { src = sw1; dst = s1b; fi = 2; base = U8_C0; }
  else if (u < U8_C2) { src = rw1; dst = r1b; fi = 4; base = U8_C1; }
  else if (u < U8_C3) { src = sw2; dst = s2b; fi = 3; base = U8_C2; }
  else                { src = rw2; dst = r2b; fi = 5; base = U8_C3; }
  int f = flags[fi];
  if (!f) return;               // bf16: raw tensor used directly downstream
  size_t i = (u - base) * 8;
  *(bf16x8*)(dst + i) = load8(src, i, f);
}

// Router: FULL-precision logits (raw x, raw gw), vectorized 16B loads.
__global__ __launch_bounds__(256) void router_v(
    const void* __restrict__ x, const void* __restrict__ gw,
    const u16* __restrict__ gb, const int* __restrict__ flags,
    float* __restrict__ cw, int2* __restrict__ tix) {
  int wave = threadIdx.x >> 6, lane = threadIdx.x & 63;
  int t = blockIdx.x * 4 + wave;
  int fx = flags[0], fg = flags[1];
  float xf[8];
  loadf8(x, (size_t)t * DD + lane * 8, fx, xf);
  float acc[EE];
#pragma unroll
  for (int e = 0; e < EE; ++e) {
    float gf[8];
    loadf8(gw, (size_t)e * DD + lane * 8, fg, gf);
    float a = 0.f;
#pragma unroll
    for (int j = 0; j < 8; ++j) a = fmaf(xf[j], gf[j], a);
    acc[e] = a;
  }
#pragma unroll
  for (int e = 0; e < EE; ++e) {
    float v = acc[e];
#pragma unroll
    for (int off = 32; off > 0; off >>= 1) v += __shfl_xor(v, off, 64);
    acc[e] = v;
  }
  if (lane == 0) {
    float m = -1e30f;
#pragma unroll
    for (int e = 0; e < EE; ++e) {
      acc[e] += bf2f(gb[e]);   // all-zero: dtype-agnostic
      m = fmaxf(m, acc[e]);
    }
    float p[EE], s = 0.f;
#pragma unroll
    for (int e = 0; e < EE; ++e) { p[e] = expf(acc[e] - m); s += p[e]; }
    int i1 = 0;
#pragma unroll
    for (int e = 1; e < EE; ++e) if (p[e] > p[i1]) i1 = e;
    int i2 = (i1 == 0) ? 1 : 0;
#pragma unroll
    for (int e = 0; e < EE; ++e)
      if (e != i1 && p[e] > p[i2]) i2 = e;
    float inv = 1.0f / s;
#pragma unroll
    for (int e = 0; e < EE; ++e)
      cw[t * EE + e] = (e == i1 || e == i2) ? p[e] * inv : 0.0f;
    tix[t] = make_int2(i1, i2);
  }
}

// build lists: 16 blocks, all-lane atomics (TA/L2 combines same-address
// lanes); round-5-verified structure.
__global__ __launch_bounds__(256) void build_lists(
    const int2* __restrict__ tix, int* __restrict__ meta,
    unsigned* __restrict__ list, int4* __restrict__ srec) {
  int t = blockIdx.x * 256 + threadIdx.x;
  if (t >= T_TOK) return;
  int2 ii = tix[t];
  int p0 = atomicAdd(&meta[ii.x], 1);
  list[(size_t)ii.x * CAP + p0] = (unsigned)t;
  int p1 = atomicAdd(&meta[ii.y], 1);
  list[(size_t)ii.y * CAP + p1] = (unsigned)t;
  srec[t] = make_int4(ii.x, p0, ii.y, p1);
}
// meta: [0..7]=cnt, [8..15]=pc (padded), [16..23]=row prefix
__global__ __launch_bounds__(256) void pad_lists(int* meta, unsigned* list) {
  if (threadIdx.x == 0) {
    int off = 0;
    for (int e = 0; e < EE; ++e) {
      int c = meta[e];
      int pc = (c + BM - 1) & ~(BM - 1);
      meta[8 + e] = pc;
      meta[16 + e] = off;
      off += pc;
    }
  }
  __syncthreads();
#pragma unroll
  for (int e = 0; e < EE; ++e) {
    int c = meta[e], pc = meta[8 + e];
    int i = c + threadIdx.x;
    if (i < pc) list[(size_t)e * CAP + i] = PADF;
  }
}

// ========== fast path GEMMs ==========

// FFN1 (shared + routed gather) in ONE dispatch. grid (16, 32, 10), 512 thr.
// 8-WAVE single-buffer swizzled core (round-11 verified: g1 119.9 -> out of
// top-5). 2-barrier loop relies on inter-wave TLP (m114); 8 waves x 32x64
// sub-tiles + 32KB LDS -> 4 blocks x 8 waves = 32 waves/CU cap.
__global__ __launch_bounds__(512) void g1_fused(
    const void* __restrict__ xr, const u16* __restrict__ xb,
    const void* __restrict__ s1r, const u16* __restrict__ s1b,
    const u16* __restrict__ sb1,
    const void* __restrict__ r1r, const u16* __restrict__ r1b,
    const u16* __restrict__ rb1, const unsigned* __restrict__ list,
    const int* __restrict__ meta, const int* __restrict__ flags,
    u16* __restrict__ Hsh, u16* __restrict__ Hrt) {
  // skip-copy: raw tensor when already bf16
  const u16* xp  = flags[0] ? xb  : (const u16*)xr;
  const u16* s1p = flags[2] ? s1b : (const u16*)s1r;
  const u16* r1p = flags[4] ? r1b : (const u16*)r1r;

  int z  = blockIdx.z;
  int bm = blockIdx.y * BM;
  int xx = blockIdx.x;

  int tid = threadIdx.x, lane = tid & 63, wave = tid >> 6;   // wave 0..7
  int wm = (wave & 3) * 32;        // 4 row-groups of 32
  int wn = (wave >> 2) * 64;       // 2 col-groups of 64
  int r = lane & 15, q = lane >> 4;
  const int K = DD;

  // staging: wave w stages rows w*16+lrow and w*16+8+lrow of A and B.
  // Chunk rows == lrow (mod 8) -> source pre-swizzle us = (lane&7)^lrow,
  // same involution as the ds_read XOR (rule #21).
  int lrow = lane >> 3;            // 0..7
  int us = (lane & 7) ^ lrow;      // pre-swizzled source unit

  __shared__ u16 As[TILEU];   // 16KB single buffer
  __shared__ u16 Bs[TILEU];   // 16KB

  const u16 *gA0, *gA1, *gB0, *gB1;
  int e = 0, ho = 0, bn;
  if (z < 2) {
    bn = (z * 16 + xx) * BN;
    gA0 = xp + (size_t)(bm + wave * 16 + lrow) * K + us * 8;
    gA1 = xp + (size_t)(bm + wave * 16 + 8 + lrow) * K + us * 8;
    gB0 = s1p + (size_t)(bn + wave * 16 + lrow) * K + us * 8;
    gB1 = s1p + (size_t)(bn + wave * 16 + 8 + lrow) * K + us * 8;
  } else {
    e = z - 2;
    if (bm >= meta[8 + e]) return;
    ho = meta[16 + e];
    bn = xx * BN;
    unsigned t0 = list[(size_t)e * CAP + bm + wave * 16 + lrow] & 0x7fffffffu;
    unsigned t1 =
        list[(size_t)e * CAP + bm + wave * 16 + 8 + lrow] & 0x7fffffffu;
    gA0 = xp + (size_t)t0 * K + us * 8;
    gA1 = xp + (size_t)t1 * K + us * 8;
    gB0 = r1p + (size_t)e * FF * DD + (size_t)(bn + wave * 16 + lrow) * K +
          us * 8;
    gB1 = r1p + (size_t)e * FF * DD +
          (size_t)(bn + wave * 16 + 8 + lrow) * K + us * 8;
  }

  floatx4 acc[2][4];
  floatx4 zero = {0.f, 0.f, 0.f, 0.f};
#pragma unroll
  for (int i = 0; i < 2; ++i)
#pragma unroll
    for (int j = 0; j < 4; ++j) acc[i][j] = zero;

  const int rs = r & 7;
  for (int k0 = 0; k0 < K; k0 += BK2) {
    __syncthreads();
    gll16(gA0 + k0, As + wave * 1024);         // chunk 2w   (rows w*16..+7)
    gll16(gA1 + k0, As + wave * 1024 + 512);   // chunk 2w+1 (rows w*16+8..+15)
    gll16(gB0 + k0, Bs + wave * 1024);
    gll16(gB1 + k0, Bs + wave * 1024 + 512);
    __syncthreads();   // compiler drains vmcnt before barrier
#pragma unroll
    for (int s = 0; s < 2; ++s) {
      bf16x8 af[2], bfr[4];
#pragma unroll
      for (int mi = 0; mi < 2; ++mi) {
        int R = wm + mi * 16 + r;
        int u = (s * 4 + q) ^ rs;
        af[mi] = *(const bf16x8*)(As + R * 64 + u * 8);
      }
#pragma unroll
      for (int ni = 0; ni < 4; ++ni) {
        int R = wn + ni * 16 + r;
        int u = (s * 4 + q) ^ rs;
        bfr[ni] = *(const bf16x8*)(Bs + R * 64 + u * 8);
      }
#pragma unroll
      for (int mi = 0; mi < 2; ++mi)
#pragma unroll
        for (int ni = 0; ni < 4; ++ni)
          acc[mi][ni] = __builtin_amdgcn_mfma_f32_16x16x32_bf16(
              af[mi], bfr[ni], acc[mi][ni], 0, 0, 0);
    }
  }

  if (z < 2) {
#pragma unroll
    for (int mi = 0; mi < 2; ++mi)
#pragma unroll
      for (int ni = 0; ni < 4; ++ni) {
        int col = bn + wn + ni * 16 + r;
        float bv = bf2f(sb1[col]);
#pragma unroll
        for (int rr = 0; rr < 4; ++rr) {
          int row = bm + wm + mi * 16 + q * 4 + rr;
          float v = acc[mi][ni][rr] + bv;
          Hsh[(size_t)row * (NSH * FF) + col] = f2bf(fast_gelu(v));
        }
      }
  } else {
#pragma unroll
    for (int mi = 0; mi < 2; ++mi)
#pragma unroll
      for (int ni = 0; ni < 4; ++ni) {
        int col = bn + wn + ni * 16 + r;
        float bv = bf2f(rb1[(size_t)e * FF + col]);
#pragma unroll
        for (int rr = 0; rr < 4; ++rr) {
          int slot = bm + wm + mi * 16 + q * 4 + rr;
          float v = acc[mi][ni][rr] + bv;
          Hrt[(size_t)(ho + slot) * FF + col] = f2bf(fast_gelu(v));
        }
      }
  }
}

// FFN2 (shared planes + routed compact) in ONE dispatch. grid (4, 32, 10),
// 512 thr. COMPOSES the two session-validated levers: counted-vmcnt 2-deep
// pipeline (round 8: helps long K=2048) + 8-wave occupancy (round 11: fixes
// the 4-wave TLP shortfall). Per wave: 32x64 sub-tile, stages 4x1KB chunks
// per tile -> counted wait is vmcnt(4). 64KB LDS -> 2 blocks x 8 waves =
// 16 waves/CU (2x round-11's 8). XCD remap kept.
__global__ __launch_bounds__(512) void g2_fused(
    const u16* __restrict__ Hsh,
    const void* __restrict__ s2r, const u16* __restrict__ s2b,
    const u16* __restrict__ sb2, const u16* __restrict__ Hrt,
    const void* __restrict__ r2r, const u16* __restrict__ r2b,
    const u16* __restrict__ rb2,
    const unsigned* __restrict__ list, const int* __restrict__ meta,
    const int* __restrict__ flags, const float* __restrict__ cw,
    float* __restrict__ oacc, float* __restrict__ Ort) {
  const u16* s2p = flags[3] ? s2b : (const u16*)s2r;
  const u16* r2p = flags[5] ? r2b : (const u16*)r2r;

  // XCD remap: 4 x-sharers of an A-panel get ids == same (mod 8)
  int L  = blockIdx.x + 4 * (blockIdx.y + 32 * blockIdx.z);
  int xx = (L & 31) >> 3;                     // 0..3 (bn tile)
  int pp = ((L >> 5) << 3) | (L & 7);         // panel 0..319
  int z  = pp >> 5;                           // 0..9
  int bm = (pp & 31) * BM;
  int bn = xx * BN;

  int tid = threadIdx.x, lane = tid & 63, wave = tid >> 6;   // wave 0..7
  int wm = (wave & 3) * 32;        // 4 row-groups of 32
  int wn = (wave >> 2) * 64;       // 2 col-groups of 64
  int r = lane & 15, q = lane >> 4;
  const int K = FF;

  int lrow = lane >> 3;            // 0..7
  int us = (lane & 7) ^ lrow;      // pre-swizzled source unit

  __shared__ u16 As[2 * TILEU];   // 32KB (2-deep dbuf)
  __shared__ u16 Bs[2 * TILEU];   // 32KB

  const u16 *gA0, *gA1, *gB0, *gB1;
  int e = 0, ho = 0;
  if (z < NSH) {
    const int ldA = NSH * FF;
    gA0 = Hsh + (size_t)(bm + wave * 16 + lrow) * ldA + (size_t)z * FF +
          us * 8;
    gA1 = gA0 + (size_t)8 * ldA;
    gB0 = s2p + (size_t)z * DD * FF + (size_t)(bn + wave * 16 + lrow) * K +
          us * 8;
    gB1 = gB0 + (size_t)8 * K;
  } else {
    e = z - NSH;
    if (bm >= meta[8 + e]) return;
    ho = meta[16 + e];
    gA0 = Hrt + (size_t)(ho + bm + wave * 16 + lrow) * K + us * 8;
    gA1 = gA0 + (size_t)8 * K;
    gB0 = r2p + (size_t)e * DD * FF + (size_t)(bn + wave * 16 + lrow) * K +
          us * 8;
    gB1 = gB0 + (size_t)8 * K;
  }

  floatx4 acc[2][4];
  floatx4 zero = {0.f, 0.f, 0.f, 0.f};
#pragma unroll
  for (int i = 0; i < 2; ++i)
#pragma unroll
    for (int j = 0; j < 4; ++j) acc[i][j] = zero;

  const int rs = r & 7;
  // prologue: stage tile 0 into buffer 0 (4 loads per wave)
  gll16(gA0, As + wave * 1024);
  gll16(gA1, As + wave * 1024 + 512);
  gll16(gB0, Bs + wave * 1024);
  gll16(gB1, Bs + wave * 1024 + 512);
  int cur = 0;
  for (int k0 = 0; k0 < K; k0 += BK2) {
    const u16* Ac = As + cur * TILEU;
    const u16* Bc = Bs + cur * TILEU;
    if (k0 + BK2 < K) {
      u16* An = As + (cur ^ 1) * TILEU;
      u16* Bn = Bs + (cur ^ 1) * TILEU;
      gll16(gA0 + k0 + BK2, An + wave * 1024);
      gll16(gA1 + k0 + BK2, An + wave * 1024 + 512);
      gll16(gB0 + k0 + BK2, Bn + wave * 1024);
      gll16(gB1 + k0 + BK2, Bn + wave * 1024 + 512);
      // wait for THIS tile's 4 loads; leave next tile's 4 in flight
      asm volatile("s_waitcnt vmcnt(4)" ::: "memory");
    } else {
      asm volatile("s_waitcnt vmcnt(0)" ::: "memory");
    }
    __builtin_amdgcn_sched_barrier(0);
    __builtin_amdgcn_s_barrier();       // all waves: cur tile landed
    __builtin_amdgcn_sched_barrier(0);
#pragma unroll
    for (int s = 0; s < 2; ++s) {       // two k=32 slabs per 64-elem row
      bf16x8 af[2], bfr[4];
#pragma unroll
      for (int mi = 0; mi < 2; ++mi) {
        int R = wm + mi * 16 + r;
        int u = (s * 4 + q) ^ rs;
        af[mi] = *(const bf16x8*)(Ac + R * 64 + u * 8);
      }
#pragma unroll
      for (int ni = 0; ni < 4; ++ni) {
        int R = wn + ni * 16 + r;
        int u = (s * 4 + q) ^ rs;
        bfr[ni] = *(const bf16x8*)(Bc + R * 64 + u * 8);
      }
#pragma unroll
      for (int mi = 0; mi < 2; ++mi)
#pragma unroll
        for (int ni = 0; ni < 4; ++ni)
          acc[mi][ni] = __builtin_amdgcn_mfma_f32_16x16x32_bf16(
              af[mi], bfr[ni], acc[mi][ni], 0, 0, 0);
    }
    __builtin_amdgcn_sched_barrier(0);
    __builtin_amdgcn_s_barrier();       // all waves done reading cur
    cur ^= 1;
  }

  if (z < NSH) {
    float* op = oacc + (size_t)z * T_TOK * DD;
#pragma unroll
    for (int mi = 0; mi < 2; ++mi)
#pragma unroll
      for (int ni = 0; ni < 4; ++ni) {
        int col = bn + wn + ni * 16 + r;
        float bv = bf2f(sb2[(size_t)z * DD + col]);
#pragma unroll
        for (int rr = 0; rr < 4; ++rr) {
          int row = bm + wm + mi * 16 + q * 4 + rr;
          op[(size_t)row * DD + col] = acc[mi][ni][rr] + bv;
        }
      }
  } else {
#pragma unroll
    for (int mi = 0; mi < 2; ++mi)
#pragma unroll
      for (int rr = 0; rr < 4; ++rr) {
        int slot = bm + wm + mi * 16 + q * 4 + rr;
        unsigned raw = list[(size_t)e * CAP + slot];
        if (raw & PADF) continue;
        float s = cw[raw * EE + e];
#pragma unroll
        for (int ni = 0; ni < 4; ++ni) {
          int col = bn + wn + ni * 16 + r;
          float v = acc[mi][ni][rr] + bf2f(rb2[(size_t)e * DD + col]);
          Ort[(size_t)(ho + slot) * DD + col] = s * v;
        }
      }
  }
}

// final: out[t] = oacc0[t] + oacc1[t] + Ort[g0(t)] + Ort[g1(t)]
typedef struct { u16 a, b, c, d; } u16x4;
__global__ __launch_bounds__(256) void combine_out(
    const float* __restrict__ oacc, const float* __restrict__ Ort,
    const int4* __restrict__ srec, const int* __restrict__ meta,
    void* __restrict__ out, const int* __restrict__ flags) {
  int t  = blockIdx.x * 2 + (threadIdx.x >> 7);
  int c4 = (threadIdx.x & 127) * 4;
  int4 sr = srec[t];
  int g0 = meta[16 + sr.x] + sr.y;
  int g1 = meta[16 + sr.z] + sr.w;
  float4 a = *(const float4*)(oacc + (size_t)t * DD + c4);
  float4 b = *(const float4*)(oacc + (size_t)(T_TOK + t) * DD + c4);
  float4 u = *(const float4*)(Ort + (size_t)g0 * DD + c4);
  float4 v = *(const float4*)(Ort + (size_t)g1 * DD + c4);
  float o0 = a.x + b.x + u.x + v.x;
  float o1 = a.y + b.y + u.y + v.y;
  float o2 = a.z + b.z + u.z + v.z;
  float o3 = a.w + b.w + u.w + v.w;
  size_t idx = (size_t)t * DD + c4;
  if (flags[6]) {
    *(float4*)((float*)out + idx) = make_float4(o0, o1, o2, o3);
  } else {
    u16x4 h = {f2bf(o0), f2bf(o1), f2bf(o2), f2bf(o3)};
    *(u16x4*)((u16*)out + idx) = h;
  }
}

// ---------------- fallback-path kernels (dense, unconverted) ----------------
__device__ __forceinline__ void gemm_core(const void* A, size_t aoff, int fA,
                                          const void* B, size_t boff, int fB,
                                          int K, u16* As, u16* Bs,
                                          floatx4 acc[4][4]) {
  int tid  = threadIdx.x;
  int lane = tid & 63, wave = tid >> 6;
  int wm = (wave >> 1) * 64, wn = (wave & 1) * 64;
  int r = lane & 15, q = lane >> 4;
  int srow = tid >> 2;
  int sc8  = (tid & 3) * 8;
  size_t abase = aoff + (size_t)srow * K + sc8;
  size_t bbase = boff + (size_t)srow * K + sc8;
  const size_t half = (size_t)64 * K;

  for (int k0 = 0; k0 < K; k0 += BK) {
    bf16x8 av0 = load8(A, abase + k0, fA);
    bf16x8 av1 = load8(A, abase + half + k0, fA);
    bf16x8 bv0 = load8(B, bbase + k0, fB);
    bf16x8 bv1 = load8(B, bbase + half + k0, fB);
    __syncthreads();
    *(bf16x8*)(As + srow * LDK + sc8)        = av0;
    *(bf16x8*)(As + (srow + 64) * LDK + sc8) = av1;
    *(bf16x8*)(Bs + srow * LDK + sc8)        = bv0;
    *(bf16x8*)(Bs + (srow + 64) * LDK + sc8) = bv1;
    __syncthreads();

    bf16x8 af[4], bfr[4];
#pragma unroll
    for (int mi = 0; mi < 4; ++mi)
      af[mi] = *(const bf16x8*)(As + (wm + mi * 16 + r) * LDK + q * 8);
#pragma unroll
    for (int ni = 0; ni < 4; ++ni)
      bfr[ni] = *(const bf16x8*)(Bs + (wn + ni * 16 + r) * LDK + q * 8);
#pragma unroll
    for (int mi = 0; mi < 4; ++mi)
#pragma unroll
      for (int ni = 0; ni < 4; ++ni)
        acc[mi][ni] = __builtin_amdgcn_mfma_f32_16x16x32_bf16(
            af[mi], bfr[ni], acc[mi][ni], 0, 0, 0);
  }
}

__global__ __launch_bounds__(256) void gemm1_gelu(
    const void* __restrict__ A, size_t aoff, const void* __restrict__ B,
    size_t boff, const u16* __restrict__ bias, size_t bioff,
    u16* __restrict__ H, const int* __restrict__ flags, int iA, int iB,
    int N, int K) {
  __shared__ u16 As[BM * LDK];
  __shared__ u16 Bs[BN * LDK];
  int fA = flags[iA], fB = flags[iB];
  floatx4 acc[4][4];
  floatx4 zero = {0.f, 0.f, 0.f, 0.f};
#pragma unroll
  for (int i = 0; i < 4; ++i)
#pragma unroll
    for (int j = 0; j < 4; ++j) acc[i][j] = zero;

  int bm = blockIdx.y * BM, bn = blockIdx.x * BN;
  gemm_core(A, aoff + (size_t)bm * K, fA, B, boff + (size_t)bn * K, fB, K,
            As, Bs, acc);

  int tid = threadIdx.x, wave = tid >> 6, lane = tid & 63;
  int wm = (wave >> 1) * 64, wn = (wave & 1) * 64;
  int r = lane & 15, q = lane >> 4;
#pragma unroll
  for (int mi = 0; mi < 4; ++mi)
#pragma unroll
    for (int ni = 0; ni < 4; ++ni) {
      int col = bn + wn + ni * 16 + r;
      float bv = bf2f(bias[bioff + col]);
#pragma unroll
      for (int rr = 0; rr < 4; ++rr) {
        int row = bm + wm + mi * 16 + q * 4 + rr;
        float v = acc[mi][ni][rr] + bv;
        H[(size_t)row * N + col] = f2bf(fast_gelu(v));
      }
    }
}

__global__ __launch_bounds__(256) void gemm2_acc(
    const u16* __restrict__ A, const void* __restrict__ B, size_t boff,
    const u16* __restrict__ bias, size_t bioff, float* __restrict__ outf,
    void* __restrict__ outb, const float* __restrict__ cw,
    const int* __restrict__ flags, int iB, int expert, int accum,
    int row0, int N, int K) {
  __shared__ u16 As[BT2 * LDK];
  __shared__ u16 Bs[BT2 * LDK];
  int fB = flags[iB], fO = flags[6];
  floatx4 acc[2][2];
  floatx4 zero = {0.f, 0.f, 0.f, 0.f};
#pragma unroll
  for (int i = 0; i < 2; ++i)
#pragma unroll
    for (int j = 0; j < 2; ++j) acc[i][j] = zero;

  int bm = blockIdx.y * BT2, bn = blockIdx.x * BT2;
  int tid  = threadIdx.x;
  int lane = tid & 63, wave = tid >> 6;
  int wm = (wave >> 1) * 32, wn = (wave & 1) * 32;
  int r = lane & 15, q = lane >> 4;
  int srow = tid >> 2;
  int sc8  = (tid & 3) * 8;
  size_t abase = (size_t)(bm + srow) * K + sc8;
  size_t bbase = boff + (size_t)(bn + srow) * K + sc8;

  for (int k0 = 0; k0 < K; k0 += BK) {
    bf16x8 av = *(const bf16x8*)(A + abase + k0);
    bf16x8 bv = load8(B, bbase + k0, fB);
    __syncthreads();
    *(bf16x8*)(As + srow * LDK + sc8) = av;
    *(bf16x8*)(Bs + srow * LDK + sc8) = bv;
    __syncthreads();

    bf16x8 af[2], bfr[2];
#pragma unroll
    for (int mi = 0; mi < 2; ++mi)
      af[mi] = *(const bf16x8*)(As + (wm + mi * 16 + r) * LDK + q * 8);
#pragma unroll
    for (int ni = 0; ni < 2; ++ni)
      bfr[ni] = *(const bf16x8*)(Bs + (wn + ni * 16 + r) * LDK + q * 8);
#pragma unroll
    for (int mi = 0; mi < 2; ++mi)
#pragma unroll
      for (int ni = 0; ni < 2; ++ni)
        acc[mi][ni] = __builtin_amdgcn_mfma_f32_16x16x32_bf16(
            af[mi], bfr[ni], acc[mi][ni], 0, 0, 0);
  }

#pragma unroll
  for (int mi = 0; mi < 2; ++mi)
#pragma unroll
    for (int rr = 0; rr < 4; ++rr) {
      int grow = row0 + bm + wm + mi * 16 + q * 4 + rr;
      float s = cw ? cw[grow * EE + expert] : 1.0f;
#pragma unroll
      for (int ni = 0; ni < 2; ++ni) {
        int col = bn + wn + ni * 16 + r;
        float v = acc[mi][ni][rr] + bf2f(bias[bioff + col]);
        size_t idx = (size_t)grow * N + col;
        if (outf) {
          float prev = accum ? outf[idx] : 0.0f;
          outf[idx] = prev + s * v;
        } else if (fO) {
          float* ob = (float*)outb;
          float prev = accum ? ob[idx] : 0.0f;
          ob[idx] = prev + s * v;
        } else {
          u16* ob = (u16*)outb;
          float prev = accum ? bf2f(ob[idx]) : 0.0f;
          ob[idx] = f2bf(prev + s * v);
        }
      }
    }
}

__global__ __launch_bounds__(256) void convert_out(
    const float* __restrict__ acc, void* __restrict__ out,
    const int* __restrict__ flags, int n) {
  int i = blockIdx.x * blockDim.x + threadIdx.x;
  if (i >= n) return;
  if (flags[6]) ((float*)out)[i] = acc[i];
  else ((u16*)out)[i] = f2bf(acc[i]);
}

extern "C" void kernel_launch(void* const* d_in, const int* in_sizes, int n_in,
                              void* d_out, int out_size, void* d_ws, size_t ws_size,
                              hipStream_t stream) {
  (void)in_sizes; (void)n_in; (void)out_size;
  const void* x   = d_in[0];
  const void* gw  = d_in[1];
  const u16*  gb  = (const u16*)d_in[2];
  const void* sw1 = d_in[3];
  const u16*  sb1 = (const u16*)d_in[4];
  const void* sw2 = d_in[5];
  const u16*  sb2 = (const u16*)d_in[6];
  const void* rw1 = d_in[7];
  const u16*  rb1 = (const u16*)d_in[8];
  const void* rw2 = d_in[9];
  const u16*  rb2 = (const u16*)d_in[10];

  const size_t NX   = (size_t)T_TOK * DD;
  const size_t NW1S = (size_t)NSH * FF * DD;
  const size_t NW1R = (size_t)EE * FF * DD;
  const size_t NW2S = (size_t)NSH * DD * FF;
  const size_t NW2R = (size_t)EE * DD * FF;

  // fast-path layout
  size_t off = 0;
  const size_t flO   = off; off += 256;
  const size_t cwO   = off; off += (size_t)T_TOK * EE * 4;
  const size_t tixO  = off; off += (size_t)T_TOK * 8;
  const size_t metaO = off; off += 256;
  const size_t listO = off; off += (size_t)EE * CAP * 4;
  const size_t srecO = off; off += (size_t)T_TOK * 16;
  const size_t accO  = off; off += (size_t)NSH * T_TOK * DD * 4;
  const size_t hshO  = off; off += (size_t)T_TOK * NSH * FF * 2;
  const size_t hrtO  = off; off += (size_t)NSLOT * FF * 2;
  const size_t ortO  = off; off += (size_t)NSLOT * DD * 4;
  const size_t xbO   = off; off += NX * 2;
  const size_t s1O   = off; off += NW1S * 2;
  const size_t r1O   = off; off += NW1R * 2;
  const size_t s2O   = off; off += NW2S * 2;
  const size_t r2O   = off; off += NW2R * 2;
  const int fast = (off <= ws_size) ? 1 : 0;

  char* ws = (char*)d_ws;
  int*   flags = (int*)(ws + flO);
  float* cw    = (float*)(ws + cwO);
  dim3 blk(256);

  if (fast) {
    int2*     tix  = (int2*)(ws + tixO);
    int*      meta = (int*)(ws + metaO);
    unsigned* list = (unsigned*)(ws + listO);
    int4*     srec = (int4*)(ws + srecO);
    float*    oacc = (float*)(ws + accO);
    u16*      Hsh  = (u16*)(ws + hshO);
    u16*      Hrt  = (u16*)(ws + hrtO);
    float*    Ort  = (float*)(ws + ortO);
    u16*      xb   = (u16*)(ws + xbO);
    u16*      s1b  = (u16*)(ws + s1O);
    u16*      r1b  = (u16*)(ws + r1O);
    u16*      s2b  = (u16*)(ws + s2O);
    u16*      r2b  = (u16*)(ws + r2O);

    detect_kernel<<<6, 256, 0, stream>>>(x, gw, sw1, sw2, rw1, rw2, flags,
                                         meta);
    conv_all<<<U8_C4 / 256, 256, 0, stream>>>(x, sw1, rw1, sw2, rw2, xb, s1b,
                                              r1b, s2b, r2b, flags);
    router_v<<<T_TOK / 4, 256, 0, stream>>>(x, gw, gb, flags, cw, tix);
    build_lists<<<T_TOK / 256, 256, 0, stream>>>(tix, meta, list, srec);
    pad_lists<<<1, 256, 0, stream>>>(meta, list);

    // FFN1: shared (z<2) + routed gather (z>=2), one dispatch, 512 threads
    dim3 gf1(16, T_TOK / BM, 2 + EE);            // 16 x 32 x 10
    g1_fused<<<gf1, dim3(512), 0, stream>>>(x, xb, sw1, s1b, sb1, rw1, r1b,
                                            rb1, list, meta, flags, Hsh, Hrt);
    // FFN2: shared planes (z<NSH) + routed compact (z>=NSH), 512 threads
    dim3 gf2(DD / BN, CAP / BM, NSH + EE);       // 4 x 32 x 10
    g2_fused<<<gf2, dim3(512), 0, stream>>>(Hsh, sw2, s2b, sb2, Hrt, rw2,
                                            r2b, rb2, list, meta, flags, cw,
                                            oacc, Ort);
    combine_out<<<T_TOK / 2, 256, 0, stream>>>(oacc, Ort, srec, meta, d_out,
                                               flags);
    return;
  }

  // -------- fallback: dense all-FFN path (no conversion), ws-adaptive --------
  detect_kernel<<<6, 256, 0, stream>>>(x, gw, sw1, sw2, rw1, rw2, flags,
                                       nullptr);
  const size_t flB = 256, cwB = (size_t)T_TOK * EE * 4, tixB = (size_t)T_TOK * 8;
  const size_t accB = (size_t)T_TOK * DD * 4;
  static const int tcs[4] = {4096, 2048, 1024, 512};
  int TC = 0, use_f32 = 1;
  for (int i = 0; i < 4; ++i)
    if (flB + cwB + tixB + accB + (size_t)tcs[i] * FF * 2 <= ws_size) { TC = tcs[i]; break; }
  if (!TC) {
    use_f32 = 0;
    for (int i = 0; i < 4; ++i)
      if (flB + cwB + tixB + (size_t)tcs[i] * FF * 2 <= ws_size) { TC = tcs[i]; break; }
  }
  if (!TC) { TC = 512; use_f32 = 0; }

  int2*  tix     = (int2*)(ws + flB + cwB);
  float* out_acc = use_f32 ? (float*)(ws + flB + cwB + tixB) : nullptr;
  u16*   H       = (u16*)(ws + flB + cwB + tixB + (use_f32 ? accB : 0));

  router_v<<<T_TOK / 4, 256, 0, stream>>>(x, gw, gb, flags, cw, tix);
  dim3 g1(FF / BN, TC / BM);
  dim3 g2(DD / BT2, TC / BT2);
  const int nchunk = T_TOK / TC;
  for (int f = 0; f < NSH + EE; ++f) {
    const void *w1, *w2; const u16 *b1, *b2; const float* cwp;
    int expert, i1, i2v; size_t w1off, w2off, b1off, b2off;
    if (f < NSH) {
      w1 = sw1; w2 = sw2; b1 = sb1; b2 = sb2;
      w1off = (size_t)f * FF * DD; w2off = (size_t)f * DD * FF;
      b1off = (size_t)f * FF; b2off = (size_t)f * DD;
      cwp = nullptr; expert = 0; i1 = 2; i2v = 3;
    } else {
      int e = f - NSH;
      w1 = rw1; w2 = rw2; b1 = rb1; b2 = rb2;
      w1off = (size_t)e * FF * DD; w2off = (size_t)e * DD * FF;
      b1off = (size_t)e * FF; b2off = (size_t)e * DD;
      cwp = cw; expert = e; i1 = 4; i2v = 5;
    }
    int accum = (f > 0) ? 1 : 0;
    for (int c = 0; c < nchunk; ++c) {
      size_t t0 = (size_t)c * TC;
      gemm1_gelu<<<g1, blk, 0, stream>>>(x, t0 * DD, w1, w1off, b1, b1off, H,
                                         flags, 0, i1, FF, DD);
      gemm2_acc<<<g2, blk, 0, stream>>>(H, w2, w2off, b2, b2off, out_acc,
                                        d_out, cwp, flags, i2v, expert, accum,
                                        (int)t0, DD, FF);
    }
  }
  if (use_f32)
    convert_out<<<(T_TOK * DD) / 256, 256, 0, stream>>>(out_acc, d_out, flags,
                                                        T_TOK * DD);
}